// Round 13
// baseline (1500.394 us; speedup 1.0000x reference)
//
#include <hip/hip_runtime.h>

// PatchVQVAETransformer forward, round 13:
//  - pkB: 4 waves per patch (256 thr). Every output computed by one thread
//    with the identical expression/order as r12; LN and z phases run
//    verbatim on wave 0 -> z bit-identical -> idx exact.
//  - wout/ffn2 GEMMs emit bf16 (proj increment rounded); LN residual adds
//    b2f(bf16). tb residual stream stays f32. Affects y only (~+0.02).
//  - everything else unchanged from r12.

#define SQRT1_2F 0.70710678118654752440f

typedef __attribute__((ext_vector_type(8))) short short8;
typedef __attribute__((ext_vector_type(4))) float f32x4;
typedef __attribute__((ext_vector_type(8))) unsigned short ushort8;
typedef unsigned short ushort;
typedef unsigned long long u64;

__device__ __forceinline__ float gelu_exact(float v) {
  return 0.5f * v * (1.0f + erff(v * SQRT1_2F));
}

__device__ __forceinline__ ushort f2b_rne(float f) {
  unsigned u = __float_as_uint(f);
  unsigned r = (u + 0x7fffu + ((u >> 16) & 1u)) >> 16;
  return (ushort)r;
}

__device__ __forceinline__ float b2f(ushort u) {
  return __uint_as_float(((unsigned)u) << 16);
}

__device__ __forceinline__ void gload16(const void* g, void* l) {
  __builtin_amdgcn_global_load_lds(
      (const __attribute__((address_space(1))) void*)g,
      (__attribute__((address_space(3))) void*)l, 16, 0, 0);
}

// monotone float->u32 (finite inputs): preserves <
__device__ __forceinline__ unsigned fkey(float d) {
  unsigned u = __float_as_uint(d);
  return (u & 0x80000000u) ? ~u : (u | 0x80000000u);
}

// ---------------------------------------------------------------------------
// One-time setup: q16 = lq@wq^T + bq; w1T[u][d]=w1[d][u]; w2T[c][u]=w2[u][c].
// ---------------------------------------------------------------------------
__global__ __launch_bounds__(64) void patch_setup_kernel(
    const float* __restrict__ lq, const float* __restrict__ win,
    const float* __restrict__ bin, const float* __restrict__ w1,
    const float* __restrict__ w2, float* __restrict__ q16,
    float* __restrict__ w1T, float* __restrict__ w2T) {
  const int tid = threadIdx.x;
#pragma unroll
  for (int q = 0; q < 8; q++) {
    int e = tid + (q << 6);
    int i = e >> 5, c = e & 31;
    const float* wr = win + (size_t)c * 32;
    float acc = bin[c];
#pragma unroll
    for (int d = 0; d < 32; d++) acc += lq[(i << 5) + d] * wr[d];
    q16[e] = acc;
  }
#pragma unroll
  for (int q = 0; q < 32; q++) {
    int e = tid + (q << 6);          // e = u*32 + d
    int u = e >> 5, d = e & 31;
    w1T[e] = w1[(size_t)d * 64 + u];
  }
#pragma unroll
  for (int q = 0; q < 32; q++) {
    int e = tid + (q << 6);          // e = c*64 + u
    int c = e >> 6, u = e & 63;
    w2T[e] = w2[(size_t)u * 32 + c];
  }
}

// ---------------------------------------------------------------------------
// LN over 16 rows x 32 cols at row-stride 34 in LDS, in place. 4 lanes/row.
// (call with tid < 64 only; identical code/order to r4-r12)
// ---------------------------------------------------------------------------
__device__ __forceinline__ void ln_16xS(float* buf, const float* g,
                                        const float* bb, int tid) {
  int row = tid >> 2, sub = tid & 3;
  int c0 = sub << 3;
  float* r = buf + row * 34 + c0;
  float v[8];
  float s = 0.f, s2 = 0.f;
#pragma unroll
  for (int n = 0; n < 8; n++) {
    float t = r[n];
    v[n] = t; s += t; s2 += t * t;
  }
  s += __shfl_xor(s, 1);  s += __shfl_xor(s, 2);
  s2 += __shfl_xor(s2, 1); s2 += __shfl_xor(s2, 2);
  float m = s * (1.0f / 32.0f);
  float var = s2 * (1.0f / 32.0f) - m * m;
  float inv = 1.0f / sqrtf(var + 1e-5f);
#pragma unroll
  for (int n = 0; n < 8; n++)
    r[n] = (v[n] - m) * inv * g[c0 + n] + bb[c0 + n];
}

// ---------------------------------------------------------------------------
// pkA v2 (unchanged from r12).
// ---------------------------------------------------------------------------
__global__ __launch_bounds__(256) void pkA_kernel(
    const float* __restrict__ x, const float* __restrict__ pos,
    const float* __restrict__ win, const float* __restrict__ bin,
    const float* __restrict__ q16, float* __restrict__ so) {
  __shared__ float sxp[2048];
  __shared__ float skv[4096];
  __shared__ float sq16[16 * 33];
  const int blk = blockIdx.x, t = threadIdx.x;
  const int p0 = blk << 2;
  const int cfix = t & 31;

#pragma unroll
  for (int q = 0; q < 8; q++) {
    int e = t + (q << 8);
    int pl = e >> 9, r = e & 511;
    sxp[e] = x[(size_t)(p0 + pl) * 512 + r] + pos[r];
  }
  if (t < 128) {
#pragma unroll
    for (int q = 0; q < 4; q++) {
      int e = t + (q << 7);
      sq16[(e >> 5) * 33 + (e & 31)] = q16[e];
    }
  }

  float wr0[32], wr1[32];
#pragma unroll
  for (int d4 = 0; d4 < 8; d4++) {
    *(float4*)(wr0 + 4 * d4) =
        *(const float4*)(win + (size_t)(32 + cfix) * 32 + 4 * d4);
    *(float4*)(wr1 + 4 * d4) =
        *(const float4*)(win + (size_t)(64 + cfix) * 32 + 4 * d4);
  }
  const float bk = bin[32 + cfix];
  const float bv = bin[64 + cfix];
  __syncthreads();

#pragma unroll
  for (int q = 0; q < 16; q++) {
    int e = t + (q << 8);
    int pl = e >> 10, rr = e & 1023;
    int w = rr >> 9, rj = rr & 511, j = rj >> 5;
    const float* sx = sxp + (pl << 9) + (j << 5);
    const float* wreg = w ? wr1 : wr0;
    float acc = w ? bv : bk;
#pragma unroll
    for (int d = 0; d < 32; d++) acc += sx[d] * wreg[d];
    skv[e] = acc;
  }
  __syncthreads();

  const int pl = t >> 6, hh = (t >> 4) & 3, i = t & 15;
  const int p = p0 + pl;
  const float* kp = skv + (pl << 10);
  const int hd = hh << 3;

  float sc[16];
#pragma unroll
  for (int j = 0; j < 16; j++) {
    float acc = 0.f;
#pragma unroll
    for (int d = 0; d < 8; d++)
      acc += sq16[i * 33 + hd + d] * kp[(j << 5) + hd + d];
    sc[j] = acc * 0.35355339059327373f;
  }
  {
    float mx = sc[0];
#pragma unroll
    for (int j = 1; j < 16; j++) mx = fmaxf(mx, sc[j]);
    float sm = 0.f;
    float ev[16];
#pragma unroll
    for (int j = 0; j < 16; j++) { ev[j] = expf(sc[j] - mx); sm += ev[j]; }
    float inv = 1.0f / sm;
#pragma unroll
    for (int j = 0; j < 16; j++) sc[j] = ev[j] * inv;
  }
  float* orow = so + (size_t)p * 512 + (i << 5) + hd;
#pragma unroll
  for (int c8 = 0; c8 < 8; c8++) {
    const int c = hd + c8;
    float acc = 0.f;
#pragma unroll
    for (int j = 0; j < 16; j++) acc += sc[j] * kp[512 + (j << 5) + c];
    orow[c8] = acc;
  }
}

// ---------------------------------------------------------------------------
// pkB v4: 4 waves per patch (256 thr). Same per-output expressions/order as
// r12 -> z bit-identical. LN + z/split phases run verbatim on wave 0.
// ---------------------------------------------------------------------------
__global__ __launch_bounds__(256) void pkB_kernel(
    const float* __restrict__ so_g, const float* __restrict__ x,
    const float* __restrict__ wout, const float* __restrict__ bout,
    const float* __restrict__ lq,
    const float* __restrict__ ln1g, const float* __restrict__ ln1b,
    const float* __restrict__ w1T, const float* __restrict__ b1,
    const float* __restrict__ w2T, const float* __restrict__ b2,
    const float* __restrict__ ln2g, const float* __restrict__ ln2b,
    float* __restrict__ z, ushort* __restrict__ zh,
    ushort* __restrict__ zl, float* __restrict__ znorm) {
  __shared__ float sso[544], sst[544], ssh[1056];
  const int p = blockIdx.x, t = threadIdx.x;
  const int cfix = t & 31, ufix = t & 63;

  // stage so (512 elems, 2/thread)
#pragma unroll
  for (int q = 0; q < 2; q++) {
    int e = t + (q << 8);
    sso[(e >> 5) * 34 + (e & 31)] = so_g[(size_t)p * 512 + e];
  }

  float wo[32];
#pragma unroll
  for (int d4 = 0; d4 < 8; d4++)
    *(float4*)(wo + 4 * d4) = *(const float4*)(wout + (size_t)cfix * 32 + 4 * d4);
  __syncthreads();

  // out-proj + lq residual (2 outputs/thread, same (i,c)+d-order as r12)
#pragma unroll
  for (int q = 0; q < 2; q++) {
    int e = t + (q << 8);
    int i = e >> 5;
    float acc = bout[cfix];
#pragma unroll
    for (int d = 0; d < 32; d++) acc += sso[i * 34 + d] * wo[d];
    sst[i * 34 + cfix] = acc + lq[(i << 5) + cfix];
  }
  __syncthreads();
  if (t < 64) ln_16xS(sst, ln1g, ln1b, t);

  float w1r[32];
#pragma unroll
  for (int d4 = 0; d4 < 8; d4++)
    *(float4*)(w1r + 4 * d4) = *(const float4*)(w1T + (size_t)ufix * 32 + 4 * d4);
  __syncthreads();

  // FFN1 (4 outputs/thread: i = e>>6, u = e&63)
#pragma unroll
  for (int q = 0; q < 4; q++) {
    int e = t + (q << 8);
    int i = e >> 6;
    float acc = b1[ufix];
#pragma unroll
    for (int d = 0; d < 32; d++) acc += sst[i * 34 + d] * w1r[d];
    ssh[i * 66 + ufix] = gelu_exact(acc);
  }

  float w2r[64];
#pragma unroll
  for (int u4 = 0; u4 < 16; u4++)
    *(float4*)(w2r + 4 * u4) = *(const float4*)(w2T + (size_t)cfix * 64 + 4 * u4);
  __syncthreads();

  // FFN2 + residual (2 outputs/thread)
#pragma unroll
  for (int q = 0; q < 2; q++) {
    int e = t + (q << 8);
    int i = e >> 5;
    float acc = b2[cfix];
#pragma unroll
    for (int u = 0; u < 64; u++) acc += ssh[i * 66 + u] * w2r[u];
    sso[i * 34 + cfix] = acc + sst[i * 34 + cfix];
  }
  __syncthreads();
  if (t < 64) ln_16xS(sso, ln2g, ln2b, t);
  __syncthreads();

  // z + bf16 split + znorm: wave 0, verbatim r12 partition (lane t: 8 elems)
  if (t < 64) {
    const float* xp = x + (size_t)p * 512;
    const int row = t >> 2, c0v = (t & 3) << 3;
    float zv[8];
#pragma unroll
    for (int n = 0; n < 8; n++)
      zv[n] = xp[(t << 3) + n] + sso[row * 34 + c0v + n];
    float* zo = z + (size_t)p * 512 + (t << 3);
    *(float4*)(zo)     = *(float4*)(zv);
    *(float4*)(zo + 4) = *(float4*)(zv + 4);
    ushort8 hv, lv;
    float s2 = 0.f;
#pragma unroll
    for (int n = 0; n < 8; n++) {
      s2 += zv[n] * zv[n];
      ushort h = f2b_rne(zv[n]);
      hv[n] = h;
      lv[n] = f2b_rne(zv[n] - b2f(h));
    }
    *(ushort8*)(zh + (size_t)p * 512 + (t << 3)) = hv;
    *(ushort8*)(zl + (size_t)p * 512 + (t << 3)) = lv;
#pragma unroll
    for (int off = 1; off < 64; off <<= 1) s2 += __shfl_xor(s2, off);
    if (t == 0) znorm[p] = s2;
  }
}

// ---------------------------------------------------------------------------
// cbnorm + bf16 split of the codebook (ch/cl).
// ---------------------------------------------------------------------------
__global__ __launch_bounds__(64) void cbnorm_kernel(
    const float* __restrict__ cb, float* __restrict__ cbn,
    ushort* __restrict__ ch, ushort* __restrict__ cl) {
  int c = blockIdx.x, lane = threadIdx.x;
  const float* r = cb + (size_t)c * 512 + lane * 8;
  float v[8];
  *(float4*)(v)     = *(const float4*)(r);
  *(float4*)(v + 4) = *(const float4*)(r + 4);
  float s = 0.f;
  ushort8 hv, lv;
#pragma unroll
  for (int n = 0; n < 8; n++) {
    s += v[n] * v[n];
    ushort h = f2b_rne(v[n]);
    hv[n] = h;
    lv[n] = f2b_rne(v[n] - b2f(h));
  }
  *(ushort8*)(ch + (size_t)c * 512 + lane * 8) = hv;
  *(ushort8*)(cl + (size_t)c * 512 + lane * 8) = lv;
#pragma unroll
  for (int off = 1; off < 64; off <<= 1) s += __shfl_xor(s, off);
  if (lane == 0) cbn[c] = s;
}

// ---------------------------------------------------------------------------
// VQ scores via bf16x3 MFMA with fused argmin epilogue + XCD swizzle.
// ---------------------------------------------------------------------------
__global__ __launch_bounds__(256) void gemm_vq_b3(
    const ushort* __restrict__ Ah, const ushort* __restrict__ Al,
    const ushort* __restrict__ Bh, const ushort* __restrict__ Bl,
    const float* __restrict__ znorm, const float* __restrict__ cbn,
    u64* __restrict__ packed) {
  __shared__ ushort sAh[4096], sAl[4096], sBh[4096], sBl[4096];
  const int cpx = gridDim.x >> 3;
  const int bid = (blockIdx.x & 7) * cpx + (blockIdx.x >> 3);
  const int bx = bid & 7, by = bid >> 3;
  const int m0 = by << 7, n0 = bx << 7;
  const int tid = threadIdx.x;
  const int wid = tid >> 6, lane = tid & 63;
  const int wr = wid >> 1, wc = wid & 1;
  const int l15 = lane & 15, lk = lane >> 4;

  const f32x4 fzero = {0.f, 0.f, 0.f, 0.f};
  f32x4 acc[4][4];
#pragma unroll
  for (int i = 0; i < 4; i++)
#pragma unroll
    for (int j = 0; j < 4; j++) acc[i][j] = fzero;

  for (int k0 = 0; k0 < 512; k0 += 32) {
#pragma unroll
    for (int c = 0; c < 2; c++) {
      const int I = tid + (c << 8);
      const int r = I >> 2, kk = (I & 3) << 3;
      const size_t ga = (size_t)(m0 + r) * 512 + k0 + kk;
      const size_t gb = (size_t)(n0 + r) * 512 + k0 + kk;
      const size_t lo = (size_t)((wid << 6) + (c << 8)) * 8;
      gload16(Ah + ga, sAh + lo);
      gload16(Al + ga, sAl + lo);
      gload16(Bh + gb, sBh + lo);
      gload16(Bl + gb, sBl + lo);
    }
    __syncthreads();

    short8 ah[4], al[4], bh[4], bl[4];
#pragma unroll
    for (int m = 0; m < 4; m++) {
      const int ar = ((wr << 6) + (m << 4) + l15) * 32 + lk * 8;
      ah[m] = *(const short8*)(sAh + ar);
      al[m] = *(const short8*)(sAl + ar);
      const int br = ((wc << 6) + (m << 4) + l15) * 32 + lk * 8;
      bh[m] = *(const short8*)(sBh + br);
      bl[m] = *(const short8*)(sBl + br);
    }
#pragma unroll
    for (int m = 0; m < 4; m++)
#pragma unroll
      for (int n = 0; n < 4; n++) {
        acc[m][n] = __builtin_amdgcn_mfma_f32_16x16x32_bf16(ah[m], bh[n],
                                                            acc[m][n], 0, 0, 0);
        acc[m][n] = __builtin_amdgcn_mfma_f32_16x16x32_bf16(ah[m], bl[n],
                                                            acc[m][n], 0, 0, 0);
        acc[m][n] = __builtin_amdgcn_mfma_f32_16x16x32_bf16(al[m], bh[n],
                                                            acc[m][n], 0, 0, 0);
      }
    __syncthreads();
  }

  float zn[4][4];
#pragma unroll
  for (int m = 0; m < 4; m++)
#pragma unroll
    for (int r = 0; r < 4; r++)
      zn[m][r] = znorm[m0 + (wr << 6) + (m << 4) + (lk << 2) + r];
  float cbnv[4];
#pragma unroll
  for (int n = 0; n < 4; n++)
    cbnv[n] = cbn[n0 + (wc << 6) + (n << 4) + l15];

#pragma unroll
  for (int m = 0; m < 4; m++) {
#pragma unroll
    for (int r = 0; r < 4; r++) {
      u64 best = ~0ull;
#pragma unroll
      for (int n = 0; n < 4; n++) {
        const int gcol = n0 + (wc << 6) + (n << 4) + l15;
        float d = (zn[m][r] + cbnv[n]) - 2.0f * acc[m][n][r];
        u64 key = ((u64)fkey(d) << 32) | (unsigned)gcol;
        best = best < key ? best : key;
      }
#pragma unroll
      for (int off = 1; off < 16; off <<= 1) {
        u64 o = __shfl_xor(best, off);
        best = best < o ? best : o;
      }
      if (l15 == 0) {
        const int grow = m0 + (wr << 6) + (m << 4) + (lk << 2) + r;
        atomicMin(&packed[grow], best);
      }
    }
  }
}

// ---------------------------------------------------------------------------
// slim VQ finish (per-block loss partial, no same-address atomics).
// ---------------------------------------------------------------------------
__global__ __launch_bounds__(256) void vq_slim_kernel(
    const u64* __restrict__ packed, const float* __restrict__ cb,
    const float* __restrict__ z, const float* __restrict__ tf_pos,
    float* __restrict__ t, ushort* __restrict__ th,
    float* __restrict__ idx_out, float* __restrict__ loss_part) {
  __shared__ float spart[4];
  const int wv = threadIdx.x >> 6;
  const int r = (blockIdx.x << 2) + wv;
  const int lane = threadIdx.x & 63;
  const int bi = (int)(unsigned)(packed[r] & 0xFFFFFFFFull);
  const float* zr = z + (size_t)r * 512 + (lane << 3);
  const float* q = cb + (size_t)bi * 512 + (lane << 3);
  const float* pr = tf_pos + (size_t)(r & 255) * 512 + (lane << 3);
  float zv[8], qv[8], pv[8];
  *(float4*)(zv)     = *(const float4*)(zr);
  *(float4*)(zv + 4) = *(const float4*)(zr + 4);
  *(float4*)(qv)     = *(const float4*)(q);
  *(float4*)(qv + 4) = *(const float4*)(q + 4);
  *(float4*)(pv)     = *(const float4*)(pr);
  *(float4*)(pv + 4) = *(const float4*)(pr + 4);
  float lsum = 0.f;
  float tv[8];
  ushort8 w;
#pragma unroll
  for (int n = 0; n < 8; n++) {
    float diff = qv[n] - zv[n];
    lsum += diff * diff;
    tv[n] = qv[n] + pv[n];
    w[n] = f2b_rne(tv[n]);
  }
  float* to = t + (size_t)r * 512 + (lane << 3);
  *(float4*)(to)     = *(float4*)(tv);
  *(float4*)(to + 4) = *(float4*)(tv + 4);
  *(ushort8*)(th + (size_t)r * 512 + (lane << 3)) = w;
#pragma unroll
  for (int off = 1; off < 64; off <<= 1) lsum += __shfl_xor(lsum, off);
  if (lane == 0) {
    idx_out[r] = (float)bi;
    spart[wv] = lsum;
  }
  __syncthreads();
  if (threadIdx.x == 0)
    loss_part[blockIdx.x] = (spart[0] + spart[1]) + (spart[2] + spart[3]);
}

// ---------------------------------------------------------------------------
__global__ __launch_bounds__(256) void loss_reduce_kernel(
    const float* __restrict__ loss_part, float* __restrict__ loss_out) {
  __shared__ float sw[4];
  float s = 0.f;
  for (int i = threadIdx.x; i < 4096; i += 256) s += loss_part[i];
#pragma unroll
  for (int off = 1; off < 64; off <<= 1) s += __shfl_xor(s, off);
  const int wv = threadIdx.x >> 6;
  if ((threadIdx.x & 63) == 0) sw[wv] = s;
  __syncthreads();
  if (threadIdx.x == 0)
    loss_out[0] = ((sw[0] + sw[1]) + (sw[2] + sw[3])) * (1.25f / 8388608.0f);
}

// ---------------------------------------------------------------------------
// bf16 MFMA GEMM with XCD-aware bijective swizzle (grids all %8==0).
// ---------------------------------------------------------------------------
template <int OUTMODE>
__global__ __launch_bounds__(256) void gemm_bf16_kernel(
    const ushort* __restrict__ A, const ushort* __restrict__ B,
    const float* __restrict__ bias, void* __restrict__ Cout,
    int M, int N, int K) {
  __shared__ ushort As[4096];
  __shared__ ushort Bs[4096];
  const int nbx = N >> 7;
  const int cpx = gridDim.x >> 3;
  const int bid = (blockIdx.x & 7) * cpx + (blockIdx.x >> 3);
  const int bx = bid % nbx, by = bid / nbx;
  const int m0 = by << 7, n0 = bx << 7;
  const int tid = threadIdx.x;
  const int wid = tid >> 6, lane = tid & 63;
  const int wr = wid >> 1, wc = wid & 1;
  const int l15 = lane & 15, lk = lane >> 4;

  const f32x4 fzero = {0.f, 0.f, 0.f, 0.f};
  f32x4 acc[4][4];
#pragma unroll
  for (int i = 0; i < 4; i++)
#pragma unroll
    for (int j = 0; j < 4; j++) acc[i][j] = fzero;

  for (int k0 = 0; k0 < K; k0 += 32) {
#pragma unroll
    for (int c = 0; c < 2; c++) {
      const int I = tid + (c << 8);
      const int r = I >> 2, kk = (I & 3) << 3;
      gload16(A + (size_t)(m0 + r) * K + k0 + kk,
              As + (size_t)((wid << 6) + (c << 8)) * 8);
      gload16(B + (size_t)(n0 + r) * K + k0 + kk,
              Bs + (size_t)((wid << 6) + (c << 8)) * 8);
    }
    __syncthreads();

    short8 a[4], b[4];
#pragma unroll
    for (int m = 0; m < 4; m++) {
      const int ar = (wr << 6) + (m << 4) + l15;
      a[m] = *(const short8*)(As + ar * 32 + lk * 8);
      const int br = (wc << 6) + (m << 4) + l15;
      b[m] = *(const short8*)(Bs + br * 32 + lk * 8);
    }
#pragma unroll
    for (int m = 0; m < 4; m++)
#pragma unroll
      for (int n = 0; n < 4; n++)
        acc[m][n] = __builtin_amdgcn_mfma_f32_16x16x32_bf16(a[m], b[n],
                                                            acc[m][n], 0, 0, 0);
    __syncthreads();
  }

  float bv[4];
#pragma unroll
  for (int n = 0; n < 4; n++)
    bv[n] = bias[n0 + (wc << 6) + (n << 4) + l15];

#pragma unroll
  for (int m = 0; m < 4; m++) {
#pragma unroll
    for (int n = 0; n < 4; n++) {
      const int gcol = n0 + (wc << 6) + (n << 4) + l15;
#pragma unroll
      for (int r = 0; r < 4; r++) {
        const int grow = m0 + (wr << 6) + (m << 4) + (lk << 2) + r;
        float v = acc[m][n][r] + bv[n];
        if (OUTMODE == 0) {
          ((float*)Cout)[(size_t)grow * N + gcol] = v;
        } else if (OUTMODE == 1) {
          ((ushort*)Cout)[(size_t)grow * N + gcol] = f2b_rne(gelu_exact(v));
        } else {
          ((ushort*)Cout)[(size_t)grow * N + gcol] = f2b_rne(v);
        }
      }
    }
  }
}

// ---------------------------------------------------------------------------
// Weight conversions.
// ---------------------------------------------------------------------------
__global__ void cvt_flat(const float* __restrict__ in, ushort* __restrict__ out,
                         int n) {
  int i = blockIdx.x * blockDim.x + threadIdx.x;
  const int stride = gridDim.x * blockDim.x;
  for (; i < n; i += stride) out[i] = f2b_rne(in[i]);
}

__global__ __launch_bounds__(256) void cvt_tr(const float* __restrict__ in,
                                              ushort* __restrict__ out,
                                              int R, int C) {
  __shared__ float tile[32][33];
  const int bc = blockIdx.x, br = blockIdx.y, lay = blockIdx.z;
  const float* src = in + (size_t)lay * R * C;
  ushort* dst = out + (size_t)lay * R * C;
  const int tid = threadIdx.x;
#pragma unroll
  for (int q = 0; q < 4; q++) {
    int idx = tid + (q << 8);
    int rr = idx >> 5, cc = idx & 31;
    tile[rr][cc] = src[(size_t)(br * 32 + rr) * C + bc * 32 + cc];
  }
  __syncthreads();
#pragma unroll
  for (int q = 0; q < 4; q++) {
    int idx = tid + (q << 8);
    int co = idx >> 5, ro = idx & 31;
    dst[(size_t)(bc * 32 + co) * R + br * 32 + ro] = f2b_rne(tile[ro][co]);
  }
}

// ---------------------------------------------------------------------------
// MFMA flash attention (unchanged from r5-r12).
// ---------------------------------------------------------------------------
__global__ __launch_bounds__(64) void attn_mfma_kernel(
    const ushort* __restrict__ qkv, ushort* __restrict__ o) {
  __shared__ ushort lds[8192];
  char* KsB = (char*)lds;
  char* VtB = (char*)(lds + 4096);
  const int bid = blockIdx.x;
  const int xcd = bid & 7, slot = bid >> 3;
  const int b = (xcd << 3) | (slot >> 5);
  const int h = (slot >> 2) & 7;
  const int qb = slot & 3;
  const int lane = threadIdx.x;
  const int l15 = lane & 15, lk4 = lane >> 4;

  short8 qf[4][2];
#pragma unroll
  for (int m = 0; m < 4; m++)
#pragma unroll
    for (int kc = 0; kc < 2; kc++)
      qf[m][kc] = *(const short8*)(qkv +
          (size_t)(b * 256 + qb * 64 + m * 16 + l15) * 1536 +
          h * 64 + kc * 32 + lk4 * 8);

  const f32x4 fz = {0.f, 0.f, 0.f, 0.f};
  f32x4 O[4][4];
#pragma unroll
  for (int m = 0; m < 4; m++)
#pragma unroll
    for (int n = 0; n < 4; n++) O[m][n] = fz;
  float lsum[4][4];
#pragma unroll
  for (int m = 0; m < 4; m++)
#pragma unroll
    for (int r = 0; r < 4; r++) lsum[m][r] = 0.f;

  for (int jt = 0; jt <= qb; jt++) {
    ushort8 kv[8], vv[8];
    const ushort* krow = qkv + (size_t)(b * 256 + jt * 64 + lane) * 1536 +
                         512 + h * 64;
#pragma unroll
    for (int u = 0; u < 8; u++) kv[u] = ((const ushort8*)krow)[u];
#pragma unroll
    for (int u = 0; u < 8; u++) vv[u] = ((const ushort8*)(krow + 512))[u];
    __syncthreads();
    {
      const int rx = (lane & 7) << 4;
#pragma unroll
      for (int u = 0; u < 8; u++)
        *(ushort8*)(KsB + lane * 128 + ((u << 4) ^ rx)) = kv[u];
#pragma unroll
      for (int u = 0; u < 8; u++)
#pragma unroll
        for (int i = 0; i < 8; i++) {
          const int d = u * 8 + i;
          *(ushort*)(VtB + ((d * 128 + lane * 2) ^ ((d & 7) << 4))) =
              (ushort)vv[u][i];
        }
    }
    __syncthreads();

    f32x4 sacc[4][4];
#pragma unroll
    for (int m = 0; m < 4; m++)
#pragma unroll
      for (int n = 0; n < 4; n++) sacc[m][n] = fz;
#pragma unroll
    for (int kc = 0; kc < 2; kc++) {
      short8 bf[4];
#pragma unroll
      for (int n = 0; n < 4; n++) {
        const int row = n * 16 + l15;
        bf[n] = *(const short8*)(KsB + row * 128 +
                                 ((kc * 64 + lk4 * 16) ^ ((row & 7) << 4)));
      }
#pragma unroll
      for (int m = 0; m < 4; m++)
#pragma unroll
        for (int n = 0; n < 4; n++)
          sacc[m][n] = __builtin_amdgcn_mfma_f32_16x16x32_bf16(
              qf[m][kc], bf[n], sacc[m][n], 0, 0, 0);
    }
    __syncthreads();

    const bool diag = (jt == qb);
#pragma unroll
    for (int m = 0; m < 4; m++)
#pragma unroll
      for (int n = 0; n < 4; n++)
#pragma unroll
        for (int r = 0; r < 4; r++) {
          const int ql = m * 16 + lk4 * 4 + r;
          const int jl = n * 16 + l15;
          float e = __expf(sacc[m][n][r] * 0.125f);
          if (diag && jl > ql) e = 0.f;
          const ushort pu = f2b_rne(e);
          lsum[m][r] += b2f(pu);
          *(ushort*)(KsB + ql * 128 + ((jl * 2) ^ ((ql & 7) << 4))) = pu;
        }
    __syncthreads();

#pragma unroll
    for (int kc = 0; kc < 2; kc++) {
      short8 pf[4], vf[4];
#pragma unroll
      for (int m = 0; m < 4; m++) {
        const int row = m * 16 + l15;
        pf[m] = *(const short8*)(KsB + row * 128 +
                                 ((kc * 64 + lk4 * 16) ^ ((row & 7) << 4)));
      }
#pragma unroll
      for (int n = 0; n < 4; n++) {
        const int row = n * 16 + l15;
        vf[n] = *(const short8*)(VtB + row * 128 +
                                 ((kc * 64 + lk4 * 16) ^ ((row & 7) << 4)));
      }
#pragma unroll
      for (int m = 0; m < 4; m++)
#pragma unroll
        for (int n = 0; n < 4; n++)
          O[m][n] = __builtin_amdgcn_mfma_f32_16x16x32_bf16(
              pf[m], vf[n], O[m][n], 0, 0, 0);
    }
  }

  float inv[4][4];
#pragma unroll
  for (int m = 0; m < 4; m++)
#pragma unroll
    for (int r = 0; r < 4; r++) {
      float v = lsum[m][r];
      v += __shfl_xor(v, 1); v += __shfl_xor(v, 2);
      v += __shfl_xor(v, 4); v += __shfl_xor(v, 8);
      inv[m][r] = 1.0f / v;
    }
#pragma unroll
  for (int m = 0; m < 4; m++)
#pragma unroll
    for (int n = 0; n < 4; n++)
#pragma unroll
      for (int r = 0; r < 4; r++) {
        const int row = b * 256 + qb * 64 + m * 16 + lk4 * 4 + r;
        const int col = h * 64 + n * 16 + l15;
        o[(size_t)row * 512 + col] = f2b_rne(O[m][n][r] * inv[m][r]);
      }
}

// ---------------------------------------------------------------------------
// LayerNorm over 512 with optional bf16 residual add.
// out = LN(x [+ b2f(addin_b)]); writes f32 out and optional bf16 copy.
// ---------------------------------------------------------------------------
__global__ __launch_bounds__(256) void ln_kernel(
    const float* __restrict__ xin, const ushort* __restrict__ addin_b,
    const float* __restrict__ g, const float* __restrict__ bb,
    float* __restrict__ outp, ushort* __restrict__ outb) {
  const int r = blockIdx.x * 4 + (threadIdx.x >> 6);
  const int lane = threadIdx.x & 63;
  const float* xr = xin + (size_t)r * 512 + lane * 8;
  float v[8];
  *(float4*)(v)     = *(const float4*)(xr);
  *(float4*)(v + 4) = *(const float4*)(xr + 4);
  if (addin_b) {
    ushort8 a = *(const ushort8*)(addin_b + (size_t)r * 512 + lane * 8);
#pragma unroll
    for (int n = 0; n < 8; n++) v[n] += b2f(a[n]);
  }
  float s = 0.f, s2 = 0.f;
#pragma unroll
  for (int n = 0; n < 8; n++) { s += v[n]; s2 += v[n] * v[n]; }
#pragma unroll
  for (int off = 1; off < 64; off <<= 1) {
    s += __shfl_xor(s, off);
    s2 += __shfl_xor(s2, off);
  }
  float m = s * (1.0f / 512.0f);
  float var = s2 * (1.0f / 512.0f) - m * m;
  float inv = 1.0f / sqrtf(var + 1e-5f);
  const int c0 = lane * 8;
  float outv[8];
#pragma unroll
  for (int n = 0; n < 8; n++) outv[n] = (v[n] - m) * inv * g[c0 + n] + bb[c0 + n];
  float* orow = outp + (size_t)r * 512 + c0;
  *(float4*)(orow)     = *(float4*)(outv);
  *(float4*)(orow + 4) = *(float4*)(outv + 4);
  if (outb) {
    ushort8 w;
#pragma unroll
    for (int n = 0; n < 8; n++) w[n] = f2b_rne(outv[n]);
    *(ushort8*)(outb + (size_t)r * 512 + c0) = w;
  }
}

// ---------------------------------------------------------------------------
extern "C" void kernel_launch(void* const* d_in, const int* in_sizes, int n_in,
                              void* d_out, int out_size, void* d_ws, size_t ws_size,
                              hipStream_t stream) {
  const float* x       = (const float*)d_in[0];
  const float* pa_lq   = (const float*)d_in[1];
  const float* pa_pos  = (const float*)d_in[2];
  const float* pa_win  = (const float*)d_in[3];
  const float* pa_bin  = (const float*)d_in[4];
  const float* pa_wout = (const float*)d_in[5];
  const float* pa_bout = (const float*)d_in[6];
  const float* pa_ln1g = (const float*)d_in[7];
  const float* pa_ln1b = (const float*)d_in[8];
  const float* pa_ln2g = (const float*)d_in[9];
  const float* pa_ln2b = (const float*)d_in[10];
  const float* pa_w1   = (const float*)d_in[11];
  const float* pa_b1   = (const float*)d_in[12];
  const float* pa_w2   = (const float*)d_in[13];
  const float* pa_b2   = (const float*)d_in[14];
  const float* cb      = (const float*)d_in[15];
  const float* tf_pos  = (const float*)d_in[16];
  const float* tf_win  = (const float*)d_in[17];
  const float* tf_bin  = (const float*)d_in[18];
  const float* tf_wout = (const float*)d_in[19];
  const float* tf_bout = (const float*)d_in[20];
  const float* tf_ln1g = (const float*)d_in[21];
  const float* tf_ln1b = (const float*)d_in[22];
  const float* tf_ln2g = (const float*)d_in[23];
  const float* tf_ln2b = (const float*)d_in[24];
  const float* tf_w1   = (const float*)d_in[25];
  const float* tf_b1   = (const float*)d_in[26];
  const float* tf_w2   = (const float*)d_in[27];
  const float* tf_b2   = (const float*)d_in[28];
  const float* fin_g   = (const float*)d_in[29];
  const float* fin_b   = (const float*)d_in[30];

  float* yout = (float*)d_out;            // 16384 x 512
  float* loss_out = yout + 8388608;       // scalar
  float* idx_out = loss_out + 1;          // 16384 (as float)

  float* ws   = (float*)d_ws;
  float* z    = ws;                   // 8388608
  float* tb   = z + 8388608;          // 8388608
  float* bufA = tb + 8388608;         // 16777216 (patch: so ; tf: qkv/ffn-h)
  float* bufC = bufA + 16777216;      // 8388608  (patch: zh/zl ; tf: projh bf16)
  float* wreg = bufC + 8388608;       // 6291456
  float* treg = wreg + 6291456;       // 4194304  (VQ: ch/cl ; tf: tbh)
  float* cbn  = treg + 4194304;       // 1024
  float* q16  = cbn + 1024;           // 512
  float* w1T  = q16 + 512;            // 2048
  float* w2T  = w1T + 2048;           // 2048
  float* znorm = w2T + 2048;          // 16384
  u64*   packed = (u64*)(znorm + 16384);  // 16384 u64
  float* loss_part = (float*)(packed + 16384); // 4096

  ushort* win_b  = (ushort*)wreg;
  ushort* wout_b = win_b + 3145728;
  ushort* w1t_b  = wout_b + 1048576;
  ushort* w2t_b  = w1t_b + 4194304;
  ushort* tbh    = (ushort*)treg;
  ushort* qkvh   = (ushort*)bufA;
  ushort* abh    = (ushort*)z;
  ushort* zh_b   = (ushort*)bufC;
  ushort* zl_b   = zh_b + 8388608;
  ushort* projh  = (ushort*)bufC;          // bf16 proj outputs (zh/zl dead)
  ushort* ch_b   = (ushort*)treg;          // dead before tbh written
  ushort* cl_b   = ch_b + 524288;

  hipMemsetAsync(packed, 0xFF, 16384 * sizeof(u64), stream);
  cbnorm_kernel<<<1024, 64, 0, stream>>>(cb, cbn, ch_b, cl_b);
  patch_setup_kernel<<<1, 64, 0, stream>>>(pa_lq, pa_win, pa_bin, pa_w1,
                                           pa_w2, q16, w1T, w2T);

  pkA_kernel<<<4096, 256, 0, stream>>>(x, pa_pos, pa_win, pa_bin, q16, bufA);
  pkB_kernel<<<16384, 256, 0, stream>>>(bufA, x, pa_wout, pa_bout, pa_lq,
                                        pa_ln1g, pa_ln1b, w1T, pa_b1,
                                        w2T, pa_b2, pa_ln2g, pa_ln2b, z,
                                        zh_b, zl_b, znorm);

  cvt_flat<<<2048, 256, 0, stream>>>(tf_win, win_b, 3145728);
  cvt_flat<<<1024, 256, 0, stream>>>(tf_wout, wout_b, 1048576);
  cvt_tr<<<dim3(64, 16, 4), 256, 0, stream>>>(tf_w1, w1t_b, 512, 2048);
  cvt_tr<<<dim3(16, 64, 4), 256, 0, stream>>>(tf_w2, w2t_b, 2048, 512);

  gemm_vq_b3<<<dim3(1024), 256, 0, stream>>>(zh_b, zl_b, ch_b, cl_b,
                                             znorm, cbn, packed);
  vq_slim_kernel<<<4096, 256, 0, stream>>>(packed, cb, z, tf_pos, tb, tbh,
                                           idx_out, loss_part);
  loss_reduce_kernel<<<1, 256, 0, stream>>>(loss_part, loss_out);

  for (int l = 0; l < 4; l++) {
    gemm_bf16_kernel<2><<<dim3(128 * 12), 256, 0, stream>>>(
        tbh, win_b + (size_t)l * 1536 * 512, tf_bin + l * 1536, qkvh,
        16384, 1536, 512);
    attn_mfma_kernel<<<dim3(2048), 64, 0, stream>>>(qkvh, abh);
    gemm_bf16_kernel<2><<<dim3(128 * 4), 256, 0, stream>>>(
        abh, wout_b + (size_t)l * 512 * 512, tf_bout + l * 512, projh,
        16384, 512, 512);
    ln_kernel<<<dim3(4096), 256, 0, stream>>>(tb, projh, tf_ln1g + l * 512,
                                              tf_ln1b + l * 512, tb, tbh);
    gemm_bf16_kernel<1><<<dim3(128 * 16), 256, 0, stream>>>(
        tbh, w1t_b + (size_t)l * 1048576, tf_b1 + l * 2048, qkvh,
        16384, 2048, 512);
    gemm_bf16_kernel<2><<<dim3(128 * 4), 256, 0, stream>>>(
        qkvh, w2t_b + (size_t)l * 1048576, tf_b2 + l * 512, projh,
        16384, 512, 2048);
    ln_kernel<<<dim3(4096), 256, 0, stream>>>(tb, projh, tf_ln2g + l * 512,
                                              tf_ln2b + l * 512, tb, tbh);
  }
  ln_kernel<<<dim3(4096), 256, 0, stream>>>(tb, nullptr, fin_g, fin_b, yout,
                                            nullptr);

  (void)in_sizes; (void)n_in; (void)out_size; (void)ws_size;
}

// Round 14
// 1369.452 us; speedup vs baseline: 1.0956x; 1.0956x over previous
//
#include <hip/hip_runtime.h>

// PatchVQVAETransformer forward, round 14:
//  - pkB reverted to the r12 64-thread version (r13's 4-wave variant
//    quadrupled per-block weight-register loads and idled waves at LN:
//    123us -> 263us). z bit-identical path restored.
//  - KEPT from r13: wout/ffn2 GEMMs emit bf16, LN adds bf16 residual
//    (saved ~49us, absmax unchanged).

#define SQRT1_2F 0.70710678118654752440f

typedef __attribute__((ext_vector_type(8))) short short8;
typedef __attribute__((ext_vector_type(4))) float f32x4;
typedef __attribute__((ext_vector_type(8))) unsigned short ushort8;
typedef unsigned short ushort;
typedef unsigned long long u64;

__device__ __forceinline__ float gelu_exact(float v) {
  return 0.5f * v * (1.0f + erff(v * SQRT1_2F));
}

__device__ __forceinline__ ushort f2b_rne(float f) {
  unsigned u = __float_as_uint(f);
  unsigned r = (u + 0x7fffu + ((u >> 16) & 1u)) >> 16;
  return (ushort)r;
}

__device__ __forceinline__ float b2f(ushort u) {
  return __uint_as_float(((unsigned)u) << 16);
}

__device__ __forceinline__ void gload16(const void* g, void* l) {
  __builtin_amdgcn_global_load_lds(
      (const __attribute__((address_space(1))) void*)g,
      (__attribute__((address_space(3))) void*)l, 16, 0, 0);
}

// monotone float->u32 (finite inputs): preserves <
__device__ __forceinline__ unsigned fkey(float d) {
  unsigned u = __float_as_uint(d);
  return (u & 0x80000000u) ? ~u : (u | 0x80000000u);
}

// ---------------------------------------------------------------------------
// One-time setup: q16 = lq@wq^T + bq; w1T[u][d]=w1[d][u]; w2T[c][u]=w2[u][c].
// ---------------------------------------------------------------------------
__global__ __launch_bounds__(64) void patch_setup_kernel(
    const float* __restrict__ lq, const float* __restrict__ win,
    const float* __restrict__ bin, const float* __restrict__ w1,
    const float* __restrict__ w2, float* __restrict__ q16,
    float* __restrict__ w1T, float* __restrict__ w2T) {
  const int tid = threadIdx.x;
#pragma unroll
  for (int q = 0; q < 8; q++) {
    int e = tid + (q << 6);
    int i = e >> 5, c = e & 31;
    const float* wr = win + (size_t)c * 32;
    float acc = bin[c];
#pragma unroll
    for (int d = 0; d < 32; d++) acc += lq[(i << 5) + d] * wr[d];
    q16[e] = acc;
  }
#pragma unroll
  for (int q = 0; q < 32; q++) {
    int e = tid + (q << 6);          // e = u*32 + d
    int u = e >> 5, d = e & 31;
    w1T[e] = w1[(size_t)d * 64 + u];
  }
#pragma unroll
  for (int q = 0; q < 32; q++) {
    int e = tid + (q << 6);          // e = c*64 + u
    int c = e >> 6, u = e & 63;
    w2T[e] = w2[(size_t)u * 32 + c];
  }
}

// ---------------------------------------------------------------------------
// LN over 16 rows x 32 cols at row-stride 34 in LDS, in place. 4 lanes/row.
// ---------------------------------------------------------------------------
__device__ __forceinline__ void ln_16xS(float* buf, const float* g,
                                        const float* bb, int tid) {
  int row = tid >> 2, sub = tid & 3;
  int c0 = sub << 3;
  float* r = buf + row * 34 + c0;
  float v[8];
  float s = 0.f, s2 = 0.f;
#pragma unroll
  for (int n = 0; n < 8; n++) {
    float t = r[n];
    v[n] = t; s += t; s2 += t * t;
  }
  s += __shfl_xor(s, 1);  s += __shfl_xor(s, 2);
  s2 += __shfl_xor(s2, 1); s2 += __shfl_xor(s2, 2);
  float m = s * (1.0f / 32.0f);
  float var = s2 * (1.0f / 32.0f) - m * m;
  float inv = 1.0f / sqrtf(var + 1e-5f);
#pragma unroll
  for (int n = 0; n < 8; n++)
    r[n] = (v[n] - m) * inv * g[c0 + n] + bb[c0 + n];
}

// ---------------------------------------------------------------------------
// pkA v2 (unchanged from r12/r13).
// ---------------------------------------------------------------------------
__global__ __launch_bounds__(256) void pkA_kernel(
    const float* __restrict__ x, const float* __restrict__ pos,
    const float* __restrict__ win, const float* __restrict__ bin,
    const float* __restrict__ q16, float* __restrict__ so) {
  __shared__ float sxp[2048];
  __shared__ float skv[4096];
  __shared__ float sq16[16 * 33];
  const int blk = blockIdx.x, t = threadIdx.x;
  const int p0 = blk << 2;
  const int cfix = t & 31;

#pragma unroll
  for (int q = 0; q < 8; q++) {
    int e = t + (q << 8);
    int pl = e >> 9, r = e & 511;
    sxp[e] = x[(size_t)(p0 + pl) * 512 + r] + pos[r];
  }
  if (t < 128) {
#pragma unroll
    for (int q = 0; q < 4; q++) {
      int e = t + (q << 7);
      sq16[(e >> 5) * 33 + (e & 31)] = q16[e];
    }
  }

  float wr0[32], wr1[32];
#pragma unroll
  for (int d4 = 0; d4 < 8; d4++) {
    *(float4*)(wr0 + 4 * d4) =
        *(const float4*)(win + (size_t)(32 + cfix) * 32 + 4 * d4);
    *(float4*)(wr1 + 4 * d4) =
        *(const float4*)(win + (size_t)(64 + cfix) * 32 + 4 * d4);
  }
  const float bk = bin[32 + cfix];
  const float bv = bin[64 + cfix];
  __syncthreads();

#pragma unroll
  for (int q = 0; q < 16; q++) {
    int e = t + (q << 8);
    int pl = e >> 10, rr = e & 1023;
    int w = rr >> 9, rj = rr & 511, j = rj >> 5;
    const float* sx = sxp + (pl << 9) + (j << 5);
    const float* wreg = w ? wr1 : wr0;
    float acc = w ? bv : bk;
#pragma unroll
    for (int d = 0; d < 32; d++) acc += sx[d] * wreg[d];
    skv[e] = acc;
  }
  __syncthreads();

  const int pl = t >> 6, hh = (t >> 4) & 3, i = t & 15;
  const int p = p0 + pl;
  const float* kp = skv + (pl << 10);
  const int hd = hh << 3;

  float sc[16];
#pragma unroll
  for (int j = 0; j < 16; j++) {
    float acc = 0.f;
#pragma unroll
    for (int d = 0; d < 8; d++)
      acc += sq16[i * 33 + hd + d] * kp[(j << 5) + hd + d];
    sc[j] = acc * 0.35355339059327373f;
  }
  {
    float mx = sc[0];
#pragma unroll
    for (int j = 1; j < 16; j++) mx = fmaxf(mx, sc[j]);
    float sm = 0.f;
    float ev[16];
#pragma unroll
    for (int j = 0; j < 16; j++) { ev[j] = expf(sc[j] - mx); sm += ev[j]; }
    float inv = 1.0f / sm;
#pragma unroll
    for (int j = 0; j < 16; j++) sc[j] = ev[j] * inv;
  }
  float* orow = so + (size_t)p * 512 + (i << 5) + hd;
#pragma unroll
  for (int c8 = 0; c8 < 8; c8++) {
    const int c = hd + c8;
    float acc = 0.f;
#pragma unroll
    for (int j = 0; j < 16; j++) acc += sc[j] * kp[512 + (j << 5) + c];
    orow[c8] = acc;
  }
}

// ---------------------------------------------------------------------------
// pkB v3 (r12 64-thread version, restored): weight columns register-resident.
// z bit-identical.
// ---------------------------------------------------------------------------
__global__ __launch_bounds__(64) void pkB_kernel(
    const float* __restrict__ so_g, const float* __restrict__ x,
    const float* __restrict__ wout, const float* __restrict__ bout,
    const float* __restrict__ lq,
    const float* __restrict__ ln1g, const float* __restrict__ ln1b,
    const float* __restrict__ w1T, const float* __restrict__ b1,
    const float* __restrict__ w2T, const float* __restrict__ b2,
    const float* __restrict__ ln2g, const float* __restrict__ ln2b,
    float* __restrict__ z, ushort* __restrict__ zh,
    ushort* __restrict__ zl, float* __restrict__ znorm) {
  __shared__ float sso[544], sst[544], ssh[1056];
  const int p = blockIdx.x, t = threadIdx.x;
  const int cfix = t & 31;

#pragma unroll
  for (int q = 0; q < 8; q++) {
    int e = t + (q << 6);
    sso[(e >> 5) * 34 + (e & 31)] = so_g[(size_t)p * 512 + e];
  }

  float wo[32];
#pragma unroll
  for (int d4 = 0; d4 < 8; d4++)
    *(float4*)(wo + 4 * d4) = *(const float4*)(wout + (size_t)cfix * 32 + 4 * d4);
  __syncthreads();

#pragma unroll
  for (int q = 0; q < 8; q++) {
    int e = t + (q << 6);
    int i = e >> 5;
    float acc = bout[cfix];
#pragma unroll
    for (int d = 0; d < 32; d++) acc += sso[i * 34 + d] * wo[d];
    sst[i * 34 + cfix] = acc + lq[(i << 5) + cfix];
  }
  __syncthreads();
  ln_16xS(sst, ln1g, ln1b, t);

  float w1r[32];
#pragma unroll
  for (int d4 = 0; d4 < 8; d4++)
    *(float4*)(w1r + 4 * d4) = *(const float4*)(w1T + (size_t)t * 32 + 4 * d4);
  __syncthreads();

#pragma unroll
  for (int q = 0; q < 16; q++) {
    int i = q;
    float acc = b1[t];
#pragma unroll
    for (int d = 0; d < 32; d++) acc += sst[i * 34 + d] * w1r[d];
    ssh[i * 66 + t] = gelu_exact(acc);
  }

  float w2r[64];
#pragma unroll
  for (int u4 = 0; u4 < 16; u4++)
    *(float4*)(w2r + 4 * u4) = *(const float4*)(w2T + (size_t)cfix * 64 + 4 * u4);
  __syncthreads();

#pragma unroll
  for (int q = 0; q < 8; q++) {
    int e = t + (q << 6);
    int i = e >> 5;
    float acc = b2[cfix];
#pragma unroll
    for (int u = 0; u < 64; u++) acc += ssh[i * 66 + u] * w2r[u];
    sso[i * 34 + cfix] = acc + sst[i * 34 + cfix];
  }
  __syncthreads();
  ln_16xS(sso, ln2g, ln2b, t);
  __syncthreads();

  const float* xp = x + (size_t)p * 512;
  const int row = t >> 2, c0v = (t & 3) << 3;
  float zv[8];
#pragma unroll
  for (int n = 0; n < 8; n++)
    zv[n] = xp[(t << 3) + n] + sso[row * 34 + c0v + n];
  float* zo = z + (size_t)p * 512 + (t << 3);
  *(float4*)(zo)     = *(float4*)(zv);
  *(float4*)(zo + 4) = *(float4*)(zv + 4);
  ushort8 hv, lv;
  float s2 = 0.f;
#pragma unroll
  for (int n = 0; n < 8; n++) {
    s2 += zv[n] * zv[n];
    ushort h = f2b_rne(zv[n]);
    hv[n] = h;
    lv[n] = f2b_rne(zv[n] - b2f(h));
  }
  *(ushort8*)(zh + (size_t)p * 512 + (t << 3)) = hv;
  *(ushort8*)(zl + (size_t)p * 512 + (t << 3)) = lv;
#pragma unroll
  for (int off = 1; off < 64; off <<= 1) s2 += __shfl_xor(s2, off);
  if (t == 0) znorm[p] = s2;
}

// ---------------------------------------------------------------------------
// cbnorm + bf16 split of the codebook (ch/cl).
// ---------------------------------------------------------------------------
__global__ __launch_bounds__(64) void cbnorm_kernel(
    const float* __restrict__ cb, float* __restrict__ cbn,
    ushort* __restrict__ ch, ushort* __restrict__ cl) {
  int c = blockIdx.x, lane = threadIdx.x;
  const float* r = cb + (size_t)c * 512 + lane * 8;
  float v[8];
  *(float4*)(v)     = *(const float4*)(r);
  *(float4*)(v + 4) = *(const float4*)(r + 4);
  float s = 0.f;
  ushort8 hv, lv;
#pragma unroll
  for (int n = 0; n < 8; n++) {
    s += v[n] * v[n];
    ushort h = f2b_rne(v[n]);
    hv[n] = h;
    lv[n] = f2b_rne(v[n] - b2f(h));
  }
  *(ushort8*)(ch + (size_t)c * 512 + lane * 8) = hv;
  *(ushort8*)(cl + (size_t)c * 512 + lane * 8) = lv;
#pragma unroll
  for (int off = 1; off < 64; off <<= 1) s += __shfl_xor(s, off);
  if (lane == 0) cbn[c] = s;
}

// ---------------------------------------------------------------------------
// VQ scores via bf16x3 MFMA with fused argmin epilogue + XCD swizzle.
// ---------------------------------------------------------------------------
__global__ __launch_bounds__(256) void gemm_vq_b3(
    const ushort* __restrict__ Ah, const ushort* __restrict__ Al,
    const ushort* __restrict__ Bh, const ushort* __restrict__ Bl,
    const float* __restrict__ znorm, const float* __restrict__ cbn,
    u64* __restrict__ packed) {
  __shared__ ushort sAh[4096], sAl[4096], sBh[4096], sBl[4096];
  const int cpx = gridDim.x >> 3;
  const int bid = (blockIdx.x & 7) * cpx + (blockIdx.x >> 3);
  const int bx = bid & 7, by = bid >> 3;
  const int m0 = by << 7, n0 = bx << 7;
  const int tid = threadIdx.x;
  const int wid = tid >> 6, lane = tid & 63;
  const int wr = wid >> 1, wc = wid & 1;
  const int l15 = lane & 15, lk = lane >> 4;

  const f32x4 fzero = {0.f, 0.f, 0.f, 0.f};
  f32x4 acc[4][4];
#pragma unroll
  for (int i = 0; i < 4; i++)
#pragma unroll
    for (int j = 0; j < 4; j++) acc[i][j] = fzero;

  for (int k0 = 0; k0 < 512; k0 += 32) {
#pragma unroll
    for (int c = 0; c < 2; c++) {
      const int I = tid + (c << 8);
      const int r = I >> 2, kk = (I & 3) << 3;
      const size_t ga = (size_t)(m0 + r) * 512 + k0 + kk;
      const size_t gb = (size_t)(n0 + r) * 512 + k0 + kk;
      const size_t lo = (size_t)((wid << 6) + (c << 8)) * 8;
      gload16(Ah + ga, sAh + lo);
      gload16(Al + ga, sAl + lo);
      gload16(Bh + gb, sBh + lo);
      gload16(Bl + gb, sBl + lo);
    }
    __syncthreads();

    short8 ah[4], al[4], bh[4], bl[4];
#pragma unroll
    for (int m = 0; m < 4; m++) {
      const int ar = ((wr << 6) + (m << 4) + l15) * 32 + lk * 8;
      ah[m] = *(const short8*)(sAh + ar);
      al[m] = *(const short8*)(sAl + ar);
      const int br = ((wc << 6) + (m << 4) + l15) * 32 + lk * 8;
      bh[m] = *(const short8*)(sBh + br);
      bl[m] = *(const short8*)(sBl + br);
    }
#pragma unroll
    for (int m = 0; m < 4; m++)
#pragma unroll
      for (int n = 0; n < 4; n++) {
        acc[m][n] = __builtin_amdgcn_mfma_f32_16x16x32_bf16(ah[m], bh[n],
                                                            acc[m][n], 0, 0, 0);
        acc[m][n] = __builtin_amdgcn_mfma_f32_16x16x32_bf16(ah[m], bl[n],
                                                            acc[m][n], 0, 0, 0);
        acc[m][n] = __builtin_amdgcn_mfma_f32_16x16x32_bf16(al[m], bh[n],
                                                            acc[m][n], 0, 0, 0);
      }
    __syncthreads();
  }

  float zn[4][4];
#pragma unroll
  for (int m = 0; m < 4; m++)
#pragma unroll
    for (int r = 0; r < 4; r++)
      zn[m][r] = znorm[m0 + (wr << 6) + (m << 4) + (lk << 2) + r];
  float cbnv[4];
#pragma unroll
  for (int n = 0; n < 4; n++)
    cbnv[n] = cbn[n0 + (wc << 6) + (n << 4) + l15];

#pragma unroll
  for (int m = 0; m < 4; m++) {
#pragma unroll
    for (int r = 0; r < 4; r++) {
      u64 best = ~0ull;
#pragma unroll
      for (int n = 0; n < 4; n++) {
        const int gcol = n0 + (wc << 6) + (n << 4) + l15;
        float d = (zn[m][r] + cbnv[n]) - 2.0f * acc[m][n][r];
        u64 key = ((u64)fkey(d) << 32) | (unsigned)gcol;
        best = best < key ? best : key;
      }
#pragma unroll
      for (int off = 1; off < 16; off <<= 1) {
        u64 o = __shfl_xor(best, off);
        best = best < o ? best : o;
      }
      if (l15 == 0) {
        const int grow = m0 + (wr << 6) + (m << 4) + (lk << 2) + r;
        atomicMin(&packed[grow], best);
      }
    }
  }
}

// ---------------------------------------------------------------------------
// slim VQ finish (per-block loss partial, no same-address atomics).
// ---------------------------------------------------------------------------
__global__ __launch_bounds__(256) void vq_slim_kernel(
    const u64* __restrict__ packed, const float* __restrict__ cb,
    const float* __restrict__ z, const float* __restrict__ tf_pos,
    float* __restrict__ t, ushort* __restrict__ th,
    float* __restrict__ idx_out, float* __restrict__ loss_part) {
  __shared__ float spart[4];
  const int wv = threadIdx.x >> 6;
  const int r = (blockIdx.x << 2) + wv;
  const int lane = threadIdx.x & 63;
  const int bi = (int)(unsigned)(packed[r] & 0xFFFFFFFFull);
  const float* zr = z + (size_t)r * 512 + (lane << 3);
  const float* q = cb + (size_t)bi * 512 + (lane << 3);
  const float* pr = tf_pos + (size_t)(r & 255) * 512 + (lane << 3);
  float zv[8], qv[8], pv[8];
  *(float4*)(zv)     = *(const float4*)(zr);
  *(float4*)(zv + 4) = *(const float4*)(zr + 4);
  *(float4*)(qv)     = *(const float4*)(q);
  *(float4*)(qv + 4) = *(const float4*)(q + 4);
  *(float4*)(pv)     = *(const float4*)(pr);
  *(float4*)(pv + 4) = *(const float4*)(pr + 4);
  float lsum = 0.f;
  float tv[8];
  ushort8 w;
#pragma unroll
  for (int n = 0; n < 8; n++) {
    float diff = qv[n] - zv[n];
    lsum += diff * diff;
    tv[n] = qv[n] + pv[n];
    w[n] = f2b_rne(tv[n]);
  }
  float* to = t + (size_t)r * 512 + (lane << 3);
  *(float4*)(to)     = *(float4*)(tv);
  *(float4*)(to + 4) = *(float4*)(tv + 4);
  *(ushort8*)(th + (size_t)r * 512 + (lane << 3)) = w;
#pragma unroll
  for (int off = 1; off < 64; off <<= 1) lsum += __shfl_xor(lsum, off);
  if (lane == 0) {
    idx_out[r] = (float)bi;
    spart[wv] = lsum;
  }
  __syncthreads();
  if (threadIdx.x == 0)
    loss_part[blockIdx.x] = (spart[0] + spart[1]) + (spart[2] + spart[3]);
}

// ---------------------------------------------------------------------------
__global__ __launch_bounds__(256) void loss_reduce_kernel(
    const float* __restrict__ loss_part, float* __restrict__ loss_out) {
  __shared__ float sw[4];
  float s = 0.f;
  for (int i = threadIdx.x; i < 4096; i += 256) s += loss_part[i];
#pragma unroll
  for (int off = 1; off < 64; off <<= 1) s += __shfl_xor(s, off);
  const int wv = threadIdx.x >> 6;
  if ((threadIdx.x & 63) == 0) sw[wv] = s;
  __syncthreads();
  if (threadIdx.x == 0)
    loss_out[0] = ((sw[0] + sw[1]) + (sw[2] + sw[3])) * (1.25f / 8388608.0f);
}

// ---------------------------------------------------------------------------
// bf16 MFMA GEMM with XCD-aware bijective swizzle (grids all %8==0).
// ---------------------------------------------------------------------------
template <int OUTMODE>
__global__ __launch_bounds__(256) void gemm_bf16_kernel(
    const ushort* __restrict__ A, const ushort* __restrict__ B,
    const float* __restrict__ bias, void* __restrict__ Cout,
    int M, int N, int K) {
  __shared__ ushort As[4096];
  __shared__ ushort Bs[4096];
  const int nbx = N >> 7;
  const int cpx = gridDim.x >> 3;
  const int bid = (blockIdx.x & 7) * cpx + (blockIdx.x >> 3);
  const int bx = bid % nbx, by = bid / nbx;
  const int m0 = by << 7, n0 = bx << 7;
  const int tid = threadIdx.x;
  const int wid = tid >> 6, lane = tid & 63;
  const int wr = wid >> 1, wc = wid & 1;
  const int l15 = lane & 15, lk = lane >> 4;

  const f32x4 fzero = {0.f, 0.f, 0.f, 0.f};
  f32x4 acc[4][4];
#pragma unroll
  for (int i = 0; i < 4; i++)
#pragma unroll
    for (int j = 0; j < 4; j++) acc[i][j] = fzero;

  for (int k0 = 0; k0 < K; k0 += 32) {
#pragma unroll
    for (int c = 0; c < 2; c++) {
      const int I = tid + (c << 8);
      const int r = I >> 2, kk = (I & 3) << 3;
      gload16(A + (size_t)(m0 + r) * K + k0 + kk,
              As + (size_t)((wid << 6) + (c << 8)) * 8);
      gload16(B + (size_t)(n0 + r) * K + k0 + kk,
              Bs + (size_t)((wid << 6) + (c << 8)) * 8);
    }
    __syncthreads();

    short8 a[4], b[4];
#pragma unroll
    for (int m = 0; m < 4; m++) {
      const int ar = (wr << 6) + (m << 4) + l15;
      a[m] = *(const short8*)(As + ar * 32 + lk * 8);
      const int br = (wc << 6) + (m << 4) + l15;
      b[m] = *(const short8*)(Bs + br * 32 + lk * 8);
    }
#pragma unroll
    for (int m = 0; m < 4; m++)
#pragma unroll
      for (int n = 0; n < 4; n++)
        acc[m][n] = __builtin_amdgcn_mfma_f32_16x16x32_bf16(a[m], b[n],
                                                            acc[m][n], 0, 0, 0);
    __syncthreads();
  }

  float bv[4];
#pragma unroll
  for (int n = 0; n < 4; n++)
    bv[n] = bias[n0 + (wc << 6) + (n << 4) + l15];

#pragma unroll
  for (int m = 0; m < 4; m++) {
#pragma unroll
    for (int n = 0; n < 4; n++) {
      const int gcol = n0 + (wc << 6) + (n << 4) + l15;
#pragma unroll
      for (int r = 0; r < 4; r++) {
        const int grow = m0 + (wr << 6) + (m << 4) + (lk << 2) + r;
        float v = acc[m][n][r] + bv[n];
        if (OUTMODE == 0) {
          ((float*)Cout)[(size_t)grow * N + gcol] = v;
        } else if (OUTMODE == 1) {
          ((ushort*)Cout)[(size_t)grow * N + gcol] = f2b_rne(gelu_exact(v));
        } else {
          ((ushort*)Cout)[(size_t)grow * N + gcol] = f2b_rne(v);
        }
      }
    }
  }
}

// ---------------------------------------------------------------------------
// Weight conversions.
// ---------------------------------------------------------------------------
__global__ void cvt_flat(const float* __restrict__ in, ushort* __restrict__ out,
                         int n) {
  int i = blockIdx.x * blockDim.x + threadIdx.x;
  const int stride = gridDim.x * blockDim.x;
  for (; i < n; i += stride) out[i] = f2b_rne(in[i]);
}

__global__ __launch_bounds__(256) void cvt_tr(const float* __restrict__ in,
                                              ushort* __restrict__ out,
                                              int R, int C) {
  __shared__ float tile[32][33];
  const int bc = blockIdx.x, br = blockIdx.y, lay = blockIdx.z;
  const float* src = in + (size_t)lay * R * C;
  ushort* dst = out + (size_t)lay * R * C;
  const int tid = threadIdx.x;
#pragma unroll
  for (int q = 0; q < 4; q++) {
    int idx = tid + (q << 8);
    int rr = idx >> 5, cc = idx & 31;
    tile[rr][cc] = src[(size_t)(br * 32 + rr) * C + bc * 32 + cc];
  }
  __syncthreads();
#pragma unroll
  for (int q = 0; q < 4; q++) {
    int idx = tid + (q << 8);
    int co = idx >> 5, ro = idx & 31;
    dst[(size_t)(bc * 32 + co) * R + br * 32 + ro] = f2b_rne(tile[ro][co]);
  }
}

// ---------------------------------------------------------------------------
// MFMA flash attention (unchanged from r5-r13).
// ---------------------------------------------------------------------------
__global__ __launch_bounds__(64) void attn_mfma_kernel(
    const ushort* __restrict__ qkv, ushort* __restrict__ o) {
  __shared__ ushort lds[8192];
  char* KsB = (char*)lds;
  char* VtB = (char*)(lds + 4096);
  const int bid = blockIdx.x;
  const int xcd = bid & 7, slot = bid >> 3;
  const int b = (xcd << 3) | (slot >> 5);
  const int h = (slot >> 2) & 7;
  const int qb = slot & 3;
  const int lane = threadIdx.x;
  const int l15 = lane & 15, lk4 = lane >> 4;

  short8 qf[4][2];
#pragma unroll
  for (int m = 0; m < 4; m++)
#pragma unroll
    for (int kc = 0; kc < 2; kc++)
      qf[m][kc] = *(const short8*)(qkv +
          (size_t)(b * 256 + qb * 64 + m * 16 + l15) * 1536 +
          h * 64 + kc * 32 + lk4 * 8);

  const f32x4 fz = {0.f, 0.f, 0.f, 0.f};
  f32x4 O[4][4];
#pragma unroll
  for (int m = 0; m < 4; m++)
#pragma unroll
    for (int n = 0; n < 4; n++) O[m][n] = fz;
  float lsum[4][4];
#pragma unroll
  for (int m = 0; m < 4; m++)
#pragma unroll
    for (int r = 0; r < 4; r++) lsum[m][r] = 0.f;

  for (int jt = 0; jt <= qb; jt++) {
    ushort8 kv[8], vv[8];
    const ushort* krow = qkv + (size_t)(b * 256 + jt * 64 + lane) * 1536 +
                         512 + h * 64;
#pragma unroll
    for (int u = 0; u < 8; u++) kv[u] = ((const ushort8*)krow)[u];
#pragma unroll
    for (int u = 0; u < 8; u++) vv[u] = ((const ushort8*)(krow + 512))[u];
    __syncthreads();
    {
      const int rx = (lane & 7) << 4;
#pragma unroll
      for (int u = 0; u < 8; u++)
        *(ushort8*)(KsB + lane * 128 + ((u << 4) ^ rx)) = kv[u];
#pragma unroll
      for (int u = 0; u < 8; u++)
#pragma unroll
        for (int i = 0; i < 8; i++) {
          const int d = u * 8 + i;
          *(ushort*)(VtB + ((d * 128 + lane * 2) ^ ((d & 7) << 4))) =
              (ushort)vv[u][i];
        }
    }
    __syncthreads();

    f32x4 sacc[4][4];
#pragma unroll
    for (int m = 0; m < 4; m++)
#pragma unroll
      for (int n = 0; n < 4; n++) sacc[m][n] = fz;
#pragma unroll
    for (int kc = 0; kc < 2; kc++) {
      short8 bf[4];
#pragma unroll
      for (int n = 0; n < 4; n++) {
        const int row = n * 16 + l15;
        bf[n] = *(const short8*)(KsB + row * 128 +
                                 ((kc * 64 + lk4 * 16) ^ ((row & 7) << 4)));
      }
#pragma unroll
      for (int m = 0; m < 4; m++)
#pragma unroll
        for (int n = 0; n < 4; n++)
          sacc[m][n] = __builtin_amdgcn_mfma_f32_16x16x32_bf16(
              qf[m][kc], bf[n], sacc[m][n], 0, 0, 0);
    }
    __syncthreads();

    const bool diag = (jt == qb);
#pragma unroll
    for (int m = 0; m < 4; m++)
#pragma unroll
      for (int n = 0; n < 4; n++)
#pragma unroll
        for (int r = 0; r < 4; r++) {
          const int ql = m * 16 + lk4 * 4 + r;
          const int jl = n * 16 + l15;
          float e = __expf(sacc[m][n][r] * 0.125f);
          if (diag && jl > ql) e = 0.f;
          const ushort pu = f2b_rne(e);
          lsum[m][r] += b2f(pu);
          *(ushort*)(KsB + ql * 128 + ((jl * 2) ^ ((ql & 7) << 4))) = pu;
        }
    __syncthreads();

#pragma unroll
    for (int kc = 0; kc < 2; kc++) {
      short8 pf[4], vf[4];
#pragma unroll
      for (int m = 0; m < 4; m++) {
        const int row = m * 16 + l15;
        pf[m] = *(const short8*)(KsB + row * 128 +
                                 ((kc * 64 + lk4 * 16) ^ ((row & 7) << 4)));
      }
#pragma unroll
      for (int n = 0; n < 4; n++) {
        const int row = n * 16 + l15;
        vf[n] = *(const short8*)(VtB + row * 128 +
                                 ((kc * 64 + lk4 * 16) ^ ((row & 7) << 4)));
      }
#pragma unroll
      for (int m = 0; m < 4; m++)
#pragma unroll
        for (int n = 0; n < 4; n++)
          O[m][n] = __builtin_amdgcn_mfma_f32_16x16x32_bf16(
              pf[m], vf[n], O[m][n], 0, 0, 0);
    }
  }

  float inv[4][4];
#pragma unroll
  for (int m = 0; m < 4; m++)
#pragma unroll
    for (int r = 0; r < 4; r++) {
      float v = lsum[m][r];
      v += __shfl_xor(v, 1); v += __shfl_xor(v, 2);
      v += __shfl_xor(v, 4); v += __shfl_xor(v, 8);
      inv[m][r] = 1.0f / v;
    }
#pragma unroll
  for (int m = 0; m < 4; m++)
#pragma unroll
    for (int n = 0; n < 4; n++)
#pragma unroll
      for (int r = 0; r < 4; r++) {
        const int row = b * 256 + qb * 64 + m * 16 + lk4 * 4 + r;
        const int col = h * 64 + n * 16 + l15;
        o[(size_t)row * 512 + col] = f2b_rne(O[m][n][r] * inv[m][r]);
      }
}

// ---------------------------------------------------------------------------
// LayerNorm over 512 with optional bf16 residual add.
// ---------------------------------------------------------------------------
__global__ __launch_bounds__(256) void ln_kernel(
    const float* __restrict__ xin, const ushort* __restrict__ addin_b,
    const float* __restrict__ g, const float* __restrict__ bb,
    float* __restrict__ outp, ushort* __restrict__ outb) {
  const int r = blockIdx.x * 4 + (threadIdx.x >> 6);
  const int lane = threadIdx.x & 63;
  const float* xr = xin + (size_t)r * 512 + lane * 8;
  float v[8];
  *(float4*)(v)     = *(const float4*)(xr);
  *(float4*)(v + 4) = *(const float4*)(xr + 4);
  if (addin_b) {
    ushort8 a = *(const ushort8*)(addin_b + (size_t)r * 512 + lane * 8);
#pragma unroll
    for (int n = 0; n < 8; n++) v[n] += b2f(a[n]);
  }
  float s = 0.f, s2 = 0.f;
#pragma unroll
  for (int n = 0; n < 8; n++) { s += v[n]; s2 += v[n] * v[n]; }
#pragma unroll
  for (int off = 1; off < 64; off <<= 1) {
    s += __shfl_xor(s, off);
    s2 += __shfl_xor(s2, off);
  }
  float m = s * (1.0f / 512.0f);
  float var = s2 * (1.0f / 512.0f) - m * m;
  float inv = 1.0f / sqrtf(var + 1e-5f);
  const int c0 = lane * 8;
  float outv[8];
#pragma unroll
  for (int n = 0; n < 8; n++) outv[n] = (v[n] - m) * inv * g[c0 + n] + bb[c0 + n];
  float* orow = outp + (size_t)r * 512 + c0;
  *(float4*)(orow)     = *(float4*)(outv);
  *(float4*)(orow + 4) = *(float4*)(outv + 4);
  if (outb) {
    ushort8 w;
#pragma unroll
    for (int n = 0; n < 8; n++) w[n] = f2b_rne(outv[n]);
    *(ushort8*)(outb + (size_t)r * 512 + c0) = w;
  }
}

// ---------------------------------------------------------------------------
extern "C" void kernel_launch(void* const* d_in, const int* in_sizes, int n_in,
                              void* d_out, int out_size, void* d_ws, size_t ws_size,
                              hipStream_t stream) {
  const float* x       = (const float*)d_in[0];
  const float* pa_lq   = (const float*)d_in[1];
  const float* pa_pos  = (const float*)d_in[2];
  const float* pa_win  = (const float*)d_in[3];
  const float* pa_bin  = (const float*)d_in[4];
  const float* pa_wout = (const float*)d_in[5];
  const float* pa_bout = (const float*)d_in[6];
  const float* pa_ln1g = (const float*)d_in[7];
  const float* pa_ln1b = (const float*)d_in[8];
  const float* pa_ln2g = (const float*)d_in[9];
  const float* pa_ln2b = (const float*)d_in[10];
  const float* pa_w1   = (const float*)d_in[11];
  const float* pa_b1   = (const float*)d_in[12];
  const float* pa_w2   = (const float*)d_in[13];
  const float* pa_b2   = (const float*)d_in[14];
  const float* cb      = (const float*)d_in[15];
  const float* tf_pos  = (const float*)d_in[16];
  const float* tf_win  = (const float*)d_in[17];
  const float* tf_bin  = (const float*)d_in[18];
  const float* tf_wout = (const float*)d_in[19];
  const float* tf_bout = (const float*)d_in[20];
  const float* tf_ln1g = (const float*)d_in[21];
  const float* tf_ln1b = (const float*)d_in[22];
  const float* tf_ln2g = (const float*)d_in[23];
  const float* tf_ln2b = (const float*)d_in[24];
  const float* tf_w1   = (const float*)d_in[25];
  const float* tf_b1   = (const float*)d_in[26];
  const float* tf_w2   = (const float*)d_in[27];
  const float* tf_b2   = (const float*)d_in[28];
  const float* fin_g   = (const float*)d_in[29];
  const float* fin_b   = (const float*)d_in[30];

  float* yout = (float*)d_out;            // 16384 x 512
  float* loss_out = yout + 8388608;       // scalar
  float* idx_out = loss_out + 1;          // 16384 (as float)

  float* ws   = (float*)d_ws;
  float* z    = ws;                   // 8388608
  float* tb   = z + 8388608;          // 8388608
  float* bufA = tb + 8388608;         // 16777216 (patch: so ; tf: qkv/ffn-h)
  float* bufC = bufA + 16777216;      // 8388608  (patch: zh/zl ; tf: projh bf16)
  float* wreg = bufC + 8388608;       // 6291456
  float* treg = wreg + 6291456;       // 4194304  (VQ: ch/cl ; tf: tbh)
  float* cbn  = treg + 4194304;       // 1024
  float* q16  = cbn + 1024;           // 512
  float* w1T  = q16 + 512;            // 2048
  float* w2T  = w1T + 2048;           // 2048
  float* znorm = w2T + 2048;          // 16384
  u64*   packed = (u64*)(znorm + 16384);  // 16384 u64
  float* loss_part = (float*)(packed + 16384); // 4096

  ushort* win_b  = (ushort*)wreg;
  ushort* wout_b = win_b + 3145728;
  ushort* w1t_b  = wout_b + 1048576;
  ushort* w2t_b  = w1t_b + 4194304;
  ushort* tbh    = (ushort*)treg;
  ushort* qkvh   = (ushort*)bufA;
  ushort* abh    = (ushort*)z;
  ushort* zh_b   = (ushort*)bufC;
  ushort* zl_b   = zh_b + 8388608;
  ushort* projh  = (ushort*)bufC;          // bf16 proj outputs (zh/zl dead)
  ushort* ch_b   = (ushort*)treg;          // dead before tbh written
  ushort* cl_b   = ch_b + 524288;

  hipMemsetAsync(packed, 0xFF, 16384 * sizeof(u64), stream);
  cbnorm_kernel<<<1024, 64, 0, stream>>>(cb, cbn, ch_b, cl_b);
  patch_setup_kernel<<<1, 64, 0, stream>>>(pa_lq, pa_win, pa_bin, pa_w1,
                                           pa_w2, q16, w1T, w2T);

  pkA_kernel<<<4096, 256, 0, stream>>>(x, pa_pos, pa_win, pa_bin, q16, bufA);
  pkB_kernel<<<16384, 64, 0, stream>>>(bufA, x, pa_wout, pa_bout, pa_lq,
                                       pa_ln1g, pa_ln1b, w1T, pa_b1,
                                       w2T, pa_b2, pa_ln2g, pa_ln2b, z,
                                       zh_b, zl_b, znorm);

  cvt_flat<<<2048, 256, 0, stream>>>(tf_win, win_b, 3145728);
  cvt_flat<<<1024, 256, 0, stream>>>(tf_wout, wout_b, 1048576);
  cvt_tr<<<dim3(64, 16, 4), 256, 0, stream>>>(tf_w1, w1t_b, 512, 2048);
  cvt_tr<<<dim3(16, 64, 4), 256, 0, stream>>>(tf_w2, w2t_b, 2048, 512);

  gemm_vq_b3<<<dim3(1024), 256, 0, stream>>>(zh_b, zl_b, ch_b, cl_b,
                                             znorm, cbn, packed);
  vq_slim_kernel<<<4096, 256, 0, stream>>>(packed, cb, z, tf_pos, tb, tbh,
                                           idx_out, loss_part);
  loss_reduce_kernel<<<1, 256, 0, stream>>>(loss_part, loss_out);

  for (int l = 0; l < 4; l++) {
    gemm_bf16_kernel<2><<<dim3(128 * 12), 256, 0, stream>>>(
        tbh, win_b + (size_t)l * 1536 * 512, tf_bin + l * 1536, qkvh,
        16384, 1536, 512);
    attn_mfma_kernel<<<dim3(2048), 64, 0, stream>>>(qkvh, abh);
    gemm_bf16_kernel<2><<<dim3(128 * 4), 256, 0, stream>>>(
        abh, wout_b + (size_t)l * 512 * 512, tf_bout + l * 512, projh,
        16384, 512, 512);
    ln_kernel<<<dim3(4096), 256, 0, stream>>>(tb, projh, tf_ln1g + l * 512,
                                              tf_ln1b + l * 512, tb, tbh);
    gemm_bf16_kernel<1><<<dim3(128 * 16), 256, 0, stream>>>(
        tbh, w1t_b + (size_t)l * 1048576, tf_b1 + l * 2048, qkvh,
        16384, 2048, 512);
    gemm_bf16_kernel<2><<<dim3(128 * 4), 256, 0, stream>>>(
        qkvh, w2t_b + (size_t)l * 1048576, tf_b2 + l * 512, projh,
        16384, 512, 2048);
    ln_kernel<<<dim3(4096), 256, 0, stream>>>(tb, projh, tf_ln2g + l * 512,
                                              tf_ln2b + l * 512, tb, tbh);
  }
  ln_kernel<<<dim3(4096), 256, 0, stream>>>(tb, nullptr, fin_g, fin_b, yout,
                                            nullptr);

  (void)in_sizes; (void)n_in; (void)out_size; (void)ws_size;
}

// Round 15
// 1303.201 us; speedup vs baseline: 1.1513x; 1.0508x over previous
//
#include <hip/hip_runtime.h>

// PatchVQVAETransformer forward, round 15:
//  - gemm_bf16: BK 32->64 via dual sub-tile LDS [2][128][32] (same layout per
//    half, same ascending-k MFMA order -> outputs bit-identical) -> halves
//    barrier/vmcnt drains. LDS 32KB, 5 blocks/CU.
//  - attn: next-tile K/V register prefetch issued under compute + setprio(1)
//    around MFMA clusters (load timing only -> bit-identical).
//  - everything else unchanged from r14.

#define SQRT1_2F 0.70710678118654752440f

typedef __attribute__((ext_vector_type(8))) short short8;
typedef __attribute__((ext_vector_type(4))) float f32x4;
typedef __attribute__((ext_vector_type(8))) unsigned short ushort8;
typedef unsigned short ushort;
typedef unsigned long long u64;

__device__ __forceinline__ float gelu_exact(float v) {
  return 0.5f * v * (1.0f + erff(v * SQRT1_2F));
}

__device__ __forceinline__ ushort f2b_rne(float f) {
  unsigned u = __float_as_uint(f);
  unsigned r = (u + 0x7fffu + ((u >> 16) & 1u)) >> 16;
  return (ushort)r;
}

__device__ __forceinline__ float b2f(ushort u) {
  return __uint_as_float(((unsigned)u) << 16);
}

__device__ __forceinline__ void gload16(const void* g, void* l) {
  __builtin_amdgcn_global_load_lds(
      (const __attribute__((address_space(1))) void*)g,
      (__attribute__((address_space(3))) void*)l, 16, 0, 0);
}

// monotone float->u32 (finite inputs): preserves <
__device__ __forceinline__ unsigned fkey(float d) {
  unsigned u = __float_as_uint(d);
  return (u & 0x80000000u) ? ~u : (u | 0x80000000u);
}

// ---------------------------------------------------------------------------
// One-time setup: q16 = lq@wq^T + bq; w1T[u][d]=w1[d][u]; w2T[c][u]=w2[u][c].
// ---------------------------------------------------------------------------
__global__ __launch_bounds__(64) void patch_setup_kernel(
    const float* __restrict__ lq, const float* __restrict__ win,
    const float* __restrict__ bin, const float* __restrict__ w1,
    const float* __restrict__ w2, float* __restrict__ q16,
    float* __restrict__ w1T, float* __restrict__ w2T) {
  const int tid = threadIdx.x;
#pragma unroll
  for (int q = 0; q < 8; q++) {
    int e = tid + (q << 6);
    int i = e >> 5, c = e & 31;
    const float* wr = win + (size_t)c * 32;
    float acc = bin[c];
#pragma unroll
    for (int d = 0; d < 32; d++) acc += lq[(i << 5) + d] * wr[d];
    q16[e] = acc;
  }
#pragma unroll
  for (int q = 0; q < 32; q++) {
    int e = tid + (q << 6);          // e = u*32 + d
    int u = e >> 5, d = e & 31;
    w1T[e] = w1[(size_t)d * 64 + u];
  }
#pragma unroll
  for (int q = 0; q < 32; q++) {
    int e = tid + (q << 6);          // e = c*64 + u
    int c = e >> 6, u = e & 63;
    w2T[e] = w2[(size_t)u * 32 + c];
  }
}

// ---------------------------------------------------------------------------
// LN over 16 rows x 32 cols at row-stride 34 in LDS, in place. 4 lanes/row.
// ---------------------------------------------------------------------------
__device__ __forceinline__ void ln_16xS(float* buf, const float* g,
                                        const float* bb, int tid) {
  int row = tid >> 2, sub = tid & 3;
  int c0 = sub << 3;
  float* r = buf + row * 34 + c0;
  float v[8];
  float s = 0.f, s2 = 0.f;
#pragma unroll
  for (int n = 0; n < 8; n++) {
    float t = r[n];
    v[n] = t; s += t; s2 += t * t;
  }
  s += __shfl_xor(s, 1);  s += __shfl_xor(s, 2);
  s2 += __shfl_xor(s2, 1); s2 += __shfl_xor(s2, 2);
  float m = s * (1.0f / 32.0f);
  float var = s2 * (1.0f / 32.0f) - m * m;
  float inv = 1.0f / sqrtf(var + 1e-5f);
#pragma unroll
  for (int n = 0; n < 8; n++)
    r[n] = (v[n] - m) * inv * g[c0 + n] + bb[c0 + n];
}

// ---------------------------------------------------------------------------
// pkA v2 (unchanged from r12-r14).
// ---------------------------------------------------------------------------
__global__ __launch_bounds__(256) void pkA_kernel(
    const float* __restrict__ x, const float* __restrict__ pos,
    const float* __restrict__ win, const float* __restrict__ bin,
    const float* __restrict__ q16, float* __restrict__ so) {
  __shared__ float sxp[2048];
  __shared__ float skv[4096];
  __shared__ float sq16[16 * 33];
  const int blk = blockIdx.x, t = threadIdx.x;
  const int p0 = blk << 2;
  const int cfix = t & 31;

#pragma unroll
  for (int q = 0; q < 8; q++) {
    int e = t + (q << 8);
    int pl = e >> 9, r = e & 511;
    sxp[e] = x[(size_t)(p0 + pl) * 512 + r] + pos[r];
  }
  if (t < 128) {
#pragma unroll
    for (int q = 0; q < 4; q++) {
      int e = t + (q << 7);
      sq16[(e >> 5) * 33 + (e & 31)] = q16[e];
    }
  }

  float wr0[32], wr1[32];
#pragma unroll
  for (int d4 = 0; d4 < 8; d4++) {
    *(float4*)(wr0 + 4 * d4) =
        *(const float4*)(win + (size_t)(32 + cfix) * 32 + 4 * d4);
    *(float4*)(wr1 + 4 * d4) =
        *(const float4*)(win + (size_t)(64 + cfix) * 32 + 4 * d4);
  }
  const float bk = bin[32 + cfix];
  const float bv = bin[64 + cfix];
  __syncthreads();

#pragma unroll
  for (int q = 0; q < 16; q++) {
    int e = t + (q << 8);
    int pl = e >> 10, rr = e & 1023;
    int w = rr >> 9, rj = rr & 511, j = rj >> 5;
    const float* sx = sxp + (pl << 9) + (j << 5);
    const float* wreg = w ? wr1 : wr0;
    float acc = w ? bv : bk;
#pragma unroll
    for (int d = 0; d < 32; d++) acc += sx[d] * wreg[d];
    skv[e] = acc;
  }
  __syncthreads();

  const int pl = t >> 6, hh = (t >> 4) & 3, i = t & 15;
  const int p = p0 + pl;
  const float* kp = skv + (pl << 10);
  const int hd = hh << 3;

  float sc[16];
#pragma unroll
  for (int j = 0; j < 16; j++) {
    float acc = 0.f;
#pragma unroll
    for (int d = 0; d < 8; d++)
      acc += sq16[i * 33 + hd + d] * kp[(j << 5) + hd + d];
    sc[j] = acc * 0.35355339059327373f;
  }
  {
    float mx = sc[0];
#pragma unroll
    for (int j = 1; j < 16; j++) mx = fmaxf(mx, sc[j]);
    float sm = 0.f;
    float ev[16];
#pragma unroll
    for (int j = 0; j < 16; j++) { ev[j] = expf(sc[j] - mx); sm += ev[j]; }
    float inv = 1.0f / sm;
#pragma unroll
    for (int j = 0; j < 16; j++) sc[j] = ev[j] * inv;
  }
  float* orow = so + (size_t)p * 512 + (i << 5) + hd;
#pragma unroll
  for (int c8 = 0; c8 < 8; c8++) {
    const int c = hd + c8;
    float acc = 0.f;
#pragma unroll
    for (int j = 0; j < 16; j++) acc += sc[j] * kp[512 + (j << 5) + c];
    orow[c8] = acc;
  }
}

// ---------------------------------------------------------------------------
// pkB v3 (r12/r14 64-thread version): weight columns register-resident.
// z bit-identical.
// ---------------------------------------------------------------------------
__global__ __launch_bounds__(64) void pkB_kernel(
    const float* __restrict__ so_g, const float* __restrict__ x,
    const float* __restrict__ wout, const float* __restrict__ bout,
    const float* __restrict__ lq,
    const float* __restrict__ ln1g, const float* __restrict__ ln1b,
    const float* __restrict__ w1T, const float* __restrict__ b1,
    const float* __restrict__ w2T, const float* __restrict__ b2,
    const float* __restrict__ ln2g, const float* __restrict__ ln2b,
    float* __restrict__ z, ushort* __restrict__ zh,
    ushort* __restrict__ zl, float* __restrict__ znorm) {
  __shared__ float sso[544], sst[544], ssh[1056];
  const int p = blockIdx.x, t = threadIdx.x;
  const int cfix = t & 31;

#pragma unroll
  for (int q = 0; q < 8; q++) {
    int e = t + (q << 6);
    sso[(e >> 5) * 34 + (e & 31)] = so_g[(size_t)p * 512 + e];
  }

  float wo[32];
#pragma unroll
  for (int d4 = 0; d4 < 8; d4++)
    *(float4*)(wo + 4 * d4) = *(const float4*)(wout + (size_t)cfix * 32 + 4 * d4);
  __syncthreads();

#pragma unroll
  for (int q = 0; q < 8; q++) {
    int e = t + (q << 6);
    int i = e >> 5;
    float acc = bout[cfix];
#pragma unroll
    for (int d = 0; d < 32; d++) acc += sso[i * 34 + d] * wo[d];
    sst[i * 34 + cfix] = acc + lq[(i << 5) + cfix];
  }
  __syncthreads();
  ln_16xS(sst, ln1g, ln1b, t);

  float w1r[32];
#pragma unroll
  for (int d4 = 0; d4 < 8; d4++)
    *(float4*)(w1r + 4 * d4) = *(const float4*)(w1T + (size_t)t * 32 + 4 * d4);
  __syncthreads();

#pragma unroll
  for (int q = 0; q < 16; q++) {
    int i = q;
    float acc = b1[t];
#pragma unroll
    for (int d = 0; d < 32; d++) acc += sst[i * 34 + d] * w1r[d];
    ssh[i * 66 + t] = gelu_exact(acc);
  }

  float w2r[64];
#pragma unroll
  for (int u4 = 0; u4 < 16; u4++)
    *(float4*)(w2r + 4 * u4) = *(const float4*)(w2T + (size_t)cfix * 64 + 4 * u4);
  __syncthreads();

#pragma unroll
  for (int q = 0; q < 8; q++) {
    int e = t + (q << 6);
    int i = e >> 5;
    float acc = b2[cfix];
#pragma unroll
    for (int u = 0; u < 64; u++) acc += ssh[i * 66 + u] * w2r[u];
    sso[i * 34 + cfix] = acc + sst[i * 34 + cfix];
  }
  __syncthreads();
  ln_16xS(sso, ln2g, ln2b, t);
  __syncthreads();

  const float* xp = x + (size_t)p * 512;
  const int row = t >> 2, c0v = (t & 3) << 3;
  float zv[8];
#pragma unroll
  for (int n = 0; n < 8; n++)
    zv[n] = xp[(t << 3) + n] + sso[row * 34 + c0v + n];
  float* zo = z + (size_t)p * 512 + (t << 3);
  *(float4*)(zo)     = *(float4*)(zv);
  *(float4*)(zo + 4) = *(float4*)(zv + 4);
  ushort8 hv, lv;
  float s2 = 0.f;
#pragma unroll
  for (int n = 0; n < 8; n++) {
    s2 += zv[n] * zv[n];
    ushort h = f2b_rne(zv[n]);
    hv[n] = h;
    lv[n] = f2b_rne(zv[n] - b2f(h));
  }
  *(ushort8*)(zh + (size_t)p * 512 + (t << 3)) = hv;
  *(ushort8*)(zl + (size_t)p * 512 + (t << 3)) = lv;
#pragma unroll
  for (int off = 1; off < 64; off <<= 1) s2 += __shfl_xor(s2, off);
  if (t == 0) znorm[p] = s2;
}

// ---------------------------------------------------------------------------
// cbnorm + bf16 split of the codebook (ch/cl).
// ---------------------------------------------------------------------------
__global__ __launch_bounds__(64) void cbnorm_kernel(
    const float* __restrict__ cb, float* __restrict__ cbn,
    ushort* __restrict__ ch, ushort* __restrict__ cl) {
  int c = blockIdx.x, lane = threadIdx.x;
  const float* r = cb + (size_t)c * 512 + lane * 8;
  float v[8];
  *(float4*)(v)     = *(const float4*)(r);
  *(float4*)(v + 4) = *(const float4*)(r + 4);
  float s = 0.f;
  ushort8 hv, lv;
#pragma unroll
  for (int n = 0; n < 8; n++) {
    s += v[n] * v[n];
    ushort h = f2b_rne(v[n]);
    hv[n] = h;
    lv[n] = f2b_rne(v[n] - b2f(h));
  }
  *(ushort8*)(ch + (size_t)c * 512 + lane * 8) = hv;
  *(ushort8*)(cl + (size_t)c * 512 + lane * 8) = lv;
#pragma unroll
  for (int off = 1; off < 64; off <<= 1) s += __shfl_xor(s, off);
  if (lane == 0) cbn[c] = s;
}

// ---------------------------------------------------------------------------
// VQ scores via bf16x3 MFMA with fused argmin epilogue + XCD swizzle.
// (unchanged from r9-r14)
// ---------------------------------------------------------------------------
__global__ __launch_bounds__(256) void gemm_vq_b3(
    const ushort* __restrict__ Ah, const ushort* __restrict__ Al,
    const ushort* __restrict__ Bh, const ushort* __restrict__ Bl,
    const float* __restrict__ znorm, const float* __restrict__ cbn,
    u64* __restrict__ packed) {
  __shared__ ushort sAh[4096], sAl[4096], sBh[4096], sBl[4096];
  const int cpx = gridDim.x >> 3;
  const int bid = (blockIdx.x & 7) * cpx + (blockIdx.x >> 3);
  const int bx = bid & 7, by = bid >> 3;
  const int m0 = by << 7, n0 = bx << 7;
  const int tid = threadIdx.x;
  const int wid = tid >> 6, lane = tid & 63;
  const int wr = wid >> 1, wc = wid & 1;
  const int l15 = lane & 15, lk = lane >> 4;

  const f32x4 fzero = {0.f, 0.f, 0.f, 0.f};
  f32x4 acc[4][4];
#pragma unroll
  for (int i = 0; i < 4; i++)
#pragma unroll
    for (int j = 0; j < 4; j++) acc[i][j] = fzero;

  for (int k0 = 0; k0 < 512; k0 += 32) {
#pragma unroll
    for (int c = 0; c < 2; c++) {
      const int I = tid + (c << 8);
      const int r = I >> 2, kk = (I & 3) << 3;
      const size_t ga = (size_t)(m0 + r) * 512 + k0 + kk;
      const size_t gb = (size_t)(n0 + r) * 512 + k0 + kk;
      const size_t lo = (size_t)((wid << 6) + (c << 8)) * 8;
      gload16(Ah + ga, sAh + lo);
      gload16(Al + ga, sAl + lo);
      gload16(Bh + gb, sBh + lo);
      gload16(Bl + gb, sBl + lo);
    }
    __syncthreads();

    short8 ah[4], al[4], bh[4], bl[4];
#pragma unroll
    for (int m = 0; m < 4; m++) {
      const int ar = ((wr << 6) + (m << 4) + l15) * 32 + lk * 8;
      ah[m] = *(const short8*)(sAh + ar);
      al[m] = *(const short8*)(sAl + ar);
      const int br = ((wc << 6) + (m << 4) + l15) * 32 + lk * 8;
      bh[m] = *(const short8*)(sBh + br);
      bl[m] = *(const short8*)(sBl + br);
    }
#pragma unroll
    for (int m = 0; m < 4; m++)
#pragma unroll
      for (int n = 0; n < 4; n++) {
        acc[m][n] = __builtin_amdgcn_mfma_f32_16x16x32_bf16(ah[m], bh[n],
                                                            acc[m][n], 0, 0, 0);
        acc[m][n] = __builtin_amdgcn_mfma_f32_16x16x32_bf16(ah[m], bl[n],
                                                            acc[m][n], 0, 0, 0);
        acc[m][n] = __builtin_amdgcn_mfma_f32_16x16x32_bf16(al[m], bh[n],
                                                            acc[m][n], 0, 0, 0);
      }
    __syncthreads();
  }

  float zn[4][4];
#pragma unroll
  for (int m = 0; m < 4; m++)
#pragma unroll
    for (int r = 0; r < 4; r++)
      zn[m][r] = znorm[m0 + (wr << 6) + (m << 4) + (lk << 2) + r];
  float cbnv[4];
#pragma unroll
  for (int n = 0; n < 4; n++)
    cbnv[n] = cbn[n0 + (wc << 6) + (n << 4) + l15];

#pragma unroll
  for (int m = 0; m < 4; m++) {
#pragma unroll
    for (int r = 0; r < 4; r++) {
      u64 best = ~0ull;
#pragma unroll
      for (int n = 0; n < 4; n++) {
        const int gcol = n0 + (wc << 6) + (n << 4) + l15;
        float d = (zn[m][r] + cbnv[n]) - 2.0f * acc[m][n][r];
        u64 key = ((u64)fkey(d) << 32) | (unsigned)gcol;
        best = best < key ? best : key;
      }
#pragma unroll
      for (int off = 1; off < 16; off <<= 1) {
        u64 o = __shfl_xor(best, off);
        best = best < o ? best : o;
      }
      if (l15 == 0) {
        const int grow = m0 + (wr << 6) + (m << 4) + (lk << 2) + r;
        atomicMin(&packed[grow], best);
      }
    }
  }
}

// ---------------------------------------------------------------------------
// slim VQ finish (per-block loss partial, no same-address atomics).
// ---------------------------------------------------------------------------
__global__ __launch_bounds__(256) void vq_slim_kernel(
    const u64* __restrict__ packed, const float* __restrict__ cb,
    const float* __restrict__ z, const float* __restrict__ tf_pos,
    float* __restrict__ t, ushort* __restrict__ th,
    float* __restrict__ idx_out, float* __restrict__ loss_part) {
  __shared__ float spart[4];
  const int wv = threadIdx.x >> 6;
  const int r = (blockIdx.x << 2) + wv;
  const int lane = threadIdx.x & 63;
  const int bi = (int)(unsigned)(packed[r] & 0xFFFFFFFFull);
  const float* zr = z + (size_t)r * 512 + (lane << 3);
  const float* q = cb + (size_t)bi * 512 + (lane << 3);
  const float* pr = tf_pos + (size_t)(r & 255) * 512 + (lane << 3);
  float zv[8], qv[8], pv[8];
  *(float4*)(zv)     = *(const float4*)(zr);
  *(float4*)(zv + 4) = *(const float4*)(zr + 4);
  *(float4*)(qv)     = *(const float4*)(q);
  *(float4*)(qv + 4) = *(const float4*)(q + 4);
  *(float4*)(pv)     = *(const float4*)(pr);
  *(float4*)(pv + 4) = *(const float4*)(pr + 4);
  float lsum = 0.f;
  float tv[8];
  ushort8 w;
#pragma unroll
  for (int n = 0; n < 8; n++) {
    float diff = qv[n] - zv[n];
    lsum += diff * diff;
    tv[n] = qv[n] + pv[n];
    w[n] = f2b_rne(tv[n]);
  }
  float* to = t + (size_t)r * 512 + (lane << 3);
  *(float4*)(to)     = *(float4*)(tv);
  *(float4*)(to + 4) = *(float4*)(tv + 4);
  *(ushort8*)(th + (size_t)r * 512 + (lane << 3)) = w;
#pragma unroll
  for (int off = 1; off < 64; off <<= 1) lsum += __shfl_xor(lsum, off);
  if (lane == 0) {
    idx_out[r] = (float)bi;
    spart[wv] = lsum;
  }
  __syncthreads();
  if (threadIdx.x == 0)
    loss_part[blockIdx.x] = (spart[0] + spart[1]) + (spart[2] + spart[3]);
}

// ---------------------------------------------------------------------------
__global__ __launch_bounds__(256) void loss_reduce_kernel(
    const float* __restrict__ loss_part, float* __restrict__ loss_out) {
  __shared__ float sw[4];
  float s = 0.f;
  for (int i = threadIdx.x; i < 4096; i += 256) s += loss_part[i];
#pragma unroll
  for (int off = 1; off < 64; off <<= 1) s += __shfl_xor(s, off);
  const int wv = threadIdx.x >> 6;
  if ((threadIdx.x & 63) == 0) sw[wv] = s;
  __syncthreads();
  if (threadIdx.x == 0)
    loss_out[0] = ((sw[0] + sw[1]) + (sw[2] + sw[3])) * (1.25f / 8388608.0f);
}

// ---------------------------------------------------------------------------
// bf16 MFMA GEMM, BK=64 dual sub-tile LDS [2][128][32], XCD swizzle.
// MFMA order per acc: kc=0 (k..k+31) then kc=1 -> identical to two BK=32
// iterations -> outputs bit-identical to r14. K must be multiple of 64.
// ---------------------------------------------------------------------------
template <int OUTMODE>
__global__ __launch_bounds__(256) void gemm_bf16_kernel(
    const ushort* __restrict__ A, const ushort* __restrict__ B,
    const float* __restrict__ bias, void* __restrict__ Cout,
    int M, int N, int K) {
  __shared__ ushort As[8192];  // [2][128][32]
  __shared__ ushort Bs[8192];
  const int nbx = N >> 7;
  const int cpx = gridDim.x >> 3;
  const int bid = (blockIdx.x & 7) * cpx + (blockIdx.x >> 3);
  const int bx = bid % nbx, by = bid / nbx;
  const int m0 = by << 7, n0 = bx << 7;
  const int tid = threadIdx.x;
  const int wid = tid >> 6, lane = tid & 63;
  const int wr = wid >> 1, wc = wid & 1;
  const int l15 = lane & 15, lk = lane >> 4;

  const f32x4 fzero = {0.f, 0.f, 0.f, 0.f};
  f32x4 acc[4][4];
#pragma unroll
  for (int i = 0; i < 4; i++)
#pragma unroll
    for (int j = 0; j < 4; j++) acc[i][j] = fzero;

  for (int k0 = 0; k0 < K; k0 += 64) {
#pragma unroll
    for (int c = 0; c < 4; c++) {
      const int base = (c << 8) + (wid << 6);   // 0..1023, 64-aligned
      const int half = base >> 9;               // k sub-tile
      const int Jb = base & 511;                // slot base within half
      const int J = Jb + lane;
      const int r = J >> 2, kk = (J & 3) << 3;
      gload16(A + (size_t)(m0 + r) * K + k0 + (half << 5) + kk,
              As + (size_t)((half << 12) + Jb * 8));
      gload16(B + (size_t)(n0 + r) * K + k0 + (half << 5) + kk,
              Bs + (size_t)((half << 12) + Jb * 8));
    }
    __syncthreads();

#pragma unroll
    for (int kc = 0; kc < 2; kc++) {
      short8 a[4], b[4];
#pragma unroll
      for (int m = 0; m < 4; m++) {
        const int ar = (kc << 12) + ((wr << 6) + (m << 4) + l15) * 32 + lk * 8;
        a[m] = *(const short8*)(As + ar);
        const int br = (kc << 12) + ((wc << 6) + (m << 4) + l15) * 32 + lk * 8;
        b[m] = *(const short8*)(Bs + br);
      }
#pragma unroll
      for (int m = 0; m < 4; m++)
#pragma unroll
        for (int n = 0; n < 4; n++)
          acc[m][n] = __builtin_amdgcn_mfma_f32_16x16x32_bf16(a[m], b[n],
                                                              acc[m][n], 0, 0, 0);
    }
    __syncthreads();
  }

  float bv[4];
#pragma unroll
  for (int n = 0; n < 4; n++)
    bv[n] = bias[n0 + (wc << 6) + (n << 4) + l15];

#pragma unroll
  for (int m = 0; m < 4; m++) {
#pragma unroll
    for (int n = 0; n < 4; n++) {
      const int gcol = n0 + (wc << 6) + (n << 4) + l15;
#pragma unroll
      for (int r = 0; r < 4; r++) {
        const int grow = m0 + (wr << 6) + (m << 4) + (lk << 2) + r;
        float v = acc[m][n][r] + bv[n];
        if (OUTMODE == 0) {
          ((float*)Cout)[(size_t)grow * N + gcol] = v;
        } else if (OUTMODE == 1) {
          ((ushort*)Cout)[(size_t)grow * N + gcol] = f2b_rne(gelu_exact(v));
        } else {
          ((ushort*)Cout)[(size_t)grow * N + gcol] = f2b_rne(v);
        }
      }
    }
  }
}

// ---------------------------------------------------------------------------
// Weight conversions.
// ---------------------------------------------------------------------------
__global__ void cvt_flat(const float* __restrict__ in, ushort* __restrict__ out,
                         int n) {
  int i = blockIdx.x * blockDim.x + threadIdx.x;
  const int stride = gridDim.x * blockDim.x;
  for (; i < n; i += stride) out[i] = f2b_rne(in[i]);
}

__global__ __launch_bounds__(256) void cvt_tr(const float* __restrict__ in,
                                              ushort* __restrict__ out,
                                              int R, int C) {
  __shared__ float tile[32][33];
  const int bc = blockIdx.x, br = blockIdx.y, lay = blockIdx.z;
  const float* src = in + (size_t)lay * R * C;
  ushort* dst = out + (size_t)lay * R * C;
  const int tid = threadIdx.x;
#pragma unroll
  for (int q = 0; q < 4; q++) {
    int idx = tid + (q << 8);
    int rr = idx >> 5, cc = idx & 31;
    tile[rr][cc] = src[(size_t)(br * 32 + rr) * C + bc * 32 + cc];
  }
  __syncthreads();
#pragma unroll
  for (int q = 0; q < 4; q++) {
    int idx = tid + (q << 8);
    int co = idx >> 5, ro = idx & 31;
    dst[(size_t)(bc * 32 + co) * R + br * 32 + ro] = f2b_rne(tile[ro][co]);
  }
}

// ---------------------------------------------------------------------------
// MFMA flash attention with next-tile K/V register prefetch + setprio.
// Load timing changed only -> output bit-identical to r14.
// ---------------------------------------------------------------------------
__global__ __launch_bounds__(64) void attn_mfma_kernel(
    const ushort* __restrict__ qkv, ushort* __restrict__ o) {
  __shared__ ushort lds[8192];
  char* KsB = (char*)lds;
  char* VtB = (char*)(lds + 4096);
  const int bid = blockIdx.x;
  const int xcd = bid & 7, slot = bid >> 3;
  const int b = (xcd << 3) | (slot >> 5);
  const int h = (slot >> 2) & 7;
  const int qb = slot & 3;
  const int lane = threadIdx.x;
  const int l15 = lane & 15, lk4 = lane >> 4;

  short8 qf[4][2];
#pragma unroll
  for (int m = 0; m < 4; m++)
#pragma unroll
    for (int kc = 0; kc < 2; kc++)
      qf[m][kc] = *(const short8*)(qkv +
          (size_t)(b * 256 + qb * 64 + m * 16 + l15) * 1536 +
          h * 64 + kc * 32 + lk4 * 8);

  const f32x4 fz = {0.f, 0.f, 0.f, 0.f};
  f32x4 O[4][4];
#pragma unroll
  for (int m = 0; m < 4; m++)
#pragma unroll
    for (int n = 0; n < 4; n++) O[m][n] = fz;
  float lsum[4][4];
#pragma unroll
  for (int m = 0; m < 4; m++)
#pragma unroll
    for (int r = 0; r < 4; r++) lsum[m][r] = 0.f;

  // preload tile 0
  ushort8 kv[8], vv[8];
  {
    const ushort* krow = qkv + (size_t)(b * 256 + lane) * 1536 + 512 + h * 64;
#pragma unroll
    for (int u = 0; u < 8; u++) kv[u] = ((const ushort8*)krow)[u];
#pragma unroll
    for (int u = 0; u < 8; u++) vv[u] = ((const ushort8*)(krow + 512))[u];
  }

  for (int jt = 0; jt <= qb; jt++) {
    __syncthreads();  // prior tile's LDS reads drained
    {
      const int rx = (lane & 7) << 4;
#pragma unroll
      for (int u = 0; u < 8; u++)
        *(ushort8*)(KsB + lane * 128 + ((u << 4) ^ rx)) = kv[u];
#pragma unroll
      for (int u = 0; u < 8; u++)
#pragma unroll
        for (int i = 0; i < 8; i++) {
          const int d = u * 8 + i;
          *(ushort*)(VtB + ((d * 128 + lane * 2) ^ ((d & 7) << 4))) =
              (ushort)vv[u][i];
        }
    }
    __syncthreads();

    // prefetch next tile's K/V into the freed registers (hides HBM latency
    // under the S/P/PV compute below)
    if (jt < qb) {
      const ushort* krow = qkv +
          (size_t)(b * 256 + (jt + 1) * 64 + lane) * 1536 + 512 + h * 64;
#pragma unroll
      for (int u = 0; u < 8; u++) kv[u] = ((const ushort8*)krow)[u];
#pragma unroll
      for (int u = 0; u < 8; u++) vv[u] = ((const ushort8*)(krow + 512))[u];
    }

    f32x4 sacc[4][4];
#pragma unroll
    for (int m = 0; m < 4; m++)
#pragma unroll
      for (int n = 0; n < 4; n++) sacc[m][n] = fz;
    __builtin_amdgcn_s_setprio(1);
#pragma unroll
    for (int kc = 0; kc < 2; kc++) {
      short8 bf[4];
#pragma unroll
      for (int n = 0; n < 4; n++) {
        const int row = n * 16 + l15;
        bf[n] = *(const short8*)(KsB + row * 128 +
                                 ((kc * 64 + lk4 * 16) ^ ((row & 7) << 4)));
      }
#pragma unroll
      for (int m = 0; m < 4; m++)
#pragma unroll
        for (int n = 0; n < 4; n++)
          sacc[m][n] = __builtin_amdgcn_mfma_f32_16x16x32_bf16(
              qf[m][kc], bf[n], sacc[m][n], 0, 0, 0);
    }
    __builtin_amdgcn_s_setprio(0);
    __syncthreads();

    const bool diag = (jt == qb);
#pragma unroll
    for (int m = 0; m < 4; m++)
#pragma unroll
      for (int n = 0; n < 4; n++)
#pragma unroll
        for (int r = 0; r < 4; r++) {
          const int ql = m * 16 + lk4 * 4 + r;
          const int jl = n * 16 + l15;
          float e = __expf(sacc[m][n][r] * 0.125f);
          if (diag && jl > ql) e = 0.f;
          const ushort pu = f2b_rne(e);
          lsum[m][r] += b2f(pu);
          *(ushort*)(KsB + ql * 128 + ((jl * 2) ^ ((ql & 7) << 4))) = pu;
        }
    __syncthreads();

    __builtin_amdgcn_s_setprio(1);
#pragma unroll
    for (int kc = 0; kc < 2; kc++) {
      short8 pf[4], vf[4];
#pragma unroll
      for (int m = 0; m < 4; m++) {
        const int row = m * 16 + l15;
        pf[m] = *(const short8*)(KsB + row * 128 +
                                 ((kc * 64 + lk4 * 16) ^ ((row & 7) << 4)));
      }
#pragma unroll
      for (int n = 0; n < 4; n++) {
        const int row = n * 16 + l15;
        vf[n] = *(const short8*)(VtB + row * 128 +
                                 ((kc * 64 + lk4 * 16) ^ ((row & 7) << 4)));
      }
#pragma unroll
      for (int m = 0; m < 4; m++)
#pragma unroll
        for (int n = 0; n < 4; n++)
          O[m][n] = __builtin_amdgcn_mfma_f32_16x16x32_bf16(
              pf[m], vf[n], O[m][n], 0, 0, 0);
    }
    __builtin_amdgcn_s_setprio(0);
  }

  float inv[4][4];
#pragma unroll
  for (int m = 0; m < 4; m++)
#pragma unroll
    for (int r = 0; r < 4; r++) {
      float v = lsum[m][r];
      v += __shfl_xor(v, 1); v += __shfl_xor(v, 2);
      v += __shfl_xor(v, 4); v += __shfl_xor(v, 8);
      inv[m][r] = 1.0f / v;
    }
#pragma unroll
  for (int m = 0; m < 4; m++)
#pragma unroll
    for (int n = 0; n < 4; n++)
#pragma unroll
      for (int r = 0; r < 4; r++) {
        const int row = b * 256 + qb * 64 + m * 16 + lk4 * 4 + r;
        const int col = h * 64 + n * 16 + l15;
        o[(size_t)row * 512 + col] = f2b_rne(O[m][n][r] * inv[m][r]);
      }
}

// ---------------------------------------------------------------------------
// LayerNorm over 512 with optional bf16 residual add.
// ---------------------------------------------------------------------------
__global__ __launch_bounds__(256) void ln_kernel(
    const float* __restrict__ xin, const ushort* __restrict__ addin_b,
    const float* __restrict__ g, const float* __restrict__ bb,
    float* __restrict__ outp, ushort* __restrict__ outb) {
  const int r = blockIdx.x * 4 + (threadIdx.x >> 6);
  const int lane = threadIdx.x & 63;
  const float* xr = xin + (size_t)r * 512 + lane * 8;
  float v[8];
  *(float4*)(v)     = *(const float4*)(xr);
  *(float4*)(v + 4) = *(const float4*)(xr + 4);
  if (addin_b) {
    ushort8 a = *(const ushort8*)(addin_b + (size_t)r * 512 + lane * 8);
#pragma unroll
    for (int n = 0; n < 8; n++) v[n] += b2f(a[n]);
  }
  float s = 0.f, s2 = 0.f;
#pragma unroll
  for (int n = 0; n < 8; n++) { s += v[n]; s2 += v[n] * v[n]; }
#pragma unroll
  for (int off = 1; off < 64; off <<= 1) {
    s += __shfl_xor(s, off);
    s2 += __shfl_xor(s2, off);
  }
  float m = s * (1.0f / 512.0f);
  float var = s2 * (1.0f / 512.0f) - m * m;
  float inv = 1.0f / sqrtf(var + 1e-5f);
  const int c0 = lane * 8;
  float outv[8];
#pragma unroll
  for (int n = 0; n < 8; n++) outv[n] = (v[n] - m) * inv * g[c0 + n] + bb[c0 + n];
  float* orow = outp + (size_t)r * 512 + c0;
  *(float4*)(orow)     = *(float4*)(outv);
  *(float4*)(orow + 4) = *(float4*)(outv + 4);
  if (outb) {
    ushort8 w;
#pragma unroll
    for (int n = 0; n < 8; n++) w[n] = f2b_rne(outv[n]);
    *(ushort8*)(outb + (size_t)r * 512 + c0) = w;
  }
}

// ---------------------------------------------------------------------------
extern "C" void kernel_launch(void* const* d_in, const int* in_sizes, int n_in,
                              void* d_out, int out_size, void* d_ws, size_t ws_size,
                              hipStream_t stream) {
  const float* x       = (const float*)d_in[0];
  const float* pa_lq   = (const float*)d_in[1];
  const float* pa_pos  = (const float*)d_in[2];
  const float* pa_win  = (const float*)d_in[3];
  const float* pa_bin  = (const float*)d_in[4];
  const float* pa_wout = (const float*)d_in[5];
  const float* pa_bout = (const float*)d_in[6];
  const float* pa_ln1g = (const float*)d_in[7];
  const float* pa_ln1b = (const float*)d_in[8];
  const float* pa_ln2g = (const float*)d_in[9];
  const float* pa_ln2b = (const float*)d_in[10];
  const float* pa_w1   = (const float*)d_in[11];
  const float* pa_b1   = (const float*)d_in[12];
  const float* pa_w2   = (const float*)d_in[13];
  const float* pa_b2   = (const float*)d_in[14];
  const float* cb      = (const float*)d_in[15];
  const float* tf_pos  = (const float*)d_in[16];
  const float* tf_win  = (const float*)d_in[17];
  const float* tf_bin  = (const float*)d_in[18];
  const float* tf_wout = (const float*)d_in[19];
  const float* tf_bout = (const float*)d_in[20];
  const float* tf_ln1g = (const float*)d_in[21];
  const float* tf_ln1b = (const float*)d_in[22];
  const float* tf_ln2g = (const float*)d_in[23];
  const float* tf_ln2b = (const float*)d_in[24];
  const float* tf_w1   = (const float*)d_in[25];
  const float* tf_b1   = (const float*)d_in[26];
  const float* tf_w2   = (const float*)d_in[27];
  const float* tf_b2   = (const float*)d_in[28];
  const float* fin_g   = (const float*)d_in[29];
  const float* fin_b   = (const float*)d_in[30];

  float* yout = (float*)d_out;            // 16384 x 512
  float* loss_out = yout + 8388608;       // scalar
  float* idx_out = loss_out + 1;          // 16384 (as float)

  float* ws   = (float*)d_ws;
  float* z    = ws;                   // 8388608
  float* tb   = z + 8388608;          // 8388608
  float* bufA = tb + 8388608;         // 16777216 (patch: so ; tf: qkv/ffn-h)
  float* bufC = bufA + 16777216;      // 8388608  (patch: zh/zl ; tf: projh bf16)
  float* wreg = bufC + 8388608;       // 6291456
  float* treg = wreg + 6291456;       // 4194304  (VQ: ch/cl ; tf: tbh)
  float* cbn  = treg + 4194304;       // 1024
  float* q16  = cbn + 1024;           // 512
  float* w1T  = q16 + 512;            // 2048
  float* w2T  = w1T + 2048;           // 2048
  float* znorm = w2T + 2048;          // 16384
  u64*   packed = (u64*)(znorm + 16384);  // 16384 u64
  float* loss_part = (float*)(packed + 16384); // 4096

  ushort* win_b  = (ushort*)wreg;
  ushort* wout_b = win_b + 3145728;
  ushort* w1t_b  = wout_b + 1048576;
  ushort* w2t_b  = w1t_b + 4194304;
  ushort* tbh    = (ushort*)treg;
  ushort* qkvh   = (ushort*)bufA;
  ushort* abh    = (ushort*)z;
  ushort* zh_b   = (ushort*)bufC;
  ushort* zl_b   = zh_b + 8388608;
  ushort* projh  = (ushort*)bufC;          // bf16 proj outputs (zh/zl dead)
  ushort* ch_b   = (ushort*)treg;          // dead before tbh written
  ushort* cl_b   = ch_b + 524288;

  hipMemsetAsync(packed, 0xFF, 16384 * sizeof(u64), stream);
  cbnorm_kernel<<<1024, 64, 0, stream>>>(cb, cbn, ch_b, cl_b);
  patch_setup_kernel<<<1, 64, 0, stream>>>(pa_lq, pa_win, pa_bin, pa_w1,
                                           pa_w2, q16, w1T, w2T);

  pkA_kernel<<<4096, 256, 0, stream>>>(x, pa_pos, pa_win, pa_bin, q16, bufA);
  pkB_kernel<<<16384, 64, 0, stream>>>(bufA, x, pa_wout, pa_bout, pa_lq,
                                       pa_ln1g, pa_ln1b, w1T, pa_b1,
                                       w2T, pa_b2, pa_ln2g, pa_ln2b, z,
                                       zh_b, zl_b, znorm);

  cvt_flat<<<2048, 256, 0, stream>>>(tf_win, win_b, 3145728);
  cvt_flat<<<1024, 256, 0, stream>>>(tf_wout, wout_b, 1048576);
  cvt_tr<<<dim3(64, 16, 4), 256, 0, stream>>>(tf_w1, w1t_b, 512, 2048);
  cvt_tr<<<dim3(16, 64, 4), 256, 0, stream>>>(tf_w2, w2t_b, 2048, 512);

  gemm_vq_b3<<<dim3(1024), 256, 0, stream>>>(zh_b, zl_b, ch_b, cl_b,
                                             znorm, cbn, packed);
  vq_slim_kernel<<<4096, 256, 0, stream>>>(packed, cb, z, tf_pos, tb, tbh,
                                           idx_out, loss_part);
  loss_reduce_kernel<<<1, 256, 0, stream>>>(loss_part, loss_out);

  for (int l = 0; l < 4; l++) {
    gemm_bf16_kernel<2><<<dim3(128 * 12), 256, 0, stream>>>(
        tbh, win_b + (size_t)l * 1536 * 512, tf_bin + l * 1536, qkvh,
        16384, 1536, 512);
    attn_mfma_kernel<<<dim3(2048), 64, 0, stream>>>(qkvh, abh);
    gemm_bf16_kernel<2><<<dim3(128 * 4), 256, 0, stream>>>(
        abh, wout_b + (size_t)l * 512 * 512, tf_bout + l * 512, projh,
        16384, 512, 512);
    ln_kernel<<<dim3(4096), 256, 0, stream>>>(tb, projh, tf_ln1g + l * 512,
                                              tf_ln1b + l * 512, tb, tbh);
    gemm_bf16_kernel<1><<<dim3(128 * 16), 256, 0, stream>>>(
        tbh, w1t_b + (size_t)l * 1048576, tf_b1 + l * 2048, qkvh,
        16384, 2048, 512);
    gemm_bf16_kernel<2><<<dim3(128 * 4), 256, 0, stream>>>(
        qkvh, w2t_b + (size_t)l * 1048576, tf_b2 + l * 512, projh,
        16384, 512, 2048);
    ln_kernel<<<dim3(4096), 256, 0, stream>>>(tb, projh, tf_ln2g + l * 512,
                                              tf_ln2b + l * 512, tb, tbh);
  }
  ln_kernel<<<dim3(4096), 256, 0, stream>>>(tb, nullptr, fin_g, fin_b, yout,
                                            nullptr);

  (void)in_sizes; (void)n_in; (void)out_size; (void)ws_size;
}

// Round 16
// 1301.966 us; speedup vs baseline: 1.1524x; 1.0009x over previous
//
#include <hip/hip_runtime.h>

// PatchVQVAETransformer forward, round 16:
//  - pkA+pkB fused into pkF (256 thr = 4 patches): attention output kept in
//    LDS (no 64MB so round-trip); phase B = pkB verbatim per wave ->
//    z bit-identical -> idx/loss exact. LDS 35.4KB -> 4 blocks/CU.
//  - everything else unchanged from r15.

#define SQRT1_2F 0.70710678118654752440f

typedef __attribute__((ext_vector_type(8))) short short8;
typedef __attribute__((ext_vector_type(4))) float f32x4;
typedef __attribute__((ext_vector_type(8))) unsigned short ushort8;
typedef unsigned short ushort;
typedef unsigned long long u64;

__device__ __forceinline__ float gelu_exact(float v) {
  return 0.5f * v * (1.0f + erff(v * SQRT1_2F));
}

__device__ __forceinline__ ushort f2b_rne(float f) {
  unsigned u = __float_as_uint(f);
  unsigned r = (u + 0x7fffu + ((u >> 16) & 1u)) >> 16;
  return (ushort)r;
}

__device__ __forceinline__ float b2f(ushort u) {
  return __uint_as_float(((unsigned)u) << 16);
}

__device__ __forceinline__ void gload16(const void* g, void* l) {
  __builtin_amdgcn_global_load_lds(
      (const __attribute__((address_space(1))) void*)g,
      (__attribute__((address_space(3))) void*)l, 16, 0, 0);
}

// monotone float->u32 (finite inputs): preserves <
__device__ __forceinline__ unsigned fkey(float d) {
  unsigned u = __float_as_uint(d);
  return (u & 0x80000000u) ? ~u : (u | 0x80000000u);
}

// ---------------------------------------------------------------------------
// One-time setup: q16 = lq@wq^T + bq; w1T[u][d]=w1[d][u]; w2T[c][u]=w2[u][c].
// ---------------------------------------------------------------------------
__global__ __launch_bounds__(64) void patch_setup_kernel(
    const float* __restrict__ lq, const float* __restrict__ win,
    const float* __restrict__ bin, const float* __restrict__ w1,
    const float* __restrict__ w2, float* __restrict__ q16,
    float* __restrict__ w1T, float* __restrict__ w2T) {
  const int tid = threadIdx.x;
#pragma unroll
  for (int q = 0; q < 8; q++) {
    int e = tid + (q << 6);
    int i = e >> 5, c = e & 31;
    const float* wr = win + (size_t)c * 32;
    float acc = bin[c];
#pragma unroll
    for (int d = 0; d < 32; d++) acc += lq[(i << 5) + d] * wr[d];
    q16[e] = acc;
  }
#pragma unroll
  for (int q = 0; q < 32; q++) {
    int e = tid + (q << 6);          // e = u*32 + d
    int u = e >> 5, d = e & 31;
    w1T[e] = w1[(size_t)d * 64 + u];
  }
#pragma unroll
  for (int q = 0; q < 32; q++) {
    int e = tid + (q << 6);          // e = c*64 + u
    int c = e >> 6, u = e & 63;
    w2T[e] = w2[(size_t)u * 32 + c];
  }
}

// ---------------------------------------------------------------------------
// LN over 16 rows x 32 cols at row-stride 34 in LDS, in place. 4 lanes/row.
// (lane-indexed; wave-local shfl)
// ---------------------------------------------------------------------------
__device__ __forceinline__ void ln_16xS(float* buf, const float* g,
                                        const float* bb, int tid) {
  int row = tid >> 2, sub = tid & 3;
  int c0 = sub << 3;
  float* r = buf + row * 34 + c0;
  float v[8];
  float s = 0.f, s2 = 0.f;
#pragma unroll
  for (int n = 0; n < 8; n++) {
    float t = r[n];
    v[n] = t; s += t; s2 += t * t;
  }
  s += __shfl_xor(s, 1);  s += __shfl_xor(s, 2);
  s2 += __shfl_xor(s2, 1); s2 += __shfl_xor(s2, 2);
  float m = s * (1.0f / 32.0f);
  float var = s2 * (1.0f / 32.0f) - m * m;
  float inv = 1.0f / sqrtf(var + 1e-5f);
#pragma unroll
  for (int n = 0; n < 8; n++)
    r[n] = (v[n] - m) * inv * g[c0 + n] + bb[c0 + n];
}

// ---------------------------------------------------------------------------
// pkF: fused patch encoder. 256 thr = 4 patches.
// Phase A (pkA verbatim): in-proj + scores/softmax/AV -> sso in LDS.
// Phase B (pkB verbatim, wave w = patch p0+w, lane = pkB's t):
// out-proj+LN1+FFN1+FFN2+LN2+z+bf16split+znorm. z bit-identical.
// ---------------------------------------------------------------------------
__global__ __launch_bounds__(256) void pkF_kernel(
    const float* __restrict__ x, const float* __restrict__ pos,
    const float* __restrict__ win, const float* __restrict__ bin,
    const float* __restrict__ q16,
    const float* __restrict__ wout, const float* __restrict__ bout,
    const float* __restrict__ lq,
    const float* __restrict__ ln1g, const float* __restrict__ ln1b,
    const float* __restrict__ w1T, const float* __restrict__ b1,
    const float* __restrict__ w2T, const float* __restrict__ b2,
    const float* __restrict__ ln2g, const float* __restrict__ ln2b,
    float* __restrict__ z, ushort* __restrict__ zh,
    ushort* __restrict__ zl, float* __restrict__ znorm) {
  __shared__ float sso[2176];       // 4 x 544, persists A->B
  __shared__ float ubuf[6672];      // A: sxp[2048] skv[4096] sq16[528]
                                    // B: sst[2176] ssh[4224]
  float* sxp  = ubuf;
  float* skv  = ubuf + 2048;
  float* sq16 = ubuf + 6144;
  float* sstA = ubuf;               // phase-B alias
  float* sshA = ubuf + 2176;

  const int blk = blockIdx.x, t = threadIdx.x;
  const int p0 = blk << 2;
  const int cfix = t & 31;
  const int wv = t >> 6, lane = t & 63;

  // ---- phase A: stage x+pos and q16 ----
#pragma unroll
  for (int q = 0; q < 8; q++) {
    int e = t + (q << 8);
    int pl = e >> 9, r = e & 511;
    sxp[e] = x[(size_t)(p0 + pl) * 512 + r] + pos[r];
  }
  if (t < 128) {
#pragma unroll
    for (int q = 0; q < 4; q++) {
      int e = t + (q << 7);
      sq16[(e >> 5) * 33 + (e & 31)] = q16[e];
    }
  }

  float wr0[32], wr1[32];
#pragma unroll
  for (int d4 = 0; d4 < 8; d4++) {
    *(float4*)(wr0 + 4 * d4) =
        *(const float4*)(win + (size_t)(32 + cfix) * 32 + 4 * d4);
    *(float4*)(wr1 + 4 * d4) =
        *(const float4*)(win + (size_t)(64 + cfix) * 32 + 4 * d4);
  }
  const float bk = bin[32 + cfix];
  const float bvv = bin[64 + cfix];
  __syncthreads();

  // in-proj -> skv (bit-exact pkA)
#pragma unroll
  for (int q = 0; q < 16; q++) {
    int e = t + (q << 8);
    int pl = e >> 10, rr = e & 1023;
    int w = rr >> 9, rj = rr & 511, j = rj >> 5;
    const float* sx = sxp + (pl << 9) + (j << 5);
    const float* wreg = w ? wr1 : wr0;
    float acc = w ? bvv : bk;
#pragma unroll
    for (int d = 0; d < 32; d++) acc += sx[d] * wreg[d];
    skv[e] = acc;
  }
  __syncthreads();

  // attention per (pl, hh, i) -> sso (bit-exact pkA values)
  {
    const int pl = t >> 6, hh = (t >> 4) & 3, i = t & 15;
    const float* kp = skv + (pl << 10);
    const int hd = hh << 3;

    float sc[16];
#pragma unroll
    for (int j = 0; j < 16; j++) {
      float acc = 0.f;
#pragma unroll
      for (int d = 0; d < 8; d++)
        acc += sq16[i * 33 + hd + d] * kp[(j << 5) + hd + d];
      sc[j] = acc * 0.35355339059327373f;
    }
    {
      float mx = sc[0];
#pragma unroll
      for (int j = 1; j < 16; j++) mx = fmaxf(mx, sc[j]);
      float sm = 0.f;
      float ev[16];
#pragma unroll
      for (int j = 0; j < 16; j++) { ev[j] = expf(sc[j] - mx); sm += ev[j]; }
      float inv = 1.0f / sm;
#pragma unroll
      for (int j = 0; j < 16; j++) sc[j] = ev[j] * inv;
    }
    float* orow = sso + pl * 544 + i * 34 + hd;
#pragma unroll
    for (int c8 = 0; c8 < 8; c8++) {
      const int c = hd + c8;
      float acc = 0.f;
#pragma unroll
      for (int j = 0; j < 16; j++) acc += sc[j] * kp[512 + (j << 5) + c];
      orow[c8] = acc;
    }
  }
  __syncthreads();   // all waves done reading skv before sst/ssh alias it

  // ---- phase B: wave wv = patch p0+wv, lane = pkB's t (bit-exact pkB) ----
  const int p = p0 + wv;
  float* psso = sso + wv * 544;
  float* psst = sstA + wv * 544;
  float* pssh = sshA + wv * 1056;

  float wo[32];
#pragma unroll
  for (int d4 = 0; d4 < 8; d4++)
    *(float4*)(wo + 4 * d4) = *(const float4*)(wout + (size_t)cfix * 32 + 4 * d4);

#pragma unroll
  for (int q = 0; q < 8; q++) {
    int e = lane + (q << 6);
    int i = e >> 5;
    float acc = bout[cfix];
#pragma unroll
    for (int d = 0; d < 32; d++) acc += psso[i * 34 + d] * wo[d];
    psst[i * 34 + cfix] = acc + lq[(i << 5) + cfix];
  }
  __syncthreads();
  ln_16xS(psst, ln1g, ln1b, lane);

  float w1r[32];
#pragma unroll
  for (int d4 = 0; d4 < 8; d4++)
    *(float4*)(w1r + 4 * d4) = *(const float4*)(w1T + (size_t)lane * 32 + 4 * d4);
  __syncthreads();

#pragma unroll
  for (int q = 0; q < 16; q++) {
    int i = q;
    float acc = b1[lane];
#pragma unroll
    for (int d = 0; d < 32; d++) acc += psst[i * 34 + d] * w1r[d];
    pssh[i * 66 + lane] = gelu_exact(acc);
  }

  float w2r[64];
#pragma unroll
  for (int u4 = 0; u4 < 16; u4++)
    *(float4*)(w2r + 4 * u4) = *(const float4*)(w2T + (size_t)cfix * 64 + 4 * u4);
  __syncthreads();

#pragma unroll
  for (int q = 0; q < 8; q++) {
    int e = lane + (q << 6);
    int i = e >> 5;
    float acc = b2[cfix];
#pragma unroll
    for (int u = 0; u < 64; u++) acc += pssh[i * 66 + u] * w2r[u];
    psso[i * 34 + cfix] = acc + psst[i * 34 + cfix];
  }
  __syncthreads();
  ln_16xS(psso, ln2g, ln2b, lane);
  __syncthreads();

  const float* xp = x + (size_t)p * 512;
  const int row = lane >> 2, c0v = (lane & 3) << 3;
  float zv[8];
#pragma unroll
  for (int n = 0; n < 8; n++)
    zv[n] = xp[(lane << 3) + n] + psso[row * 34 + c0v + n];
  float* zo = z + (size_t)p * 512 + (lane << 3);
  *(float4*)(zo)     = *(float4*)(zv);
  *(float4*)(zo + 4) = *(float4*)(zv + 4);
  ushort8 hv, lv;
  float s2 = 0.f;
#pragma unroll
  for (int n = 0; n < 8; n++) {
    s2 += zv[n] * zv[n];
    ushort h = f2b_rne(zv[n]);
    hv[n] = h;
    lv[n] = f2b_rne(zv[n] - b2f(h));
  }
  *(ushort8*)(zh + (size_t)p * 512 + (lane << 3)) = hv;
  *(ushort8*)(zl + (size_t)p * 512 + (lane << 3)) = lv;
#pragma unroll
  for (int off = 1; off < 64; off <<= 1) s2 += __shfl_xor(s2, off);
  if (lane == 0) znorm[p] = s2;
}

// ---------------------------------------------------------------------------
// cbnorm + bf16 split of the codebook (ch/cl).
// ---------------------------------------------------------------------------
__global__ __launch_bounds__(64) void cbnorm_kernel(
    const float* __restrict__ cb, float* __restrict__ cbn,
    ushort* __restrict__ ch, ushort* __restrict__ cl) {
  int c = blockIdx.x, lane = threadIdx.x;
  const float* r = cb + (size_t)c * 512 + lane * 8;
  float v[8];
  *(float4*)(v)     = *(const float4*)(r);
  *(float4*)(v + 4) = *(const float4*)(r + 4);
  float s = 0.f;
  ushort8 hv, lv;
#pragma unroll
  for (int n = 0; n < 8; n++) {
    s += v[n] * v[n];
    ushort h = f2b_rne(v[n]);
    hv[n] = h;
    lv[n] = f2b_rne(v[n] - b2f(h));
  }
  *(ushort8*)(ch + (size_t)c * 512 + lane * 8) = hv;
  *(ushort8*)(cl + (size_t)c * 512 + lane * 8) = lv;
#pragma unroll
  for (int off = 1; off < 64; off <<= 1) s += __shfl_xor(s, off);
  if (lane == 0) cbn[c] = s;
}

// ---------------------------------------------------------------------------
// VQ scores via bf16x3 MFMA with fused argmin epilogue + XCD swizzle.
// ---------------------------------------------------------------------------
__global__ __launch_bounds__(256) void gemm_vq_b3(
    const ushort* __restrict__ Ah, const ushort* __restrict__ Al,
    const ushort* __restrict__ Bh, const ushort* __restrict__ Bl,
    const float* __restrict__ znorm, const float* __restrict__ cbn,
    u64* __restrict__ packed) {
  __shared__ ushort sAh[4096], sAl[4096], sBh[4096], sBl[4096];
  const int cpx = gridDim.x >> 3;
  const int bid = (blockIdx.x & 7) * cpx + (blockIdx.x >> 3);
  const int bx = bid & 7, by = bid >> 3;
  const int m0 = by << 7, n0 = bx << 7;
  const int tid = threadIdx.x;
  const int wid = tid >> 6, lane = tid & 63;
  const int wr = wid >> 1, wc = wid & 1;
  const int l15 = lane & 15, lk = lane >> 4;

  const f32x4 fzero = {0.f, 0.f, 0.f, 0.f};
  f32x4 acc[4][4];
#pragma unroll
  for (int i = 0; i < 4; i++)
#pragma unroll
    for (int j = 0; j < 4; j++) acc[i][j] = fzero;

  for (int k0 = 0; k0 < 512; k0 += 32) {
#pragma unroll
    for (int c = 0; c < 2; c++) {
      const int I = tid + (c << 8);
      const int r = I >> 2, kk = (I & 3) << 3;
      const size_t ga = (size_t)(m0 + r) * 512 + k0 + kk;
      const size_t gb = (size_t)(n0 + r) * 512 + k0 + kk;
      const size_t lo = (size_t)((wid << 6) + (c << 8)) * 8;
      gload16(Ah + ga, sAh + lo);
      gload16(Al + ga, sAl + lo);
      gload16(Bh + gb, sBh + lo);
      gload16(Bl + gb, sBl + lo);
    }
    __syncthreads();

    short8 ah[4], al[4], bh[4], bl[4];
#pragma unroll
    for (int m = 0; m < 4; m++) {
      const int ar = ((wr << 6) + (m << 4) + l15) * 32 + lk * 8;
      ah[m] = *(const short8*)(sAh + ar);
      al[m] = *(const short8*)(sAl + ar);
      const int br = ((wc << 6) + (m << 4) + l15) * 32 + lk * 8;
      bh[m] = *(const short8*)(sBh + br);
      bl[m] = *(const short8*)(sBl + br);
    }
#pragma unroll
    for (int m = 0; m < 4; m++)
#pragma unroll
      for (int n = 0; n < 4; n++) {
        acc[m][n] = __builtin_amdgcn_mfma_f32_16x16x32_bf16(ah[m], bh[n],
                                                            acc[m][n], 0, 0, 0);
        acc[m][n] = __builtin_amdgcn_mfma_f32_16x16x32_bf16(ah[m], bl[n],
                                                            acc[m][n], 0, 0, 0);
        acc[m][n] = __builtin_amdgcn_mfma_f32_16x16x32_bf16(al[m], bh[n],
                                                            acc[m][n], 0, 0, 0);
      }
    __syncthreads();
  }

  float zn[4][4];
#pragma unroll
  for (int m = 0; m < 4; m++)
#pragma unroll
    for (int r = 0; r < 4; r++)
      zn[m][r] = znorm[m0 + (wr << 6) + (m << 4) + (lk << 2) + r];
  float cbnv[4];
#pragma unroll
  for (int n = 0; n < 4; n++)
    cbnv[n] = cbn[n0 + (wc << 6) + (n << 4) + l15];

#pragma unroll
  for (int m = 0; m < 4; m++) {
#pragma unroll
    for (int r = 0; r < 4; r++) {
      u64 best = ~0ull;
#pragma unroll
      for (int n = 0; n < 4; n++) {
        const int gcol = n0 + (wc << 6) + (n << 4) + l15;
        float d = (zn[m][r] + cbnv[n]) - 2.0f * acc[m][n][r];
        u64 key = ((u64)fkey(d) << 32) | (unsigned)gcol;
        best = best < key ? best : key;
      }
#pragma unroll
      for (int off = 1; off < 16; off <<= 1) {
        u64 o = __shfl_xor(best, off);
        best = best < o ? best : o;
      }
      if (l15 == 0) {
        const int grow = m0 + (wr << 6) + (m << 4) + (lk << 2) + r;
        atomicMin(&packed[grow], best);
      }
    }
  }
}

// ---------------------------------------------------------------------------
// slim VQ finish (per-block loss partial, no same-address atomics).
// ---------------------------------------------------------------------------
__global__ __launch_bounds__(256) void vq_slim_kernel(
    const u64* __restrict__ packed, const float* __restrict__ cb,
    const float* __restrict__ z, const float* __restrict__ tf_pos,
    float* __restrict__ t, ushort* __restrict__ th,
    float* __restrict__ idx_out, float* __restrict__ loss_part) {
  __shared__ float spart[4];
  const int wv = threadIdx.x >> 6;
  const int r = (blockIdx.x << 2) + wv;
  const int lane = threadIdx.x & 63;
  const int bi = (int)(unsigned)(packed[r] & 0xFFFFFFFFull);
  const float* zr = z + (size_t)r * 512 + (lane << 3);
  const float* q = cb + (size_t)bi * 512 + (lane << 3);
  const float* pr = tf_pos + (size_t)(r & 255) * 512 + (lane << 3);
  float zv[8], qv[8], pv[8];
  *(float4*)(zv)     = *(const float4*)(zr);
  *(float4*)(zv + 4) = *(const float4*)(zr + 4);
  *(float4*)(qv)     = *(const float4*)(q);
  *(float4*)(qv + 4) = *(const float4*)(q + 4);
  *(float4*)(pv)     = *(const float4*)(pr);
  *(float4*)(pv + 4) = *(const float4*)(pr + 4);
  float lsum = 0.f;
  float tv[8];
  ushort8 w;
#pragma unroll
  for (int n = 0; n < 8; n++) {
    float diff = qv[n] - zv[n];
    lsum += diff * diff;
    tv[n] = qv[n] + pv[n];
    w[n] = f2b_rne(tv[n]);
  }
  float* to = t + (size_t)r * 512 + (lane << 3);
  *(float4*)(to)     = *(float4*)(tv);
  *(float4*)(to + 4) = *(float4*)(tv + 4);
  *(ushort8*)(th + (size_t)r * 512 + (lane << 3)) = w;
#pragma unroll
  for (int off = 1; off < 64; off <<= 1) lsum += __shfl_xor(lsum, off);
  if (lane == 0) {
    idx_out[r] = (float)bi;
    spart[wv] = lsum;
  }
  __syncthreads();
  if (threadIdx.x == 0)
    loss_part[blockIdx.x] = (spart[0] + spart[1]) + (spart[2] + spart[3]);
}

// ---------------------------------------------------------------------------
__global__ __launch_bounds__(256) void loss_reduce_kernel(
    const float* __restrict__ loss_part, float* __restrict__ loss_out) {
  __shared__ float sw[4];
  float s = 0.f;
  for (int i = threadIdx.x; i < 4096; i += 256) s += loss_part[i];
#pragma unroll
  for (int off = 1; off < 64; off <<= 1) s += __shfl_xor(s, off);
  const int wv = threadIdx.x >> 6;
  if ((threadIdx.x & 63) == 0) sw[wv] = s;
  __syncthreads();
  if (threadIdx.x == 0)
    loss_out[0] = ((sw[0] + sw[1]) + (sw[2] + sw[3])) * (1.25f / 8388608.0f);
}

// ---------------------------------------------------------------------------
// bf16 MFMA GEMM, BK=64 dual sub-tile LDS [2][128][32], XCD swizzle.
// (unchanged from r15; outputs bit-identical to r14)
// ---------------------------------------------------------------------------
template <int OUTMODE>
__global__ __launch_bounds__(256) void gemm_bf16_kernel(
    const ushort* __restrict__ A, const ushort* __restrict__ B,
    const float* __restrict__ bias, void* __restrict__ Cout,
    int M, int N, int K) {
  __shared__ ushort As[8192];  // [2][128][32]
  __shared__ ushort Bs[8192];
  const int nbx = N >> 7;
  const int cpx = gridDim.x >> 3;
  const int bid = (blockIdx.x & 7) * cpx + (blockIdx.x >> 3);
  const int bx = bid % nbx, by = bid / nbx;
  const int m0 = by << 7, n0 = bx << 7;
  const int tid = threadIdx.x;
  const int wid = tid >> 6, lane = tid & 63;
  const int wr = wid >> 1, wc = wid & 1;
  const int l15 = lane & 15, lk = lane >> 4;

  const f32x4 fzero = {0.f, 0.f, 0.f, 0.f};
  f32x4 acc[4][4];
#pragma unroll
  for (int i = 0; i < 4; i++)
#pragma unroll
    for (int j = 0; j < 4; j++) acc[i][j] = fzero;

  for (int k0 = 0; k0 < K; k0 += 64) {
#pragma unroll
    for (int c = 0; c < 4; c++) {
      const int base = (c << 8) + (wid << 6);
      const int half = base >> 9;
      const int Jb = base & 511;
      const int J = Jb + lane;
      const int r = J >> 2, kk = (J & 3) << 3;
      gload16(A + (size_t)(m0 + r) * K + k0 + (half << 5) + kk,
              As + (size_t)((half << 12) + Jb * 8));
      gload16(B + (size_t)(n0 + r) * K + k0 + (half << 5) + kk,
              Bs + (size_t)((half << 12) + Jb * 8));
    }
    __syncthreads();

#pragma unroll
    for (int kc = 0; kc < 2; kc++) {
      short8 a[4], b[4];
#pragma unroll
      for (int m = 0; m < 4; m++) {
        const int ar = (kc << 12) + ((wr << 6) + (m << 4) + l15) * 32 + lk * 8;
        a[m] = *(const short8*)(As + ar);
        const int br = (kc << 12) + ((wc << 6) + (m << 4) + l15) * 32 + lk * 8;
        b[m] = *(const short8*)(Bs + br);
      }
#pragma unroll
      for (int m = 0; m < 4; m++)
#pragma unroll
        for (int n = 0; n < 4; n++)
          acc[m][n] = __builtin_amdgcn_mfma_f32_16x16x32_bf16(a[m], b[n],
                                                              acc[m][n], 0, 0, 0);
    }
    __syncthreads();
  }

  float bv[4];
#pragma unroll
  for (int n = 0; n < 4; n++)
    bv[n] = bias[n0 + (wc << 6) + (n << 4) + l15];

#pragma unroll
  for (int m = 0; m < 4; m++) {
#pragma unroll
    for (int n = 0; n < 4; n++) {
      const int gcol = n0 + (wc << 6) + (n << 4) + l15;
#pragma unroll
      for (int r = 0; r < 4; r++) {
        const int grow = m0 + (wr << 6) + (m << 4) + (lk << 2) + r;
        float v = acc[m][n][r] + bv[n];
        if (OUTMODE == 0) {
          ((float*)Cout)[(size_t)grow * N + gcol] = v;
        } else if (OUTMODE == 1) {
          ((ushort*)Cout)[(size_t)grow * N + gcol] = f2b_rne(gelu_exact(v));
        } else {
          ((ushort*)Cout)[(size_t)grow * N + gcol] = f2b_rne(v);
        }
      }
    }
  }
}

// ---------------------------------------------------------------------------
// Weight conversions.
// ---------------------------------------------------------------------------
__global__ void cvt_flat(const float* __restrict__ in, ushort* __restrict__ out,
                         int n) {
  int i = blockIdx.x * blockDim.x + threadIdx.x;
  const int stride = gridDim.x * blockDim.x;
  for (; i < n; i += stride) out[i] = f2b_rne(in[i]);
}

__global__ __launch_bounds__(256) void cvt_tr(const float* __restrict__ in,
                                              ushort* __restrict__ out,
                                              int R, int C) {
  __shared__ float tile[32][33];
  const int bc = blockIdx.x, br = blockIdx.y, lay = blockIdx.z;
  const float* src = in + (size_t)lay * R * C;
  ushort* dst = out + (size_t)lay * R * C;
  const int tid = threadIdx.x;
#pragma unroll
  for (int q = 0; q < 4; q++) {
    int idx = tid + (q << 8);
    int rr = idx >> 5, cc = idx & 31;
    tile[rr][cc] = src[(size_t)(br * 32 + rr) * C + bc * 32 + cc];
  }
  __syncthreads();
#pragma unroll
  for (int q = 0; q < 4; q++) {
    int idx = tid + (q << 8);
    int co = idx >> 5, ro = idx & 31;
    dst[(size_t)(bc * 32 + co) * R + br * 32 + ro] = f2b_rne(tile[ro][co]);
  }
}

// ---------------------------------------------------------------------------
// MFMA flash attention with next-tile K/V register prefetch + setprio.
// (unchanged from r15)
// ---------------------------------------------------------------------------
__global__ __launch_bounds__(64) void attn_mfma_kernel(
    const ushort* __restrict__ qkv, ushort* __restrict__ o) {
  __shared__ ushort lds[8192];
  char* KsB = (char*)lds;
  char* VtB = (char*)(lds + 4096);
  const int bid = blockIdx.x;
  const int xcd = bid & 7, slot = bid >> 3;
  const int b = (xcd << 3) | (slot >> 5);
  const int h = (slot >> 2) & 7;
  const int qb = slot & 3;
  const int lane = threadIdx.x;
  const int l15 = lane & 15, lk4 = lane >> 4;

  short8 qf[4][2];
#pragma unroll
  for (int m = 0; m < 4; m++)
#pragma unroll
    for (int kc = 0; kc < 2; kc++)
      qf[m][kc] = *(const short8*)(qkv +
          (size_t)(b * 256 + qb * 64 + m * 16 + l15) * 1536 +
          h * 64 + kc * 32 + lk4 * 8);

  const f32x4 fz = {0.f, 0.f, 0.f, 0.f};
  f32x4 O[4][4];
#pragma unroll
  for (int m = 0; m < 4; m++)
#pragma unroll
    for (int n = 0; n < 4; n++) O[m][n] = fz;
  float lsum[4][4];
#pragma unroll
  for (int m = 0; m < 4; m++)
#pragma unroll
    for (int r = 0; r < 4; r++) lsum[m][r] = 0.f;

  ushort8 kv[8], vv[8];
  {
    const ushort* krow = qkv + (size_t)(b * 256 + lane) * 1536 + 512 + h * 64;
#pragma unroll
    for (int u = 0; u < 8; u++) kv[u] = ((const ushort8*)krow)[u];
#pragma unroll
    for (int u = 0; u < 8; u++) vv[u] = ((const ushort8*)(krow + 512))[u];
  }

  for (int jt = 0; jt <= qb; jt++) {
    __syncthreads();
    {
      const int rx = (lane & 7) << 4;
#pragma unroll
      for (int u = 0; u < 8; u++)
        *(ushort8*)(KsB + lane * 128 + ((u << 4) ^ rx)) = kv[u];
#pragma unroll
      for (int u = 0; u < 8; u++)
#pragma unroll
        for (int i = 0; i < 8; i++) {
          const int d = u * 8 + i;
          *(ushort*)(VtB + ((d * 128 + lane * 2) ^ ((d & 7) << 4))) =
              (ushort)vv[u][i];
        }
    }
    __syncthreads();

    if (jt < qb) {
      const ushort* krow = qkv +
          (size_t)(b * 256 + (jt + 1) * 64 + lane) * 1536 + 512 + h * 64;
#pragma unroll
      for (int u = 0; u < 8; u++) kv[u] = ((const ushort8*)krow)[u];
#pragma unroll
      for (int u = 0; u < 8; u++) vv[u] = ((const ushort8*)(krow + 512))[u];
    }

    f32x4 sacc[4][4];
#pragma unroll
    for (int m = 0; m < 4; m++)
#pragma unroll
      for (int n = 0; n < 4; n++) sacc[m][n] = fz;
    __builtin_amdgcn_s_setprio(1);
#pragma unroll
    for (int kc = 0; kc < 2; kc++) {
      short8 bf[4];
#pragma unroll
      for (int n = 0; n < 4; n++) {
        const int row = n * 16 + l15;
        bf[n] = *(const short8*)(KsB + row * 128 +
                                 ((kc * 64 + lk4 * 16) ^ ((row & 7) << 4)));
      }
#pragma unroll
      for (int m = 0; m < 4; m++)
#pragma unroll
        for (int n = 0; n < 4; n++)
          sacc[m][n] = __builtin_amdgcn_mfma_f32_16x16x32_bf16(
              qf[m][kc], bf[n], sacc[m][n], 0, 0, 0);
    }
    __builtin_amdgcn_s_setprio(0);
    __syncthreads();

    const bool diag = (jt == qb);
#pragma unroll
    for (int m = 0; m < 4; m++)
#pragma unroll
      for (int n = 0; n < 4; n++)
#pragma unroll
        for (int r = 0; r < 4; r++) {
          const int ql = m * 16 + lk4 * 4 + r;
          const int jl = n * 16 + l15;
          float e = __expf(sacc[m][n][r] * 0.125f);
          if (diag && jl > ql) e = 0.f;
          const ushort pu = f2b_rne(e);
          lsum[m][r] += b2f(pu);
          *(ushort*)(KsB + ql * 128 + ((jl * 2) ^ ((ql & 7) << 4))) = pu;
        }
    __syncthreads();

    __builtin_amdgcn_s_setprio(1);
#pragma unroll
    for (int kc = 0; kc < 2; kc++) {
      short8 pf[4], vf[4];
#pragma unroll
      for (int m = 0; m < 4; m++) {
        const int row = m * 16 + l15;
        pf[m] = *(const short8*)(KsB + row * 128 +
                                 ((kc * 64 + lk4 * 16) ^ ((row & 7) << 4)));
      }
#pragma unroll
      for (int n = 0; n < 4; n++) {
        const int row = n * 16 + l15;
        vf[n] = *(const short8*)(VtB + row * 128 +
                                 ((kc * 64 + lk4 * 16) ^ ((row & 7) << 4)));
      }
#pragma unroll
      for (int m = 0; m < 4; m++)
#pragma unroll
        for (int n = 0; n < 4; n++)
          O[m][n] = __builtin_amdgcn_mfma_f32_16x16x32_bf16(
              pf[m], vf[n], O[m][n], 0, 0, 0);
    }
    __builtin_amdgcn_s_setprio(0);
  }

  float inv[4][4];
#pragma unroll
  for (int m = 0; m < 4; m++)
#pragma unroll
    for (int r = 0; r < 4; r++) {
      float v = lsum[m][r];
      v += __shfl_xor(v, 1); v += __shfl_xor(v, 2);
      v += __shfl_xor(v, 4); v += __shfl_xor(v, 8);
      inv[m][r] = 1.0f / v;
    }
#pragma unroll
  for (int m = 0; m < 4; m++)
#pragma unroll
    for (int n = 0; n < 4; n++)
#pragma unroll
      for (int r = 0; r < 4; r++) {
        const int row = b * 256 + qb * 64 + m * 16 + lk4 * 4 + r;
        const int col = h * 64 + n * 16 + l15;
        o[(size_t)row * 512 + col] = f2b_rne(O[m][n][r] * inv[m][r]);
      }
}

// ---------------------------------------------------------------------------
// LayerNorm over 512 with optional bf16 residual add.
// ---------------------------------------------------------------------------
__global__ __launch_bounds__(256) void ln_kernel(
    const float* __restrict__ xin, const ushort* __restrict__ addin_b,
    const float* __restrict__ g, const float* __restrict__ bb,
    float* __restrict__ outp, ushort* __restrict__ outb) {
  const int r = blockIdx.x * 4 + (threadIdx.x >> 6);
  const int lane = threadIdx.x & 63;
  const float* xr = xin + (size_t)r * 512 + lane * 8;
  float v[8];
  *(float4*)(v)     = *(const float4*)(xr);
  *(float4*)(v + 4) = *(const float4*)(xr + 4);
  if (addin_b) {
    ushort8 a = *(const ushort8*)(addin_b + (size_t)r * 512 + lane * 8);
#pragma unroll
    for (int n = 0; n < 8; n++) v[n] += b2f(a[n]);
  }
  float s = 0.f, s2 = 0.f;
#pragma unroll
  for (int n = 0; n < 8; n++) { s += v[n]; s2 += v[n] * v[n]; }
#pragma unroll
  for (int off = 1; off < 64; off <<= 1) {
    s += __shfl_xor(s, off);
    s2 += __shfl_xor(s2, off);
  }
  float m = s * (1.0f / 512.0f);
  float var = s2 * (1.0f / 512.0f) - m * m;
  float inv = 1.0f / sqrtf(var + 1e-5f);
  const int c0 = lane * 8;
  float outv[8];
#pragma unroll
  for (int n = 0; n < 8; n++) outv[n] = (v[n] - m) * inv * g[c0 + n] + bb[c0 + n];
  float* orow = outp + (size_t)r * 512 + c0;
  *(float4*)(orow)     = *(float4*)(outv);
  *(float4*)(orow + 4) = *(float4*)(outv + 4);
  if (outb) {
    ushort8 w;
#pragma unroll
    for (int n = 0; n < 8; n++) w[n] = f2b_rne(outv[n]);
    *(ushort8*)(outb + (size_t)r * 512 + c0) = w;
  }
}

// ---------------------------------------------------------------------------
extern "C" void kernel_launch(void* const* d_in, const int* in_sizes, int n_in,
                              void* d_out, int out_size, void* d_ws, size_t ws_size,
                              hipStream_t stream) {
  const float* x       = (const float*)d_in[0];
  const float* pa_lq   = (const float*)d_in[1];
  const float* pa_pos  = (const float*)d_in[2];
  const float* pa_win  = (const float*)d_in[3];
  const float* pa_bin  = (const float*)d_in[4];
  const float* pa_wout = (const float*)d_in[5];
  const float* pa_bout = (const float*)d_in[6];
  const float* pa_ln1g = (const float*)d_in[7];
  const float* pa_ln1b = (const float*)d_in[8];
  const float* pa_ln2g = (const float*)d_in[9];
  const float* pa_ln2b = (const float*)d_in[10];
  const float* pa_w1   = (const float*)d_in[11];
  const float* pa_b1   = (const float*)d_in[12];
  const float* pa_w2   = (const float*)d_in[13];
  const float* pa_b2   = (const float*)d_in[14];
  const float* cb      = (const float*)d_in[15];
  const float* tf_pos  = (const float*)d_in[16];
  const float* tf_win  = (const float*)d_in[17];
  const float* tf_bin  = (const float*)d_in[18];
  const float* tf_wout = (const float*)d_in[19];
  const float* tf_bout = (const float*)d_in[20];
  const float* tf_ln1g = (const float*)d_in[21];
  const float* tf_ln1b = (const float*)d_in[22];
  const float* tf_ln2g = (const float*)d_in[23];
  const float* tf_ln2b = (const float*)d_in[24];
  const float* tf_w1   = (const float*)d_in[25];
  const float* tf_b1   = (const float*)d_in[26];
  const float* tf_w2   = (const float*)d_in[27];
  const float* tf_b2   = (const float*)d_in[28];
  const float* fin_g   = (const float*)d_in[29];
  const float* fin_b   = (const float*)d_in[30];

  float* yout = (float*)d_out;            // 16384 x 512
  float* loss_out = yout + 8388608;       // scalar
  float* idx_out = loss_out + 1;          // 16384 (as float)

  float* ws   = (float*)d_ws;
  float* z    = ws;                   // 8388608
  float* tb   = z + 8388608;          // 8388608
  float* bufA = tb + 8388608;         // 16777216 (tf: qkv/ffn-h)
  float* bufC = bufA + 16777216;      // 8388608  (patch: zh/zl ; tf: projh bf16)
  float* wreg = bufC + 8388608;       // 6291456
  float* treg = wreg + 6291456;       // 4194304  (VQ: ch/cl ; tf: tbh)
  float* cbn  = treg + 4194304;       // 1024
  float* q16  = cbn + 1024;           // 512
  float* w1T  = q16 + 512;            // 2048
  float* w2T  = w1T + 2048;           // 2048
  float* znorm = w2T + 2048;          // 16384
  u64*   packed = (u64*)(znorm + 16384);  // 16384 u64
  float* loss_part = (float*)(packed + 16384); // 4096

  ushort* win_b  = (ushort*)wreg;
  ushort* wout_b = win_b + 3145728;
  ushort* w1t_b  = wout_b + 1048576;
  ushort* w2t_b  = w1t_b + 4194304;
  ushort* tbh    = (ushort*)treg;
  ushort* qkvh   = (ushort*)bufA;
  ushort* abh    = (ushort*)z;
  ushort* zh_b   = (ushort*)bufC;
  ushort* zl_b   = zh_b + 8388608;
  ushort* projh  = (ushort*)bufC;          // bf16 proj outputs (zh/zl dead)
  ushort* ch_b   = (ushort*)treg;          // dead before tbh written
  ushort* cl_b   = ch_b + 524288;

  hipMemsetAsync(packed, 0xFF, 16384 * sizeof(u64), stream);
  cbnorm_kernel<<<1024, 64, 0, stream>>>(cb, cbn, ch_b, cl_b);
  patch_setup_kernel<<<1, 64, 0, stream>>>(pa_lq, pa_win, pa_bin, pa_w1,
                                           pa_w2, q16, w1T, w2T);

  // fused patch encoder (z bit-identical)
  pkF_kernel<<<4096, 256, 0, stream>>>(x, pa_pos, pa_win, pa_bin, q16,
                                       pa_wout, pa_bout, pa_lq,
                                       pa_ln1g, pa_ln1b, w1T, pa_b1,
                                       w2T, pa_b2, pa_ln2g, pa_ln2b,
                                       z, zh_b, zl_b, znorm);

  cvt_flat<<<2048, 256, 0, stream>>>(tf_win, win_b, 3145728);
  cvt_flat<<<1024, 256, 0, stream>>>(tf_wout, wout_b, 1048576);
  cvt_tr<<<dim3(64, 16, 4), 256, 0, stream>>>(tf_w1, w1t_b, 512, 2048);
  cvt_tr<<<dim3(16, 64, 4), 256, 0, stream>>>(tf_w2, w2t_b, 2048, 512);

  gemm_vq_b3<<<dim3(1024), 256, 0, stream>>>(zh_b, zl_b, ch_b, cl_b,
                                             znorm, cbn, packed);
  vq_slim_kernel<<<4096, 256, 0, stream>>>(packed, cb, z, tf_pos, tb, tbh,
                                           idx_out, loss_part);
  loss_reduce_kernel<<<1, 256, 0, stream>>>(loss_part, loss_out);

  for (int l = 0; l < 4; l++) {
    gemm_bf16_kernel<2><<<dim3(128 * 12), 256, 0, stream>>>(
        tbh, win_b + (size_t)l * 1536 * 512, tf_bin + l * 1536, qkvh,
        16384, 1536, 512);
    attn_mfma_kernel<<<dim3(2048), 64, 0, stream>>>(qkvh, abh);
    gemm_bf16_kernel<2><<<dim3(128 * 4), 256, 0, stream>>>(
        abh, wout_b + (size_t)l * 512 * 512, tf_bout + l * 512, projh,
        16384, 512, 512);
    ln_kernel<<<dim3(4096), 256, 0, stream>>>(tb, projh, tf_ln1g + l * 512,
                                              tf_ln1b + l * 512, tb, tbh);
    gemm_bf16_kernel<1><<<dim3(128 * 16), 256, 0, stream>>>(
        tbh, w1t_b + (size_t)l * 1048576, tf_b1 + l * 2048, qkvh,
        16384, 2048, 512);
    gemm_bf16_kernel<2><<<dim3(128 * 4), 256, 0, stream>>>(
        qkvh, w2t_b + (size_t)l * 1048576, tf_b2 + l * 512, projh,
        16384, 512, 2048);
    ln_kernel<<<dim3(4096), 256, 0, stream>>>(tb, projh, tf_ln2g + l * 512,
                                              tf_ln2b + l * 512, tb, tbh);
  }
  ln_kernel<<<dim3(4096), 256, 0, stream>>>(tb, nullptr, fin_g, fin_b, yout,
                                            nullptr);

  (void)in_sizes; (void)n_in; (void)out_size; (void)ws_size;
}

// Round 17
// 1227.977 us; speedup vs baseline: 1.2218x; 1.0603x over previous
//
#include <hip/hip_runtime.h>

// PatchVQVAETransformer forward, round 17:
//  - residual stream now bf16-only (tbh); f32 tb eliminated. LN reads bf16
//    x + bf16 proj, writes bf16 (final LN writes f32 yout). vq_slim drops
//    its f32 t write. idx/loss paths untouched (upstream). y drifts ~+0.02.
//  - everything else unchanged from r16 (pkF kept: equal perf, fewer launches).

#define SQRT1_2F 0.70710678118654752440f

typedef __attribute__((ext_vector_type(8))) short short8;
typedef __attribute__((ext_vector_type(4))) float f32x4;
typedef __attribute__((ext_vector_type(8))) unsigned short ushort8;
typedef unsigned short ushort;
typedef unsigned long long u64;

__device__ __forceinline__ float gelu_exact(float v) {
  return 0.5f * v * (1.0f + erff(v * SQRT1_2F));
}

__device__ __forceinline__ ushort f2b_rne(float f) {
  unsigned u = __float_as_uint(f);
  unsigned r = (u + 0x7fffu + ((u >> 16) & 1u)) >> 16;
  return (ushort)r;
}

__device__ __forceinline__ float b2f(ushort u) {
  return __uint_as_float(((unsigned)u) << 16);
}

__device__ __forceinline__ void gload16(const void* g, void* l) {
  __builtin_amdgcn_global_load_lds(
      (const __attribute__((address_space(1))) void*)g,
      (__attribute__((address_space(3))) void*)l, 16, 0, 0);
}

// monotone float->u32 (finite inputs): preserves <
__device__ __forceinline__ unsigned fkey(float d) {
  unsigned u = __float_as_uint(d);
  return (u & 0x80000000u) ? ~u : (u | 0x80000000u);
}

// ---------------------------------------------------------------------------
// One-time setup: q16 = lq@wq^T + bq; w1T[u][d]=w1[d][u]; w2T[c][u]=w2[u][c].
// ---------------------------------------------------------------------------
__global__ __launch_bounds__(64) void patch_setup_kernel(
    const float* __restrict__ lq, const float* __restrict__ win,
    const float* __restrict__ bin, const float* __restrict__ w1,
    const float* __restrict__ w2, float* __restrict__ q16,
    float* __restrict__ w1T, float* __restrict__ w2T) {
  const int tid = threadIdx.x;
#pragma unroll
  for (int q = 0; q < 8; q++) {
    int e = tid + (q << 6);
    int i = e >> 5, c = e & 31;
    const float* wr = win + (size_t)c * 32;
    float acc = bin[c];
#pragma unroll
    for (int d = 0; d < 32; d++) acc += lq[(i << 5) + d] * wr[d];
    q16[e] = acc;
  }
#pragma unroll
  for (int q = 0; q < 32; q++) {
    int e = tid + (q << 6);          // e = u*32 + d
    int u = e >> 5, d = e & 31;
    w1T[e] = w1[(size_t)d * 64 + u];
  }
#pragma unroll
  for (int q = 0; q < 32; q++) {
    int e = tid + (q << 6);          // e = c*64 + u
    int c = e >> 6, u = e & 63;
    w2T[e] = w2[(size_t)u * 32 + c];
  }
}

// ---------------------------------------------------------------------------
// LN over 16 rows x 32 cols at row-stride 34 in LDS, in place. 4 lanes/row.
// ---------------------------------------------------------------------------
__device__ __forceinline__ void ln_16xS(float* buf, const float* g,
                                        const float* bb, int tid) {
  int row = tid >> 2, sub = tid & 3;
  int c0 = sub << 3;
  float* r = buf + row * 34 + c0;
  float v[8];
  float s = 0.f, s2 = 0.f;
#pragma unroll
  for (int n = 0; n < 8; n++) {
    float t = r[n];
    v[n] = t; s += t; s2 += t * t;
  }
  s += __shfl_xor(s, 1);  s += __shfl_xor(s, 2);
  s2 += __shfl_xor(s2, 1); s2 += __shfl_xor(s2, 2);
  float m = s * (1.0f / 32.0f);
  float var = s2 * (1.0f / 32.0f) - m * m;
  float inv = 1.0f / sqrtf(var + 1e-5f);
#pragma unroll
  for (int n = 0; n < 8; n++)
    r[n] = (v[n] - m) * inv * g[c0 + n] + bb[c0 + n];
}

// ---------------------------------------------------------------------------
// pkF: fused patch encoder (unchanged from r16; z bit-identical).
// ---------------------------------------------------------------------------
__global__ __launch_bounds__(256) void pkF_kernel(
    const float* __restrict__ x, const float* __restrict__ pos,
    const float* __restrict__ win, const float* __restrict__ bin,
    const float* __restrict__ q16,
    const float* __restrict__ wout, const float* __restrict__ bout,
    const float* __restrict__ lq,
    const float* __restrict__ ln1g, const float* __restrict__ ln1b,
    const float* __restrict__ w1T, const float* __restrict__ b1,
    const float* __restrict__ w2T, const float* __restrict__ b2,
    const float* __restrict__ ln2g, const float* __restrict__ ln2b,
    float* __restrict__ z, ushort* __restrict__ zh,
    ushort* __restrict__ zl, float* __restrict__ znorm) {
  __shared__ float sso[2176];
  __shared__ float ubuf[6672];
  float* sxp  = ubuf;
  float* skv  = ubuf + 2048;
  float* sq16 = ubuf + 6144;
  float* sstA = ubuf;
  float* sshA = ubuf + 2176;

  const int blk = blockIdx.x, t = threadIdx.x;
  const int p0 = blk << 2;
  const int cfix = t & 31;
  const int wv = t >> 6, lane = t & 63;

#pragma unroll
  for (int q = 0; q < 8; q++) {
    int e = t + (q << 8);
    int pl = e >> 9, r = e & 511;
    sxp[e] = x[(size_t)(p0 + pl) * 512 + r] + pos[r];
  }
  if (t < 128) {
#pragma unroll
    for (int q = 0; q < 4; q++) {
      int e = t + (q << 7);
      sq16[(e >> 5) * 33 + (e & 31)] = q16[e];
    }
  }

  float wr0[32], wr1[32];
#pragma unroll
  for (int d4 = 0; d4 < 8; d4++) {
    *(float4*)(wr0 + 4 * d4) =
        *(const float4*)(win + (size_t)(32 + cfix) * 32 + 4 * d4);
    *(float4*)(wr1 + 4 * d4) =
        *(const float4*)(win + (size_t)(64 + cfix) * 32 + 4 * d4);
  }
  const float bk = bin[32 + cfix];
  const float bvv = bin[64 + cfix];
  __syncthreads();

#pragma unroll
  for (int q = 0; q < 16; q++) {
    int e = t + (q << 8);
    int pl = e >> 10, rr = e & 1023;
    int w = rr >> 9, rj = rr & 511, j = rj >> 5;
    const float* sx = sxp + (pl << 9) + (j << 5);
    const float* wreg = w ? wr1 : wr0;
    float acc = w ? bvv : bk;
#pragma unroll
    for (int d = 0; d < 32; d++) acc += sx[d] * wreg[d];
    skv[e] = acc;
  }
  __syncthreads();

  {
    const int pl = t >> 6, hh = (t >> 4) & 3, i = t & 15;
    const float* kp = skv + (pl << 10);
    const int hd = hh << 3;

    float sc[16];
#pragma unroll
    for (int j = 0; j < 16; j++) {
      float acc = 0.f;
#pragma unroll
      for (int d = 0; d < 8; d++)
        acc += sq16[i * 33 + hd + d] * kp[(j << 5) + hd + d];
      sc[j] = acc * 0.35355339059327373f;
    }
    {
      float mx = sc[0];
#pragma unroll
      for (int j = 1; j < 16; j++) mx = fmaxf(mx, sc[j]);
      float sm = 0.f;
      float ev[16];
#pragma unroll
      for (int j = 0; j < 16; j++) { ev[j] = expf(sc[j] - mx); sm += ev[j]; }
      float inv = 1.0f / sm;
#pragma unroll
      for (int j = 0; j < 16; j++) sc[j] = ev[j] * inv;
    }
    float* orow = sso + pl * 544 + i * 34 + hd;
#pragma unroll
    for (int c8 = 0; c8 < 8; c8++) {
      const int c = hd + c8;
      float acc = 0.f;
#pragma unroll
      for (int j = 0; j < 16; j++) acc += sc[j] * kp[512 + (j << 5) + c];
      orow[c8] = acc;
    }
  }
  __syncthreads();

  const int p = p0 + wv;
  float* psso = sso + wv * 544;
  float* psst = sstA + wv * 544;
  float* pssh = sshA + wv * 1056;

  float wo[32];
#pragma unroll
  for (int d4 = 0; d4 < 8; d4++)
    *(float4*)(wo + 4 * d4) = *(const float4*)(wout + (size_t)cfix * 32 + 4 * d4);

#pragma unroll
  for (int q = 0; q < 8; q++) {
    int e = lane + (q << 6);
    int i = e >> 5;
    float acc = bout[cfix];
#pragma unroll
    for (int d = 0; d < 32; d++) acc += psso[i * 34 + d] * wo[d];
    psst[i * 34 + cfix] = acc + lq[(i << 5) + cfix];
  }
  __syncthreads();
  ln_16xS(psst, ln1g, ln1b, lane);

  float w1r[32];
#pragma unroll
  for (int d4 = 0; d4 < 8; d4++)
    *(float4*)(w1r + 4 * d4) = *(const float4*)(w1T + (size_t)lane * 32 + 4 * d4);
  __syncthreads();

#pragma unroll
  for (int q = 0; q < 16; q++) {
    int i = q;
    float acc = b1[lane];
#pragma unroll
    for (int d = 0; d < 32; d++) acc += psst[i * 34 + d] * w1r[d];
    pssh[i * 66 + lane] = gelu_exact(acc);
  }

  float w2r[64];
#pragma unroll
  for (int u4 = 0; u4 < 16; u4++)
    *(float4*)(w2r + 4 * u4) = *(const float4*)(w2T + (size_t)cfix * 64 + 4 * u4);
  __syncthreads();

#pragma unroll
  for (int q = 0; q < 8; q++) {
    int e = lane + (q << 6);
    int i = e >> 5;
    float acc = b2[cfix];
#pragma unroll
    for (int u = 0; u < 64; u++) acc += pssh[i * 66 + u] * w2r[u];
    psso[i * 34 + cfix] = acc + psst[i * 34 + cfix];
  }
  __syncthreads();
  ln_16xS(psso, ln2g, ln2b, lane);
  __syncthreads();

  const float* xp = x + (size_t)p * 512;
  const int row = lane >> 2, c0v = (lane & 3) << 3;
  float zv[8];
#pragma unroll
  for (int n = 0; n < 8; n++)
    zv[n] = xp[(lane << 3) + n] + psso[row * 34 + c0v + n];
  float* zo = z + (size_t)p * 512 + (lane << 3);
  *(float4*)(zo)     = *(float4*)(zv);
  *(float4*)(zo + 4) = *(float4*)(zv + 4);
  ushort8 hv, lv;
  float s2 = 0.f;
#pragma unroll
  for (int n = 0; n < 8; n++) {
    s2 += zv[n] * zv[n];
    ushort h = f2b_rne(zv[n]);
    hv[n] = h;
    lv[n] = f2b_rne(zv[n] - b2f(h));
  }
  *(ushort8*)(zh + (size_t)p * 512 + (lane << 3)) = hv;
  *(ushort8*)(zl + (size_t)p * 512 + (lane << 3)) = lv;
#pragma unroll
  for (int off = 1; off < 64; off <<= 1) s2 += __shfl_xor(s2, off);
  if (lane == 0) znorm[p] = s2;
}

// ---------------------------------------------------------------------------
// cbnorm + bf16 split of the codebook (ch/cl).
// ---------------------------------------------------------------------------
__global__ __launch_bounds__(64) void cbnorm_kernel(
    const float* __restrict__ cb, float* __restrict__ cbn,
    ushort* __restrict__ ch, ushort* __restrict__ cl) {
  int c = blockIdx.x, lane = threadIdx.x;
  const float* r = cb + (size_t)c * 512 + lane * 8;
  float v[8];
  *(float4*)(v)     = *(const float4*)(r);
  *(float4*)(v + 4) = *(const float4*)(r + 4);
  float s = 0.f;
  ushort8 hv, lv;
#pragma unroll
  for (int n = 0; n < 8; n++) {
    s += v[n] * v[n];
    ushort h = f2b_rne(v[n]);
    hv[n] = h;
    lv[n] = f2b_rne(v[n] - b2f(h));
  }
  *(ushort8*)(ch + (size_t)c * 512 + lane * 8) = hv;
  *(ushort8*)(cl + (size_t)c * 512 + lane * 8) = lv;
#pragma unroll
  for (int off = 1; off < 64; off <<= 1) s += __shfl_xor(s, off);
  if (lane == 0) cbn[c] = s;
}

// ---------------------------------------------------------------------------
// VQ scores via bf16x3 MFMA with fused argmin epilogue + XCD swizzle.
// ---------------------------------------------------------------------------
__global__ __launch_bounds__(256) void gemm_vq_b3(
    const ushort* __restrict__ Ah, const ushort* __restrict__ Al,
    const ushort* __restrict__ Bh, const ushort* __restrict__ Bl,
    const float* __restrict__ znorm, const float* __restrict__ cbn,
    u64* __restrict__ packed) {
  __shared__ ushort sAh[4096], sAl[4096], sBh[4096], sBl[4096];
  const int cpx = gridDim.x >> 3;
  const int bid = (blockIdx.x & 7) * cpx + (blockIdx.x >> 3);
  const int bx = bid & 7, by = bid >> 3;
  const int m0 = by << 7, n0 = bx << 7;
  const int tid = threadIdx.x;
  const int wid = tid >> 6, lane = tid & 63;
  const int wr = wid >> 1, wc = wid & 1;
  const int l15 = lane & 15, lk = lane >> 4;

  const f32x4 fzero = {0.f, 0.f, 0.f, 0.f};
  f32x4 acc[4][4];
#pragma unroll
  for (int i = 0; i < 4; i++)
#pragma unroll
    for (int j = 0; j < 4; j++) acc[i][j] = fzero;

  for (int k0 = 0; k0 < 512; k0 += 32) {
#pragma unroll
    for (int c = 0; c < 2; c++) {
      const int I = tid + (c << 8);
      const int r = I >> 2, kk = (I & 3) << 3;
      const size_t ga = (size_t)(m0 + r) * 512 + k0 + kk;
      const size_t gb = (size_t)(n0 + r) * 512 + k0 + kk;
      const size_t lo = (size_t)((wid << 6) + (c << 8)) * 8;
      gload16(Ah + ga, sAh + lo);
      gload16(Al + ga, sAl + lo);
      gload16(Bh + gb, sBh + lo);
      gload16(Bl + gb, sBl + lo);
    }
    __syncthreads();

    short8 ah[4], al[4], bh[4], bl[4];
#pragma unroll
    for (int m = 0; m < 4; m++) {
      const int ar = ((wr << 6) + (m << 4) + l15) * 32 + lk * 8;
      ah[m] = *(const short8*)(sAh + ar);
      al[m] = *(const short8*)(sAl + ar);
      const int br = ((wc << 6) + (m << 4) + l15) * 32 + lk * 8;
      bh[m] = *(const short8*)(sBh + br);
      bl[m] = *(const short8*)(sBl + br);
    }
#pragma unroll
    for (int m = 0; m < 4; m++)
#pragma unroll
      for (int n = 0; n < 4; n++) {
        acc[m][n] = __builtin_amdgcn_mfma_f32_16x16x32_bf16(ah[m], bh[n],
                                                            acc[m][n], 0, 0, 0);
        acc[m][n] = __builtin_amdgcn_mfma_f32_16x16x32_bf16(ah[m], bl[n],
                                                            acc[m][n], 0, 0, 0);
        acc[m][n] = __builtin_amdgcn_mfma_f32_16x16x32_bf16(al[m], bh[n],
                                                            acc[m][n], 0, 0, 0);
      }
    __syncthreads();
  }

  float zn[4][4];
#pragma unroll
  for (int m = 0; m < 4; m++)
#pragma unroll
    for (int r = 0; r < 4; r++)
      zn[m][r] = znorm[m0 + (wr << 6) + (m << 4) + (lk << 2) + r];
  float cbnv[4];
#pragma unroll
  for (int n = 0; n < 4; n++)
    cbnv[n] = cbn[n0 + (wc << 6) + (n << 4) + l15];

#pragma unroll
  for (int m = 0; m < 4; m++) {
#pragma unroll
    for (int r = 0; r < 4; r++) {
      u64 best = ~0ull;
#pragma unroll
      for (int n = 0; n < 4; n++) {
        const int gcol = n0 + (wc << 6) + (n << 4) + l15;
        float d = (zn[m][r] + cbnv[n]) - 2.0f * acc[m][n][r];
        u64 key = ((u64)fkey(d) << 32) | (unsigned)gcol;
        best = best < key ? best : key;
      }
#pragma unroll
      for (int off = 1; off < 16; off <<= 1) {
        u64 o = __shfl_xor(best, off);
        best = best < o ? best : o;
      }
      if (l15 == 0) {
        const int grow = m0 + (wr << 6) + (m << 4) + (lk << 2) + r;
        atomicMin(&packed[grow], best);
      }
    }
  }
}

// ---------------------------------------------------------------------------
// slim VQ finish: idx + loss partial + t (bf16 only, = q + pos).
// ---------------------------------------------------------------------------
__global__ __launch_bounds__(256) void vq_slim_kernel(
    const u64* __restrict__ packed, const float* __restrict__ cb,
    const float* __restrict__ z, const float* __restrict__ tf_pos,
    ushort* __restrict__ th,
    float* __restrict__ idx_out, float* __restrict__ loss_part) {
  __shared__ float spart[4];
  const int wv = threadIdx.x >> 6;
  const int r = (blockIdx.x << 2) + wv;
  const int lane = threadIdx.x & 63;
  const int bi = (int)(unsigned)(packed[r] & 0xFFFFFFFFull);
  const float* zr = z + (size_t)r * 512 + (lane << 3);
  const float* q = cb + (size_t)bi * 512 + (lane << 3);
  const float* pr = tf_pos + (size_t)(r & 255) * 512 + (lane << 3);
  float zv[8], qv[8], pv[8];
  *(float4*)(zv)     = *(const float4*)(zr);
  *(float4*)(zv + 4) = *(const float4*)(zr + 4);
  *(float4*)(qv)     = *(const float4*)(q);
  *(float4*)(qv + 4) = *(const float4*)(q + 4);
  *(float4*)(pv)     = *(const float4*)(pr);
  *(float4*)(pv + 4) = *(const float4*)(pr + 4);
  float lsum = 0.f;
  ushort8 w;
#pragma unroll
  for (int n = 0; n < 8; n++) {
    float diff = qv[n] - zv[n];
    lsum += diff * diff;
    w[n] = f2b_rne(qv[n] + pv[n]);
  }
  *(ushort8*)(th + (size_t)r * 512 + (lane << 3)) = w;
#pragma unroll
  for (int off = 1; off < 64; off <<= 1) lsum += __shfl_xor(lsum, off);
  if (lane == 0) {
    idx_out[r] = (float)bi;
    spart[wv] = lsum;
  }
  __syncthreads();
  if (threadIdx.x == 0)
    loss_part[blockIdx.x] = (spart[0] + spart[1]) + (spart[2] + spart[3]);
}

// ---------------------------------------------------------------------------
__global__ __launch_bounds__(256) void loss_reduce_kernel(
    const float* __restrict__ loss_part, float* __restrict__ loss_out) {
  __shared__ float sw[4];
  float s = 0.f;
  for (int i = threadIdx.x; i < 4096; i += 256) s += loss_part[i];
#pragma unroll
  for (int off = 1; off < 64; off <<= 1) s += __shfl_xor(s, off);
  const int wv = threadIdx.x >> 6;
  if ((threadIdx.x & 63) == 0) sw[wv] = s;
  __syncthreads();
  if (threadIdx.x == 0)
    loss_out[0] = ((sw[0] + sw[1]) + (sw[2] + sw[3])) * (1.25f / 8388608.0f);
}

// ---------------------------------------------------------------------------
// bf16 MFMA GEMM, BK=64 dual sub-tile LDS [2][128][32], XCD swizzle.
// ---------------------------------------------------------------------------
template <int OUTMODE>
__global__ __launch_bounds__(256) void gemm_bf16_kernel(
    const ushort* __restrict__ A, const ushort* __restrict__ B,
    const float* __restrict__ bias, void* __restrict__ Cout,
    int M, int N, int K) {
  __shared__ ushort As[8192];  // [2][128][32]
  __shared__ ushort Bs[8192];
  const int nbx = N >> 7;
  const int cpx = gridDim.x >> 3;
  const int bid = (blockIdx.x & 7) * cpx + (blockIdx.x >> 3);
  const int bx = bid % nbx, by = bid / nbx;
  const int m0 = by << 7, n0 = bx << 7;
  const int tid = threadIdx.x;
  const int wid = tid >> 6, lane = tid & 63;
  const int wr = wid >> 1, wc = wid & 1;
  const int l15 = lane & 15, lk = lane >> 4;

  const f32x4 fzero = {0.f, 0.f, 0.f, 0.f};
  f32x4 acc[4][4];
#pragma unroll
  for (int i = 0; i < 4; i++)
#pragma unroll
    for (int j = 0; j < 4; j++) acc[i][j] = fzero;

  for (int k0 = 0; k0 < K; k0 += 64) {
#pragma unroll
    for (int c = 0; c < 4; c++) {
      const int base = (c << 8) + (wid << 6);
      const int half = base >> 9;
      const int Jb = base & 511;
      const int J = Jb + lane;
      const int r = J >> 2, kk = (J & 3) << 3;
      gload16(A + (size_t)(m0 + r) * K + k0 + (half << 5) + kk,
              As + (size_t)((half << 12) + Jb * 8));
      gload16(B + (size_t)(n0 + r) * K + k0 + (half << 5) + kk,
              Bs + (size_t)((half << 12) + Jb * 8));
    }
    __syncthreads();

#pragma unroll
    for (int kc = 0; kc < 2; kc++) {
      short8 a[4], b[4];
#pragma unroll
      for (int m = 0; m < 4; m++) {
        const int ar = (kc << 12) + ((wr << 6) + (m << 4) + l15) * 32 + lk * 8;
        a[m] = *(const short8*)(As + ar);
        const int br = (kc << 12) + ((wc << 6) + (m << 4) + l15) * 32 + lk * 8;
        b[m] = *(const short8*)(Bs + br);
      }
#pragma unroll
      for (int m = 0; m < 4; m++)
#pragma unroll
        for (int n = 0; n < 4; n++)
          acc[m][n] = __builtin_amdgcn_mfma_f32_16x16x32_bf16(a[m], b[n],
                                                              acc[m][n], 0, 0, 0);
    }
    __syncthreads();
  }

  float bv[4];
#pragma unroll
  for (int n = 0; n < 4; n++)
    bv[n] = bias[n0 + (wc << 6) + (n << 4) + l15];

#pragma unroll
  for (int m = 0; m < 4; m++) {
#pragma unroll
    for (int n = 0; n < 4; n++) {
      const int gcol = n0 + (wc << 6) + (n << 4) + l15;
#pragma unroll
      for (int r = 0; r < 4; r++) {
        const int grow = m0 + (wr << 6) + (m << 4) + (lk << 2) + r;
        float v = acc[m][n][r] + bv[n];
        if (OUTMODE == 0) {
          ((float*)Cout)[(size_t)grow * N + gcol] = v;
        } else if (OUTMODE == 1) {
          ((ushort*)Cout)[(size_t)grow * N + gcol] = f2b_rne(gelu_exact(v));
        } else {
          ((ushort*)Cout)[(size_t)grow * N + gcol] = f2b_rne(v);
        }
      }
    }
  }
}

// ---------------------------------------------------------------------------
// Weight conversions.
// ---------------------------------------------------------------------------
__global__ void cvt_flat(const float* __restrict__ in, ushort* __restrict__ out,
                         int n) {
  int i = blockIdx.x * blockDim.x + threadIdx.x;
  const int stride = gridDim.x * blockDim.x;
  for (; i < n; i += stride) out[i] = f2b_rne(in[i]);
}

__global__ __launch_bounds__(256) void cvt_tr(const float* __restrict__ in,
                                              ushort* __restrict__ out,
                                              int R, int C) {
  __shared__ float tile[32][33];
  const int bc = blockIdx.x, br = blockIdx.y, lay = blockIdx.z;
  const float* src = in + (size_t)lay * R * C;
  ushort* dst = out + (size_t)lay * R * C;
  const int tid = threadIdx.x;
#pragma unroll
  for (int q = 0; q < 4; q++) {
    int idx = tid + (q << 8);
    int rr = idx >> 5, cc = idx & 31;
    tile[rr][cc] = src[(size_t)(br * 32 + rr) * C + bc * 32 + cc];
  }
  __syncthreads();
#pragma unroll
  for (int q = 0; q < 4; q++) {
    int idx = tid + (q << 8);
    int co = idx >> 5, ro = idx & 31;
    dst[(size_t)(bc * 32 + co) * R + br * 32 + ro] = f2b_rne(tile[ro][co]);
  }
}

// ---------------------------------------------------------------------------
// MFMA flash attention with next-tile K/V register prefetch + setprio.
// ---------------------------------------------------------------------------
__global__ __launch_bounds__(64) void attn_mfma_kernel(
    const ushort* __restrict__ qkv, ushort* __restrict__ o) {
  __shared__ ushort lds[8192];
  char* KsB = (char*)lds;
  char* VtB = (char*)(lds + 4096);
  const int bid = blockIdx.x;
  const int xcd = bid & 7, slot = bid >> 3;
  const int b = (xcd << 3) | (slot >> 5);
  const int h = (slot >> 2) & 7;
  const int qb = slot & 3;
  const int lane = threadIdx.x;
  const int l15 = lane & 15, lk4 = lane >> 4;

  short8 qf[4][2];
#pragma unroll
  for (int m = 0; m < 4; m++)
#pragma unroll
    for (int kc = 0; kc < 2; kc++)
      qf[m][kc] = *(const short8*)(qkv +
          (size_t)(b * 256 + qb * 64 + m * 16 + l15) * 1536 +
          h * 64 + kc * 32 + lk4 * 8);

  const f32x4 fz = {0.f, 0.f, 0.f, 0.f};
  f32x4 O[4][4];
#pragma unroll
  for (int m = 0; m < 4; m++)
#pragma unroll
    for (int n = 0; n < 4; n++) O[m][n] = fz;
  float lsum[4][4];
#pragma unroll
  for (int m = 0; m < 4; m++)
#pragma unroll
    for (int r = 0; r < 4; r++) lsum[m][r] = 0.f;

  ushort8 kv[8], vv[8];
  {
    const ushort* krow = qkv + (size_t)(b * 256 + lane) * 1536 + 512 + h * 64;
#pragma unroll
    for (int u = 0; u < 8; u++) kv[u] = ((const ushort8*)krow)[u];
#pragma unroll
    for (int u = 0; u < 8; u++) vv[u] = ((const ushort8*)(krow + 512))[u];
  }

  for (int jt = 0; jt <= qb; jt++) {
    __syncthreads();
    {
      const int rx = (lane & 7) << 4;
#pragma unroll
      for (int u = 0; u < 8; u++)
        *(ushort8*)(KsB + lane * 128 + ((u << 4) ^ rx)) = kv[u];
#pragma unroll
      for (int u = 0; u < 8; u++)
#pragma unroll
        for (int i = 0; i < 8; i++) {
          const int d = u * 8 + i;
          *(ushort*)(VtB + ((d * 128 + lane * 2) ^ ((d & 7) << 4))) =
              (ushort)vv[u][i];
        }
    }
    __syncthreads();

    if (jt < qb) {
      const ushort* krow = qkv +
          (size_t)(b * 256 + (jt + 1) * 64 + lane) * 1536 + 512 + h * 64;
#pragma unroll
      for (int u = 0; u < 8; u++) kv[u] = ((const ushort8*)krow)[u];
#pragma unroll
      for (int u = 0; u < 8; u++) vv[u] = ((const ushort8*)(krow + 512))[u];
    }

    f32x4 sacc[4][4];
#pragma unroll
    for (int m = 0; m < 4; m++)
#pragma unroll
      for (int n = 0; n < 4; n++) sacc[m][n] = fz;
    __builtin_amdgcn_s_setprio(1);
#pragma unroll
    for (int kc = 0; kc < 2; kc++) {
      short8 bf[4];
#pragma unroll
      for (int n = 0; n < 4; n++) {
        const int row = n * 16 + l15;
        bf[n] = *(const short8*)(KsB + row * 128 +
                                 ((kc * 64 + lk4 * 16) ^ ((row & 7) << 4)));
      }
#pragma unroll
      for (int m = 0; m < 4; m++)
#pragma unroll
        for (int n = 0; n < 4; n++)
          sacc[m][n] = __builtin_amdgcn_mfma_f32_16x16x32_bf16(
              qf[m][kc], bf[n], sacc[m][n], 0, 0, 0);
    }
    __builtin_amdgcn_s_setprio(0);
    __syncthreads();

    const bool diag = (jt == qb);
#pragma unroll
    for (int m = 0; m < 4; m++)
#pragma unroll
      for (int n = 0; n < 4; n++)
#pragma unroll
        for (int r = 0; r < 4; r++) {
          const int ql = m * 16 + lk4 * 4 + r;
          const int jl = n * 16 + l15;
          float e = __expf(sacc[m][n][r] * 0.125f);
          if (diag && jl > ql) e = 0.f;
          const ushort pu = f2b_rne(e);
          lsum[m][r] += b2f(pu);
          *(ushort*)(KsB + ql * 128 + ((jl * 2) ^ ((ql & 7) << 4))) = pu;
        }
    __syncthreads();

    __builtin_amdgcn_s_setprio(1);
#pragma unroll
    for (int kc = 0; kc < 2; kc++) {
      short8 pf[4], vf[4];
#pragma unroll
      for (int m = 0; m < 4; m++) {
        const int row = m * 16 + l15;
        pf[m] = *(const short8*)(KsB + row * 128 +
                                 ((kc * 64 + lk4 * 16) ^ ((row & 7) << 4)));
      }
#pragma unroll
      for (int n = 0; n < 4; n++) {
        const int row = n * 16 + l15;
        vf[n] = *(const short8*)(VtB + row * 128 +
                                 ((kc * 64 + lk4 * 16) ^ ((row & 7) << 4)));
      }
#pragma unroll
      for (int m = 0; m < 4; m++)
#pragma unroll
        for (int n = 0; n < 4; n++)
          O[m][n] = __builtin_amdgcn_mfma_f32_16x16x32_bf16(
              pf[m], vf[n], O[m][n], 0, 0, 0);
    }
    __builtin_amdgcn_s_setprio(0);
  }

  float inv[4][4];
#pragma unroll
  for (int m = 0; m < 4; m++)
#pragma unroll
    for (int r = 0; r < 4; r++) {
      float v = lsum[m][r];
      v += __shfl_xor(v, 1); v += __shfl_xor(v, 2);
      v += __shfl_xor(v, 4); v += __shfl_xor(v, 8);
      inv[m][r] = 1.0f / v;
    }
#pragma unroll
  for (int m = 0; m < 4; m++)
#pragma unroll
    for (int n = 0; n < 4; n++)
#pragma unroll
      for (int r = 0; r < 4; r++) {
        const int row = b * 256 + qb * 64 + m * 16 + lk4 * 4 + r;
        const int col = h * 64 + n * 16 + l15;
        o[(size_t)row * 512 + col] = f2b_rne(O[m][n][r] * inv[m][r]);
      }
}

// ---------------------------------------------------------------------------
// LayerNorm over 512, bf16 in / bf16 out (+optional f32 out for final).
// x = b2f(xin_b) [+ b2f(addin_b)].
// ---------------------------------------------------------------------------
__global__ __launch_bounds__(256) void ln_kernel(
    const ushort* __restrict__ xin_b, const ushort* __restrict__ addin_b,
    const float* __restrict__ g, const float* __restrict__ bb,
    ushort* __restrict__ outb, float* __restrict__ outp) {
  const int r = blockIdx.x * 4 + (threadIdx.x >> 6);
  const int lane = threadIdx.x & 63;
  ushort8 xv = *(const ushort8*)(xin_b + (size_t)r * 512 + lane * 8);
  float v[8];
#pragma unroll
  for (int n = 0; n < 8; n++) v[n] = b2f(xv[n]);
  if (addin_b) {
    ushort8 a = *(const ushort8*)(addin_b + (size_t)r * 512 + lane * 8);
#pragma unroll
    for (int n = 0; n < 8; n++) v[n] += b2f(a[n]);
  }
  float s = 0.f, s2 = 0.f;
#pragma unroll
  for (int n = 0; n < 8; n++) { s += v[n]; s2 += v[n] * v[n]; }
#pragma unroll
  for (int off = 1; off < 64; off <<= 1) {
    s += __shfl_xor(s, off);
    s2 += __shfl_xor(s2, off);
  }
  float m = s * (1.0f / 512.0f);
  float var = s2 * (1.0f / 512.0f) - m * m;
  float inv = 1.0f / sqrtf(var + 1e-5f);
  const int c0 = lane * 8;
  float outv[8];
#pragma unroll
  for (int n = 0; n < 8; n++) outv[n] = (v[n] - m) * inv * g[c0 + n] + bb[c0 + n];
  if (outb) {
    ushort8 w;
#pragma unroll
    for (int n = 0; n < 8; n++) w[n] = f2b_rne(outv[n]);
    *(ushort8*)(outb + (size_t)r * 512 + c0) = w;
  }
  if (outp) {
    float* orow = outp + (size_t)r * 512 + c0;
    *(float4*)(orow)     = *(float4*)(outv);
    *(float4*)(orow + 4) = *(float4*)(outv + 4);
  }
}

// ---------------------------------------------------------------------------
extern "C" void kernel_launch(void* const* d_in, const int* in_sizes, int n_in,
                              void* d_out, int out_size, void* d_ws, size_t ws_size,
                              hipStream_t stream) {
  const float* x       = (const float*)d_in[0];
  const float* pa_lq   = (const float*)d_in[1];
  const float* pa_pos  = (const float*)d_in[2];
  const float* pa_win  = (const float*)d_in[3];
  const float* pa_bin  = (const float*)d_in[4];
  const float* pa_wout = (const float*)d_in[5];
  const float* pa_bout = (const float*)d_in[6];
  const float* pa_ln1g = (const float*)d_in[7];
  const float* pa_ln1b = (const float*)d_in[8];
  const float* pa_ln2g = (const float*)d_in[9];
  const float* pa_ln2b = (const float*)d_in[10];
  const float* pa_w1   = (const float*)d_in[11];
  const float* pa_b1   = (const float*)d_in[12];
  const float* pa_w2   = (const float*)d_in[13];
  const float* pa_b2   = (const float*)d_in[14];
  const float* cb      = (const float*)d_in[15];
  const float* tf_pos  = (const float*)d_in[16];
  const float* tf_win  = (const float*)d_in[17];
  const float* tf_bin  = (const float*)d_in[18];
  const float* tf_wout = (const float*)d_in[19];
  const float* tf_bout = (const float*)d_in[20];
  const float* tf_ln1g = (const float*)d_in[21];
  const float* tf_ln1b = (const float*)d_in[22];
  const float* tf_ln2g = (const float*)d_in[23];
  const float* tf_ln2b = (const float*)d_in[24];
  const float* tf_w1   = (const float*)d_in[25];
  const float* tf_b1   = (const float*)d_in[26];
  const float* tf_w2   = (const float*)d_in[27];
  const float* tf_b2   = (const float*)d_in[28];
  const float* fin_g   = (const float*)d_in[29];
  const float* fin_b   = (const float*)d_in[30];

  float* yout = (float*)d_out;            // 16384 x 512
  float* loss_out = yout + 8388608;       // scalar
  float* idx_out = loss_out + 1;          // 16384 (as float)

  float* ws   = (float*)d_ws;
  float* z    = ws;                   // 8388608
  float* tb   = z + 8388608;          // 8388608 (unused; kept for layout)
  float* bufA = tb + 8388608;         // 16777216 (tf: qkv/ffn-h)
  float* bufC = bufA + 16777216;      // 8388608  (patch: zh/zl ; tf: projh bf16)
  float* wreg = bufC + 8388608;       // 6291456
  float* treg = wreg + 6291456;       // 4194304  (VQ: ch/cl ; tf: tbh)
  float* cbn  = treg + 4194304;       // 1024
  float* q16  = cbn + 1024;           // 512
  float* w1T  = q16 + 512;            // 2048
  float* w2T  = w1T + 2048;           // 2048
  float* znorm = w2T + 2048;          // 16384
  u64*   packed = (u64*)(znorm + 16384);  // 16384 u64
  float* loss_part = (float*)(packed + 16384); // 4096

  ushort* win_b  = (ushort*)wreg;
  ushort* wout_b = win_b + 3145728;
  ushort* w1t_b  = wout_b + 1048576;
  ushort* w2t_b  = w1t_b + 4194304;
  ushort* tbh    = (ushort*)treg;
  ushort* qkvh   = (ushort*)bufA;
  ushort* abh    = (ushort*)z;
  ushort* zh_b   = (ushort*)bufC;
  ushort* zl_b   = zh_b + 8388608;
  ushort* projh  = (ushort*)bufC;          // bf16 proj outputs (zh/zl dead)
  ushort* ch_b   = (ushort*)treg;          // dead before tbh written
  ushort* cl_b   = ch_b + 524288;

  hipMemsetAsync(packed, 0xFF, 16384 * sizeof(u64), stream);
  cbnorm_kernel<<<1024, 64, 0, stream>>>(cb, cbn, ch_b, cl_b);
  patch_setup_kernel<<<1, 64, 0, stream>>>(pa_lq, pa_win, pa_bin, pa_w1,
                                           pa_w2, q16, w1T, w2T);

  // fused patch encoder (z bit-identical)
  pkF_kernel<<<4096, 256, 0, stream>>>(x, pa_pos, pa_win, pa_bin, q16,
                                       pa_wout, pa_bout, pa_lq,
                                       pa_ln1g, pa_ln1b, w1T, pa_b1,
                                       w2T, pa_b2, pa_ln2g, pa_ln2b,
                                       z, zh_b, zl_b, znorm);

  cvt_flat<<<2048, 256, 0, stream>>>(tf_win, win_b, 3145728);
  cvt_flat<<<1024, 256, 0, stream>>>(tf_wout, wout_b, 1048576);
  cvt_tr<<<dim3(64, 16, 4), 256, 0, stream>>>(tf_w1, w1t_b, 512, 2048);
  cvt_tr<<<dim3(16, 64, 4), 256, 0, stream>>>(tf_w2, w2t_b, 2048, 512);

  gemm_vq_b3<<<dim3(1024), 256, 0, stream>>>(zh_b, zl_b, ch_b, cl_b,
                                             znorm, cbn, packed);
  vq_slim_kernel<<<4096, 256, 0, stream>>>(packed, cb, z, tf_pos, tbh,
                                           idx_out, loss_part);
  loss_reduce_kernel<<<1, 256, 0, stream>>>(loss_part, loss_out);

  for (int l = 0; l < 4; l++) {
    gemm_bf16_kernel<2><<<dim3(128 * 12), 256, 0, stream>>>(
        tbh, win_b + (size_t)l * 1536 * 512, tf_bin + l * 1536, qkvh,
        16384, 1536, 512);
    attn_mfma_kernel<<<dim3(2048), 64, 0, stream>>>(qkvh, abh);
    gemm_bf16_kernel<2><<<dim3(128 * 4), 256, 0, stream>>>(
        abh, wout_b + (size_t)l * 512 * 512, tf_bout + l * 512, projh,
        16384, 512, 512);
    ln_kernel<<<dim3(4096), 256, 0, stream>>>(tbh, projh, tf_ln1g + l * 512,
                                              tf_ln1b + l * 512, tbh, nullptr);
    gemm_bf16_kernel<1><<<dim3(128 * 16), 256, 0, stream>>>(
        tbh, w1t_b + (size_t)l * 1048576, tf_b1 + l * 2048, qkvh,
        16384, 2048, 512);
    gemm_bf16_kernel<2><<<dim3(128 * 4), 256, 0, stream>>>(
        qkvh, w2t_b + (size_t)l * 1048576, tf_b2 + l * 512, projh,
        16384, 512, 2048);
    ln_kernel<<<dim3(4096), 256, 0, stream>>>(tbh, projh, tf_ln2g + l * 512,
                                              tf_ln2b + l * 512, tbh, nullptr);
  }
  ln_kernel<<<dim3(4096), 256, 0, stream>>>(tbh, nullptr, fin_g, fin_b,
                                            nullptr, yout);

  (void)in_sizes; (void)n_in; (void)out_size; (void)ws_size;
}

// Round 18
// 1183.363 us; speedup vs baseline: 1.2679x; 1.0377x over previous
//
#include <hip/hip_runtime.h>

// PatchVQVAETransformer forward, round 18:
//  - f32 z buffer dropped: pkF writes only zh/zl/znorm; vq_slim reconstructs
//    z' = b2f(zh)+b2f(zl) for the loss (drift ~1e-7; idx path untouched).
//  - attn output repacked via LDS -> 128B-contiguous bf16 stores.
//  - everything else unchanged from r17.

#define SQRT1_2F 0.70710678118654752440f

typedef __attribute__((ext_vector_type(8))) short short8;
typedef __attribute__((ext_vector_type(4))) float f32x4;
typedef __attribute__((ext_vector_type(8))) unsigned short ushort8;
typedef unsigned short ushort;
typedef unsigned long long u64;

__device__ __forceinline__ float gelu_exact(float v) {
  return 0.5f * v * (1.0f + erff(v * SQRT1_2F));
}

__device__ __forceinline__ ushort f2b_rne(float f) {
  unsigned u = __float_as_uint(f);
  unsigned r = (u + 0x7fffu + ((u >> 16) & 1u)) >> 16;
  return (ushort)r;
}

__device__ __forceinline__ float b2f(ushort u) {
  return __uint_as_float(((unsigned)u) << 16);
}

__device__ __forceinline__ void gload16(const void* g, void* l) {
  __builtin_amdgcn_global_load_lds(
      (const __attribute__((address_space(1))) void*)g,
      (__attribute__((address_space(3))) void*)l, 16, 0, 0);
}

// monotone float->u32 (finite inputs): preserves <
__device__ __forceinline__ unsigned fkey(float d) {
  unsigned u = __float_as_uint(d);
  return (u & 0x80000000u) ? ~u : (u | 0x80000000u);
}

// ---------------------------------------------------------------------------
// One-time setup: q16 = lq@wq^T + bq; w1T[u][d]=w1[d][u]; w2T[c][u]=w2[u][c].
// ---------------------------------------------------------------------------
__global__ __launch_bounds__(64) void patch_setup_kernel(
    const float* __restrict__ lq, const float* __restrict__ win,
    const float* __restrict__ bin, const float* __restrict__ w1,
    const float* __restrict__ w2, float* __restrict__ q16,
    float* __restrict__ w1T, float* __restrict__ w2T) {
  const int tid = threadIdx.x;
#pragma unroll
  for (int q = 0; q < 8; q++) {
    int e = tid + (q << 6);
    int i = e >> 5, c = e & 31;
    const float* wr = win + (size_t)c * 32;
    float acc = bin[c];
#pragma unroll
    for (int d = 0; d < 32; d++) acc += lq[(i << 5) + d] * wr[d];
    q16[e] = acc;
  }
#pragma unroll
  for (int q = 0; q < 32; q++) {
    int e = tid + (q << 6);          // e = u*32 + d
    int u = e >> 5, d = e & 31;
    w1T[e] = w1[(size_t)d * 64 + u];
  }
#pragma unroll
  for (int q = 0; q < 32; q++) {
    int e = tid + (q << 6);          // e = c*64 + u
    int c = e >> 6, u = e & 63;
    w2T[e] = w2[(size_t)u * 32 + c];
  }
}

// ---------------------------------------------------------------------------
// LN over 16 rows x 32 cols at row-stride 34 in LDS, in place. 4 lanes/row.
// ---------------------------------------------------------------------------
__device__ __forceinline__ void ln_16xS(float* buf, const float* g,
                                        const float* bb, int tid) {
  int row = tid >> 2, sub = tid & 3;
  int c0 = sub << 3;
  float* r = buf + row * 34 + c0;
  float v[8];
  float s = 0.f, s2 = 0.f;
#pragma unroll
  for (int n = 0; n < 8; n++) {
    float t = r[n];
    v[n] = t; s += t; s2 += t * t;
  }
  s += __shfl_xor(s, 1);  s += __shfl_xor(s, 2);
  s2 += __shfl_xor(s2, 1); s2 += __shfl_xor(s2, 2);
  float m = s * (1.0f / 32.0f);
  float var = s2 * (1.0f / 32.0f) - m * m;
  float inv = 1.0f / sqrtf(var + 1e-5f);
#pragma unroll
  for (int n = 0; n < 8; n++)
    r[n] = (v[n] - m) * inv * g[c0 + n] + bb[c0 + n];
}

// ---------------------------------------------------------------------------
// pkF: fused patch encoder (z values bit-identical; z f32 no longer stored).
// ---------------------------------------------------------------------------
__global__ __launch_bounds__(256) void pkF_kernel(
    const float* __restrict__ x, const float* __restrict__ pos,
    const float* __restrict__ win, const float* __restrict__ bin,
    const float* __restrict__ q16,
    const float* __restrict__ wout, const float* __restrict__ bout,
    const float* __restrict__ lq,
    const float* __restrict__ ln1g, const float* __restrict__ ln1b,
    const float* __restrict__ w1T, const float* __restrict__ b1,
    const float* __restrict__ w2T, const float* __restrict__ b2,
    const float* __restrict__ ln2g, const float* __restrict__ ln2b,
    ushort* __restrict__ zh, ushort* __restrict__ zl,
    float* __restrict__ znorm) {
  __shared__ float sso[2176];
  __shared__ float ubuf[6672];
  float* sxp  = ubuf;
  float* skv  = ubuf + 2048;
  float* sq16 = ubuf + 6144;
  float* sstA = ubuf;
  float* sshA = ubuf + 2176;

  const int blk = blockIdx.x, t = threadIdx.x;
  const int p0 = blk << 2;
  const int cfix = t & 31;
  const int wv = t >> 6, lane = t & 63;

#pragma unroll
  for (int q = 0; q < 8; q++) {
    int e = t + (q << 8);
    int pl = e >> 9, r = e & 511;
    sxp[e] = x[(size_t)(p0 + pl) * 512 + r] + pos[r];
  }
  if (t < 128) {
#pragma unroll
    for (int q = 0; q < 4; q++) {
      int e = t + (q << 7);
      sq16[(e >> 5) * 33 + (e & 31)] = q16[e];
    }
  }

  float wr0[32], wr1[32];
#pragma unroll
  for (int d4 = 0; d4 < 8; d4++) {
    *(float4*)(wr0 + 4 * d4) =
        *(const float4*)(win + (size_t)(32 + cfix) * 32 + 4 * d4);
    *(float4*)(wr1 + 4 * d4) =
        *(const float4*)(win + (size_t)(64 + cfix) * 32 + 4 * d4);
  }
  const float bk = bin[32 + cfix];
  const float bvv = bin[64 + cfix];
  __syncthreads();

#pragma unroll
  for (int q = 0; q < 16; q++) {
    int e = t + (q << 8);
    int pl = e >> 10, rr = e & 1023;
    int w = rr >> 9, rj = rr & 511, j = rj >> 5;
    const float* sx = sxp + (pl << 9) + (j << 5);
    const float* wreg = w ? wr1 : wr0;
    float acc = w ? bvv : bk;
#pragma unroll
    for (int d = 0; d < 32; d++) acc += sx[d] * wreg[d];
    skv[e] = acc;
  }
  __syncthreads();

  {
    const int pl = t >> 6, hh = (t >> 4) & 3, i = t & 15;
    const float* kp = skv + (pl << 10);
    const int hd = hh << 3;

    float sc[16];
#pragma unroll
    for (int j = 0; j < 16; j++) {
      float acc = 0.f;
#pragma unroll
      for (int d = 0; d < 8; d++)
        acc += sq16[i * 33 + hd + d] * kp[(j << 5) + hd + d];
      sc[j] = acc * 0.35355339059327373f;
    }
    {
      float mx = sc[0];
#pragma unroll
      for (int j = 1; j < 16; j++) mx = fmaxf(mx, sc[j]);
      float sm = 0.f;
      float ev[16];
#pragma unroll
      for (int j = 0; j < 16; j++) { ev[j] = expf(sc[j] - mx); sm += ev[j]; }
      float inv = 1.0f / sm;
#pragma unroll
      for (int j = 0; j < 16; j++) sc[j] = ev[j] * inv;
    }
    float* orow = sso + pl * 544 + i * 34 + hd;
#pragma unroll
    for (int c8 = 0; c8 < 8; c8++) {
      const int c = hd + c8;
      float acc = 0.f;
#pragma unroll
      for (int j = 0; j < 16; j++) acc += sc[j] * kp[512 + (j << 5) + c];
      orow[c8] = acc;
    }
  }
  __syncthreads();

  const int p = p0 + wv;
  float* psso = sso + wv * 544;
  float* psst = sstA + wv * 544;
  float* pssh = sshA + wv * 1056;

  float wo[32];
#pragma unroll
  for (int d4 = 0; d4 < 8; d4++)
    *(float4*)(wo + 4 * d4) = *(const float4*)(wout + (size_t)cfix * 32 + 4 * d4);

#pragma unroll
  for (int q = 0; q < 8; q++) {
    int e = lane + (q << 6);
    int i = e >> 5;
    float acc = bout[cfix];
#pragma unroll
    for (int d = 0; d < 32; d++) acc += psso[i * 34 + d] * wo[d];
    psst[i * 34 + cfix] = acc + lq[(i << 5) + cfix];
  }
  __syncthreads();
  ln_16xS(psst, ln1g, ln1b, lane);

  float w1r[32];
#pragma unroll
  for (int d4 = 0; d4 < 8; d4++)
    *(float4*)(w1r + 4 * d4) = *(const float4*)(w1T + (size_t)lane * 32 + 4 * d4);
  __syncthreads();

#pragma unroll
  for (int q = 0; q < 16; q++) {
    int i = q;
    float acc = b1[lane];
#pragma unroll
    for (int d = 0; d < 32; d++) acc += psst[i * 34 + d] * w1r[d];
    pssh[i * 66 + lane] = gelu_exact(acc);
  }

  float w2r[64];
#pragma unroll
  for (int u4 = 0; u4 < 16; u4++)
    *(float4*)(w2r + 4 * u4) = *(const float4*)(w2T + (size_t)cfix * 64 + 4 * u4);
  __syncthreads();

#pragma unroll
  for (int q = 0; q < 8; q++) {
    int e = lane + (q << 6);
    int i = e >> 5;
    float acc = b2[cfix];
#pragma unroll
    for (int u = 0; u < 64; u++) acc += pssh[i * 66 + u] * w2r[u];
    psso[i * 34 + cfix] = acc + psst[i * 34 + cfix];
  }
  __syncthreads();
  ln_16xS(psso, ln2g, ln2b, lane);
  __syncthreads();

  const float* xp = x + (size_t)p * 512;
  const int row = lane >> 2, c0v = (lane & 3) << 3;
  float zv[8];
#pragma unroll
  for (int n = 0; n < 8; n++)
    zv[n] = xp[(lane << 3) + n] + psso[row * 34 + c0v + n];
  ushort8 hv, lv;
  float s2 = 0.f;
#pragma unroll
  for (int n = 0; n < 8; n++) {
    s2 += zv[n] * zv[n];
    ushort h = f2b_rne(zv[n]);
    hv[n] = h;
    lv[n] = f2b_rne(zv[n] - b2f(h));
  }
  *(ushort8*)(zh + (size_t)p * 512 + (lane << 3)) = hv;
  *(ushort8*)(zl + (size_t)p * 512 + (lane << 3)) = lv;
#pragma unroll
  for (int off = 1; off < 64; off <<= 1) s2 += __shfl_xor(s2, off);
  if (lane == 0) znorm[p] = s2;
}

// ---------------------------------------------------------------------------
// cbnorm + bf16 split of the codebook (ch/cl).
// ---------------------------------------------------------------------------
__global__ __launch_bounds__(64) void cbnorm_kernel(
    const float* __restrict__ cb, float* __restrict__ cbn,
    ushort* __restrict__ ch, ushort* __restrict__ cl) {
  int c = blockIdx.x, lane = threadIdx.x;
  const float* r = cb + (size_t)c * 512 + lane * 8;
  float v[8];
  *(float4*)(v)     = *(const float4*)(r);
  *(float4*)(v + 4) = *(const float4*)(r + 4);
  float s = 0.f;
  ushort8 hv, lv;
#pragma unroll
  for (int n = 0; n < 8; n++) {
    s += v[n] * v[n];
    ushort h = f2b_rne(v[n]);
    hv[n] = h;
    lv[n] = f2b_rne(v[n] - b2f(h));
  }
  *(ushort8*)(ch + (size_t)c * 512 + lane * 8) = hv;
  *(ushort8*)(cl + (size_t)c * 512 + lane * 8) = lv;
#pragma unroll
  for (int off = 1; off < 64; off <<= 1) s += __shfl_xor(s, off);
  if (lane == 0) cbn[c] = s;
}

// ---------------------------------------------------------------------------
// VQ scores via bf16x3 MFMA with fused argmin epilogue + XCD swizzle.
// ---------------------------------------------------------------------------
__global__ __launch_bounds__(256) void gemm_vq_b3(
    const ushort* __restrict__ Ah, const ushort* __restrict__ Al,
    const ushort* __restrict__ Bh, const ushort* __restrict__ Bl,
    const float* __restrict__ znorm, const float* __restrict__ cbn,
    u64* __restrict__ packed) {
  __shared__ ushort sAh[4096], sAl[4096], sBh[4096], sBl[4096];
  const int cpx = gridDim.x >> 3;
  const int bid = (blockIdx.x & 7) * cpx + (blockIdx.x >> 3);
  const int bx = bid & 7, by = bid >> 3;
  const int m0 = by << 7, n0 = bx << 7;
  const int tid = threadIdx.x;
  const int wid = tid >> 6, lane = tid & 63;
  const int wr = wid >> 1, wc = wid & 1;
  const int l15 = lane & 15, lk = lane >> 4;

  const f32x4 fzero = {0.f, 0.f, 0.f, 0.f};
  f32x4 acc[4][4];
#pragma unroll
  for (int i = 0; i < 4; i++)
#pragma unroll
    for (int j = 0; j < 4; j++) acc[i][j] = fzero;

  for (int k0 = 0; k0 < 512; k0 += 32) {
#pragma unroll
    for (int c = 0; c < 2; c++) {
      const int I = tid + (c << 8);
      const int r = I >> 2, kk = (I & 3) << 3;
      const size_t ga = (size_t)(m0 + r) * 512 + k0 + kk;
      const size_t gb = (size_t)(n0 + r) * 512 + k0 + kk;
      const size_t lo = (size_t)((wid << 6) + (c << 8)) * 8;
      gload16(Ah + ga, sAh + lo);
      gload16(Al + ga, sAl + lo);
      gload16(Bh + gb, sBh + lo);
      gload16(Bl + gb, sBl + lo);
    }
    __syncthreads();

    short8 ah[4], al[4], bh[4], bl[4];
#pragma unroll
    for (int m = 0; m < 4; m++) {
      const int ar = ((wr << 6) + (m << 4) + l15) * 32 + lk * 8;
      ah[m] = *(const short8*)(sAh + ar);
      al[m] = *(const short8*)(sAl + ar);
      const int br = ((wc << 6) + (m << 4) + l15) * 32 + lk * 8;
      bh[m] = *(const short8*)(sBh + br);
      bl[m] = *(const short8*)(sBl + br);
    }
#pragma unroll
    for (int m = 0; m < 4; m++)
#pragma unroll
      for (int n = 0; n < 4; n++) {
        acc[m][n] = __builtin_amdgcn_mfma_f32_16x16x32_bf16(ah[m], bh[n],
                                                            acc[m][n], 0, 0, 0);
        acc[m][n] = __builtin_amdgcn_mfma_f32_16x16x32_bf16(ah[m], bl[n],
                                                            acc[m][n], 0, 0, 0);
        acc[m][n] = __builtin_amdgcn_mfma_f32_16x16x32_bf16(al[m], bh[n],
                                                            acc[m][n], 0, 0, 0);
      }
    __syncthreads();
  }

  float zn[4][4];
#pragma unroll
  for (int m = 0; m < 4; m++)
#pragma unroll
    for (int r = 0; r < 4; r++)
      zn[m][r] = znorm[m0 + (wr << 6) + (m << 4) + (lk << 2) + r];
  float cbnv[4];
#pragma unroll
  for (int n = 0; n < 4; n++)
    cbnv[n] = cbn[n0 + (wc << 6) + (n << 4) + l15];

#pragma unroll
  for (int m = 0; m < 4; m++) {
#pragma unroll
    for (int r = 0; r < 4; r++) {
      u64 best = ~0ull;
#pragma unroll
      for (int n = 0; n < 4; n++) {
        const int gcol = n0 + (wc << 6) + (n << 4) + l15;
        float d = (zn[m][r] + cbnv[n]) - 2.0f * acc[m][n][r];
        u64 key = ((u64)fkey(d) << 32) | (unsigned)gcol;
        best = best < key ? best : key;
      }
#pragma unroll
      for (int off = 1; off < 16; off <<= 1) {
        u64 o = __shfl_xor(best, off);
        best = best < o ? best : o;
      }
      if (l15 == 0) {
        const int grow = m0 + (wr << 6) + (m << 4) + (lk << 2) + r;
        atomicMin(&packed[grow], best);
      }
    }
  }
}

// ---------------------------------------------------------------------------
// slim VQ finish: idx + loss partial + t (bf16). z reconstructed from zh/zl
// (drift ~1e-7 in loss only).
// ---------------------------------------------------------------------------
__global__ __launch_bounds__(256) void vq_slim_kernel(
    const u64* __restrict__ packed, const float* __restrict__ cb,
    const ushort* __restrict__ zh, const ushort* __restrict__ zl,
    const float* __restrict__ tf_pos, ushort* __restrict__ th,
    float* __restrict__ idx_out, float* __restrict__ loss_part) {
  __shared__ float spart[4];
  const int wv = threadIdx.x >> 6;
  const int r = (blockIdx.x << 2) + wv;
  const int lane = threadIdx.x & 63;
  const int bi = (int)(unsigned)(packed[r] & 0xFFFFFFFFull);
  ushort8 hv = *(const ushort8*)(zh + (size_t)r * 512 + (lane << 3));
  ushort8 lv = *(const ushort8*)(zl + (size_t)r * 512 + (lane << 3));
  const float* q = cb + (size_t)bi * 512 + (lane << 3);
  const float* pr = tf_pos + (size_t)(r & 255) * 512 + (lane << 3);
  float qv[8], pv[8];
  *(float4*)(qv)     = *(const float4*)(q);
  *(float4*)(qv + 4) = *(const float4*)(q + 4);
  *(float4*)(pv)     = *(const float4*)(pr);
  *(float4*)(pv + 4) = *(const float4*)(pr + 4);
  float lsum = 0.f;
  ushort8 w;
#pragma unroll
  for (int n = 0; n < 8; n++) {
    float zv = b2f(hv[n]) + b2f(lv[n]);
    float diff = qv[n] - zv;
    lsum += diff * diff;
    w[n] = f2b_rne(qv[n] + pv[n]);
  }
  *(ushort8*)(th + (size_t)r * 512 + (lane << 3)) = w;
#pragma unroll
  for (int off = 1; off < 64; off <<= 1) lsum += __shfl_xor(lsum, off);
  if (lane == 0) {
    idx_out[r] = (float)bi;
    spart[wv] = lsum;
  }
  __syncthreads();
  if (threadIdx.x == 0)
    loss_part[blockIdx.x] = (spart[0] + spart[1]) + (spart[2] + spart[3]);
}

// ---------------------------------------------------------------------------
__global__ __launch_bounds__(256) void loss_reduce_kernel(
    const float* __restrict__ loss_part, float* __restrict__ loss_out) {
  __shared__ float sw[4];
  float s = 0.f;
  for (int i = threadIdx.x; i < 4096; i += 256) s += loss_part[i];
#pragma unroll
  for (int off = 1; off < 64; off <<= 1) s += __shfl_xor(s, off);
  const int wv = threadIdx.x >> 6;
  if ((threadIdx.x & 63) == 0) sw[wv] = s;
  __syncthreads();
  if (threadIdx.x == 0)
    loss_out[0] = ((sw[0] + sw[1]) + (sw[2] + sw[3])) * (1.25f / 8388608.0f);
}

// ---------------------------------------------------------------------------
// bf16 MFMA GEMM, BK=64 dual sub-tile LDS [2][128][32], XCD swizzle.
// ---------------------------------------------------------------------------
template <int OUTMODE>
__global__ __launch_bounds__(256) void gemm_bf16_kernel(
    const ushort* __restrict__ A, const ushort* __restrict__ B,
    const float* __restrict__ bias, void* __restrict__ Cout,
    int M, int N, int K) {
  __shared__ ushort As[8192];  // [2][128][32]
  __shared__ ushort Bs[8192];
  const int nbx = N >> 7;
  const int cpx = gridDim.x >> 3;
  const int bid = (blockIdx.x & 7) * cpx + (blockIdx.x >> 3);
  const int bx = bid % nbx, by = bid / nbx;
  const int m0 = by << 7, n0 = bx << 7;
  const int tid = threadIdx.x;
  const int wid = tid >> 6, lane = tid & 63;
  const int wr = wid >> 1, wc = wid & 1;
  const int l15 = lane & 15, lk = lane >> 4;

  const f32x4 fzero = {0.f, 0.f, 0.f, 0.f};
  f32x4 acc[4][4];
#pragma unroll
  for (int i = 0; i < 4; i++)
#pragma unroll
    for (int j = 0; j < 4; j++) acc[i][j] = fzero;

  for (int k0 = 0; k0 < K; k0 += 64) {
#pragma unroll
    for (int c = 0; c < 4; c++) {
      const int base = (c << 8) + (wid << 6);
      const int half = base >> 9;
      const int Jb = base & 511;
      const int J = Jb + lane;
      const int r = J >> 2, kk = (J & 3) << 3;
      gload16(A + (size_t)(m0 + r) * K + k0 + (half << 5) + kk,
              As + (size_t)((half << 12) + Jb * 8));
      gload16(B + (size_t)(n0 + r) * K + k0 + (half << 5) + kk,
              Bs + (size_t)((half << 12) + Jb * 8));
    }
    __syncthreads();

#pragma unroll
    for (int kc = 0; kc < 2; kc++) {
      short8 a[4], b[4];
#pragma unroll
      for (int m = 0; m < 4; m++) {
        const int ar = (kc << 12) + ((wr << 6) + (m << 4) + l15) * 32 + lk * 8;
        a[m] = *(const short8*)(As + ar);
        const int br = (kc << 12) + ((wc << 6) + (m << 4) + l15) * 32 + lk * 8;
        b[m] = *(const short8*)(Bs + br);
      }
#pragma unroll
      for (int m = 0; m < 4; m++)
#pragma unroll
        for (int n = 0; n < 4; n++)
          acc[m][n] = __builtin_amdgcn_mfma_f32_16x16x32_bf16(a[m], b[n],
                                                              acc[m][n], 0, 0, 0);
    }
    __syncthreads();
  }

  float bv[4];
#pragma unroll
  for (int n = 0; n < 4; n++)
    bv[n] = bias[n0 + (wc << 6) + (n << 4) + l15];

#pragma unroll
  for (int m = 0; m < 4; m++) {
#pragma unroll
    for (int n = 0; n < 4; n++) {
      const int gcol = n0 + (wc << 6) + (n << 4) + l15;
#pragma unroll
      for (int r = 0; r < 4; r++) {
        const int grow = m0 + (wr << 6) + (m << 4) + (lk << 2) + r;
        float v = acc[m][n][r] + bv[n];
        if (OUTMODE == 0) {
          ((float*)Cout)[(size_t)grow * N + gcol] = v;
        } else if (OUTMODE == 1) {
          ((ushort*)Cout)[(size_t)grow * N + gcol] = f2b_rne(gelu_exact(v));
        } else {
          ((ushort*)Cout)[(size_t)grow * N + gcol] = f2b_rne(v);
        }
      }
    }
  }
}

// ---------------------------------------------------------------------------
// Weight conversions.
// ---------------------------------------------------------------------------
__global__ void cvt_flat(const float* __restrict__ in, ushort* __restrict__ out,
                         int n) {
  int i = blockIdx.x * blockDim.x + threadIdx.x;
  const int stride = gridDim.x * blockDim.x;
  for (; i < n; i += stride) out[i] = f2b_rne(in[i]);
}

__global__ __launch_bounds__(256) void cvt_tr(const float* __restrict__ in,
                                              ushort* __restrict__ out,
                                              int R, int C) {
  __shared__ float tile[32][33];
  const int bc = blockIdx.x, br = blockIdx.y, lay = blockIdx.z;
  const float* src = in + (size_t)lay * R * C;
  ushort* dst = out + (size_t)lay * R * C;
  const int tid = threadIdx.x;
#pragma unroll
  for (int q = 0; q < 4; q++) {
    int idx = tid + (q << 8);
    int rr = idx >> 5, cc = idx & 31;
    tile[rr][cc] = src[(size_t)(br * 32 + rr) * C + bc * 32 + cc];
  }
  __syncthreads();
#pragma unroll
  for (int q = 0; q < 4; q++) {
    int idx = tid + (q << 8);
    int co = idx >> 5, ro = idx & 31;
    dst[(size_t)(bc * 32 + co) * R + br * 32 + ro] = f2b_rne(tile[ro][co]);
  }
}

// ---------------------------------------------------------------------------
// MFMA flash attention; O repacked via LDS (stride-66 rows) for 128B stores.
// Single-wave block -> no barrier needed for the repack.
// ---------------------------------------------------------------------------
__global__ __launch_bounds__(64) void attn_mfma_kernel(
    const ushort* __restrict__ qkv, ushort* __restrict__ o) {
  __shared__ ushort lds[8192];
  char* KsB = (char*)lds;
  char* VtB = (char*)(lds + 4096);
  const int bid = blockIdx.x;
  const int xcd = bid & 7, slot = bid >> 3;
  const int b = (xcd << 3) | (slot >> 5);
  const int h = (slot >> 2) & 7;
  const int qb = slot & 3;
  const int lane = threadIdx.x;
  const int l15 = lane & 15, lk4 = lane >> 4;

  short8 qf[4][2];
#pragma unroll
  for (int m = 0; m < 4; m++)
#pragma unroll
    for (int kc = 0; kc < 2; kc++)
      qf[m][kc] = *(const short8*)(qkv +
          (size_t)(b * 256 + qb * 64 + m * 16 + l15) * 1536 +
          h * 64 + kc * 32 + lk4 * 8);

  const f32x4 fz = {0.f, 0.f, 0.f, 0.f};
  f32x4 O[4][4];
#pragma unroll
  for (int m = 0; m < 4; m++)
#pragma unroll
    for (int n = 0; n < 4; n++) O[m][n] = fz;
  float lsum[4][4];
#pragma unroll
  for (int m = 0; m < 4; m++)
#pragma unroll
    for (int r = 0; r < 4; r++) lsum[m][r] = 0.f;

  ushort8 kv[8], vv[8];
  {
    const ushort* krow = qkv + (size_t)(b * 256 + lane) * 1536 + 512 + h * 64;
#pragma unroll
    for (int u = 0; u < 8; u++) kv[u] = ((const ushort8*)krow)[u];
#pragma unroll
    for (int u = 0; u < 8; u++) vv[u] = ((const ushort8*)(krow + 512))[u];
  }

  for (int jt = 0; jt <= qb; jt++) {
    __syncthreads();
    {
      const int rx = (lane & 7) << 4;
#pragma unroll
      for (int u = 0; u < 8; u++)
        *(ushort8*)(KsB + lane * 128 + ((u << 4) ^ rx)) = kv[u];
#pragma unroll
      for (int u = 0; u < 8; u++)
#pragma unroll
        for (int i = 0; i < 8; i++) {
          const int d = u * 8 + i;
          *(ushort*)(VtB + ((d * 128 + lane * 2) ^ ((d & 7) << 4))) =
              (ushort)vv[u][i];
        }
    }
    __syncthreads();

    if (jt < qb) {
      const ushort* krow = qkv +
          (size_t)(b * 256 + (jt + 1) * 64 + lane) * 1536 + 512 + h * 64;
#pragma unroll
      for (int u = 0; u < 8; u++) kv[u] = ((const ushort8*)krow)[u];
#pragma unroll
      for (int u = 0; u < 8; u++) vv[u] = ((const ushort8*)(krow + 512))[u];
    }

    f32x4 sacc[4][4];
#pragma unroll
    for (int m = 0; m < 4; m++)
#pragma unroll
      for (int n = 0; n < 4; n++) sacc[m][n] = fz;
    __builtin_amdgcn_s_setprio(1);
#pragma unroll
    for (int kc = 0; kc < 2; kc++) {
      short8 bf[4];
#pragma unroll
      for (int n = 0; n < 4; n++) {
        const int row = n * 16 + l15;
        bf[n] = *(const short8*)(KsB + row * 128 +
                                 ((kc * 64 + lk4 * 16) ^ ((row & 7) << 4)));
      }
#pragma unroll
      for (int m = 0; m < 4; m++)
#pragma unroll
        for (int n = 0; n < 4; n++)
          sacc[m][n] = __builtin_amdgcn_mfma_f32_16x16x32_bf16(
              qf[m][kc], bf[n], sacc[m][n], 0, 0, 0);
    }
    __builtin_amdgcn_s_setprio(0);
    __syncthreads();

    const bool diag = (jt == qb);
#pragma unroll
    for (int m = 0; m < 4; m++)
#pragma unroll
      for (int n = 0; n < 4; n++)
#pragma unroll
        for (int r = 0; r < 4; r++) {
          const int ql = m * 16 + lk4 * 4 + r;
          const int jl = n * 16 + l15;
          float e = __expf(sacc[m][n][r] * 0.125f);
          if (diag && jl > ql) e = 0.f;
          const ushort pu = f2b_rne(e);
          lsum[m][r] += b2f(pu);
          *(ushort*)(KsB + ql * 128 + ((jl * 2) ^ ((ql & 7) << 4))) = pu;
        }
    __syncthreads();

    __builtin_amdgcn_s_setprio(1);
#pragma unroll
    for (int kc = 0; kc < 2; kc++) {
      short8 pf[4], vf[4];
#pragma unroll
      for (int m = 0; m < 4; m++) {
        const int row = m * 16 + l15;
        pf[m] = *(const short8*)(KsB + row * 128 +
                                 ((kc * 64 + lk4 * 16) ^ ((row & 7) << 4)));
      }
#pragma unroll
      for (int n = 0; n < 4; n++) {
        const int row = n * 16 + l15;
        vf[n] = *(const short8*)(VtB + row * 128 +
                                 ((kc * 64 + lk4 * 16) ^ ((row & 7) << 4)));
      }
#pragma unroll
      for (int m = 0; m < 4; m++)
#pragma unroll
        for (int n = 0; n < 4; n++)
          O[m][n] = __builtin_amdgcn_mfma_f32_16x16x32_bf16(
              pf[m], vf[n], O[m][n], 0, 0, 0);
    }
    __builtin_amdgcn_s_setprio(0);
  }

  float inv[4][4];
#pragma unroll
  for (int m = 0; m < 4; m++)
#pragma unroll
    for (int r = 0; r < 4; r++) {
      float v = lsum[m][r];
      v += __shfl_xor(v, 1); v += __shfl_xor(v, 2);
      v += __shfl_xor(v, 4); v += __shfl_xor(v, 8);
      inv[m][r] = 1.0f / v;
    }

  // repack O -> LDS (rows stride 66 ushorts), then 128B-coalesced stores.
  // Single wave: in-wave LDS ordering is program order; no barrier needed.
  ushort* Ob = lds;
#pragma unroll
  for (int m = 0; m < 4; m++)
#pragma unroll
    for (int n = 0; n < 4; n++)
#pragma unroll
      for (int r = 0; r < 4; r++) {
        const int row = m * 16 + lk4 * 4 + r;
        const int col = n * 16 + l15;
        Ob[row * 66 + col] = f2b_rne(O[m][n][r] * inv[m][r]);
      }
#pragma unroll
  for (int it = 0; it < 8; it++) {
    const int row = it * 8 + (lane >> 3);
    const int c0 = (lane & 7) << 3;
    ushort8 w = *(const ushort8*)(Ob + row * 66 + c0);
    *(ushort8*)(o + (size_t)(b * 256 + qb * 64 + row) * 512 + h * 64 + c0) = w;
  }
}

// ---------------------------------------------------------------------------
// LayerNorm over 512, bf16 in / bf16 out (+optional f32 out for final).
// ---------------------------------------------------------------------------
__global__ __launch_bounds__(256) void ln_kernel(
    const ushort* __restrict__ xin_b, const ushort* __restrict__ addin_b,
    const float* __restrict__ g, const float* __restrict__ bb,
    ushort* __restrict__ outb, float* __restrict__ outp) {
  const int r = blockIdx.x * 4 + (threadIdx.x >> 6);
  const int lane = threadIdx.x & 63;
  ushort8 xv = *(const ushort8*)(xin_b + (size_t)r * 512 + lane * 8);
  float v[8];
#pragma unroll
  for (int n = 0; n < 8; n++) v[n] = b2f(xv[n]);
  if (addin_b) {
    ushort8 a = *(const ushort8*)(addin_b + (size_t)r * 512 + lane * 8);
#pragma unroll
    for (int n = 0; n < 8; n++) v[n] += b2f(a[n]);
  }
  float s = 0.f, s2 = 0.f;
#pragma unroll
  for (int n = 0; n < 8; n++) { s += v[n]; s2 += v[n] * v[n]; }
#pragma unroll
  for (int off = 1; off < 64; off <<= 1) {
    s += __shfl_xor(s, off);
    s2 += __shfl_xor(s2, off);
  }
  float m = s * (1.0f / 512.0f);
  float var = s2 * (1.0f / 512.0f) - m * m;
  float inv = 1.0f / sqrtf(var + 1e-5f);
  const int c0 = lane * 8;
  float outv[8];
#pragma unroll
  for (int n = 0; n < 8; n++) outv[n] = (v[n] - m) * inv * g[c0 + n] + bb[c0 + n];
  if (outb) {
    ushort8 w;
#pragma unroll
    for (int n = 0; n < 8; n++) w[n] = f2b_rne(outv[n]);
    *(ushort8*)(outb + (size_t)r * 512 + c0) = w;
  }
  if (outp) {
    float* orow = outp + (size_t)r * 512 + c0;
    *(float4*)(orow)     = *(float4*)(outv);
    *(float4*)(orow + 4) = *(float4*)(outv + 4);
  }
}

// ---------------------------------------------------------------------------
extern "C" void kernel_launch(void* const* d_in, const int* in_sizes, int n_in,
                              void* d_out, int out_size, void* d_ws, size_t ws_size,
                              hipStream_t stream) {
  const float* x       = (const float*)d_in[0];
  const float* pa_lq   = (const float*)d_in[1];
  const float* pa_pos  = (const float*)d_in[2];
  const float* pa_win  = (const float*)d_in[3];
  const float* pa_bin  = (const float*)d_in[4];
  const float* pa_wout = (const float*)d_in[5];
  const float* pa_bout = (const float*)d_in[6];
  const float* pa_ln1g = (const float*)d_in[7];
  const float* pa_ln1b = (const float*)d_in[8];
  const float* pa_ln2g = (const float*)d_in[9];
  const float* pa_ln2b = (const float*)d_in[10];
  const float* pa_w1   = (const float*)d_in[11];
  const float* pa_b1   = (const float*)d_in[12];
  const float* pa_w2   = (const float*)d_in[13];
  const float* pa_b2   = (const float*)d_in[14];
  const float* cb      = (const float*)d_in[15];
  const float* tf_pos  = (const float*)d_in[16];
  const float* tf_win  = (const float*)d_in[17];
  const float* tf_bin  = (const float*)d_in[18];
  const float* tf_wout = (const float*)d_in[19];
  const float* tf_bout = (const float*)d_in[20];
  const float* tf_ln1g = (const float*)d_in[21];
  const float* tf_ln1b = (const float*)d_in[22];
  const float* tf_ln2g = (const float*)d_in[23];
  const float* tf_ln2b = (const float*)d_in[24];
  const float* tf_w1   = (const float*)d_in[25];
  const float* tf_b1   = (const float*)d_in[26];
  const float* tf_w2   = (const float*)d_in[27];
  const float* tf_b2   = (const float*)d_in[28];
  const float* fin_g   = (const float*)d_in[29];
  const float* fin_b   = (const float*)d_in[30];

  float* yout = (float*)d_out;            // 16384 x 512
  float* loss_out = yout + 8388608;       // scalar
  float* idx_out = loss_out + 1;          // 16384 (as float)

  float* ws   = (float*)d_ws;
  float* z    = ws;                   // 8388608 (tf: abh attn out bf16)
  float* tb   = z + 8388608;          // 8388608 (unused; layout keep)
  float* bufA = tb + 8388608;         // 16777216 (tf: qkv/ffn-h)
  float* bufC = bufA + 16777216;      // 8388608  (patch: zh/zl ; tf: projh bf16)
  float* wreg = bufC + 8388608;       // 6291456
  float* treg = wreg + 6291456;       // 4194304  (VQ: ch/cl ; tf: tbh)
  float* cbn  = treg + 4194304;       // 1024
  float* q16  = cbn + 1024;           // 512
  float* w1T  = q16 + 512;            // 2048
  float* w2T  = w1T + 2048;           // 2048
  float* znorm = w2T + 2048;          // 16384
  u64*   packed = (u64*)(znorm + 16384);  // 16384 u64
  float* loss_part = (float*)(packed + 16384); // 4096

  ushort* win_b  = (ushort*)wreg;
  ushort* wout_b = win_b + 3145728;
  ushort* w1t_b  = wout_b + 1048576;
  ushort* w2t_b  = w1t_b + 4194304;
  ushort* tbh    = (ushort*)treg;
  ushort* qkvh   = (ushort*)bufA;
  ushort* abh    = (ushort*)z;
  ushort* zh_b   = (ushort*)bufC;
  ushort* zl_b   = zh_b + 8388608;
  ushort* projh  = (ushort*)bufC;          // bf16 proj outputs (zh/zl dead)
  ushort* ch_b   = (ushort*)treg;          // dead before tbh written
  ushort* cl_b   = ch_b + 524288;

  hipMemsetAsync(packed, 0xFF, 16384 * sizeof(u64), stream);
  cbnorm_kernel<<<1024, 64, 0, stream>>>(cb, cbn, ch_b, cl_b);
  patch_setup_kernel<<<1, 64, 0, stream>>>(pa_lq, pa_win, pa_bin, pa_w1,
                                           pa_w2, q16, w1T, w2T);

  // fused patch encoder (z values bit-identical; stored only as zh/zl)
  pkF_kernel<<<4096, 256, 0, stream>>>(x, pa_pos, pa_win, pa_bin, q16,
                                       pa_wout, pa_bout, pa_lq,
                                       pa_ln1g, pa_ln1b, w1T, pa_b1,
                                       w2T, pa_b2, pa_ln2g, pa_ln2b,
                                       zh_b, zl_b, znorm);

  cvt_flat<<<2048, 256, 0, stream>>>(tf_win, win_b, 3145728);
  cvt_flat<<<1024, 256, 0, stream>>>(tf_wout, wout_b, 1048576);
  cvt_tr<<<dim3(64, 16, 4), 256, 0, stream>>>(tf_w1, w1t_b, 512, 2048);
  cvt_tr<<<dim3(16, 64, 4), 256, 0, stream>>>(tf_w2, w2t_b, 2048, 512);

  gemm_vq_b3<<<dim3(1024), 256, 0, stream>>>(zh_b, zl_b, ch_b, cl_b,
                                             znorm, cbn, packed);
  vq_slim_kernel<<<4096, 256, 0, stream>>>(packed, cb, zh_b, zl_b, tf_pos,
                                           tbh, idx_out, loss_part);
  loss_reduce_kernel<<<1, 256, 0, stream>>>(loss_part, loss_out);

  for (int l = 0; l < 4; l++) {
    gemm_bf16_kernel<2><<<dim3(128 * 12), 256, 0, stream>>>(
        tbh, win_b + (size_t)l * 1536 * 512, tf_bin + l * 1536, qkvh,
        16384, 1536, 512);
    attn_mfma_kernel<<<dim3(2048), 64, 0, stream>>>(qkvh, abh);
    gemm_bf16_kernel<2><<<dim3(128 * 4), 256, 0, stream>>>(
        abh, wout_b + (size_t)l * 512 * 512, tf_bout + l * 512, projh,
        16384, 512, 512);
    ln_kernel<<<dim3(4096), 256, 0, stream>>>(tbh, projh, tf_ln1g + l * 512,
                                              tf_ln1b + l * 512, tbh, nullptr);
    gemm_bf16_kernel<1><<<dim3(128 * 16), 256, 0, stream>>>(
        tbh, w1t_b + (size_t)l * 1048576, tf_b1 + l * 2048, qkvh,
        16384, 2048, 512);
    gemm_bf16_kernel<2><<<dim3(128 * 4), 256, 0, stream>>>(
        qkvh, w2t_b + (size_t)l * 1048576, tf_b2 + l * 512, projh,
        16384, 512, 2048);
    ln_kernel<<<dim3(4096), 256, 0, stream>>>(tbh, projh, tf_ln2g + l * 512,
                                              tf_ln2b + l * 512, tbh, nullptr);
  }
  ln_kernel<<<dim3(4096), 256, 0, stream>>>(tbh, nullptr, fin_g, fin_b,
                                            nullptr, yout);

  (void)in_sizes; (void)n_in; (void)out_size; (void)ws_size;
}